// Round 1
// baseline (409.797 us; speedup 1.0000x reference)
//
#include <hip/hip_runtime.h>
#include <math.h>
#include <stdint.h>

// BlindCrossAttention on MI355X (gfx950).
// Pipeline (all f16 MFMA, fp32 accum/stats):
//  pos table -> cvt q,k,W(T) to f16 -> 3x GEMM(+LN) -> transpose vn
//  -> s1 GEMM (writes raw scores into att slot) -> softmax1 (in place + f16 copy)
//  -> x = a1@pos GEMM -> attn2 (x' = x@Wp+bp; s2 = x'.pos^T/8 -> att slot)
//  -> softmax2 -> out = a2@vn GEMM.

typedef _Float16 f16;
typedef _Float16 f16x4 __attribute__((ext_vector_type(4)));
typedef _Float16 f16x8 __attribute__((ext_vector_type(8)));
typedef float f32x4 __attribute__((ext_vector_type(4)));

static constexpr int CB  = 4;     // batch
static constexpr int CNQ = 2048;  // queries
static constexpr int CNK = 2048;  // keys
static constexpr int CD  = 1024;  // Q_DIM = K_DIM = ATT_DIM
static constexpr int CP  = 64;    // POS_DIM

// ---------- async global->LDS, 16B/lane (dest = wave-uniform base + lane*16) ----------
static __device__ __forceinline__ void async16(const f16* gp, f16* lp) {
  // generic LDS pointer has the AS3 offset in its low 32 bits (AMDGPU aperture layout)
  __builtin_amdgcn_global_load_lds(
      (const __attribute__((address_space(1))) void*)(uintptr_t)gp,
      (__attribute__((address_space(3))) void*)(uint32_t)(uintptr_t)lp,
      16, 0, 0);
}

// ---------- pos table: posb[j][p] and posTb[p][j], f16 ----------
__global__ __launch_bounds__(256) void pos_kernel(f16* __restrict__ posb,
                                                  f16* __restrict__ posTb) {
  int tid = blockIdx.x * 256 + threadIdx.x;   // CP*CNK threads
  int p = tid >> 11;                          // 0..63
  int j = tid & (CNK - 1);                    // 0..2047
  int i = p & 31;
  float ph = (float)j * powf(10000.0f, -(float)i * (1.0f / 32.0f));
  float v = (p < 32) ? sinf(ph) : cosf(ph);   // sin(ph + pi/2) == cos(ph)
  posb[j * CP + p]   = (f16)v;
  posTb[p * CNK + j] = (f16)v;
}

// ---------- f32 -> f16, 4 elems/thread ----------
__global__ __launch_bounds__(256) void cvt_kernel(const float* __restrict__ in,
                                                  f16* __restrict__ out) {
  int tid = blockIdx.x * 256 + threadIdx.x;
  float4 v = reinterpret_cast<const float4*>(in)[tid];
  f16x4 o = {(f16)v.x, (f16)v.y, (f16)v.z, (f16)v.w};
  reinterpret_cast<f16x4*>(out)[tid] = o;
}

// ---------- W[k][n] f32 -> WT[n][k] f16 (1024x1024) ----------
__global__ __launch_bounds__(256) void cvtWT_kernel(const float* __restrict__ W,
                                                    f16* __restrict__ WT) {
  __shared__ float t[64][65];
  int k0 = blockIdx.x * 64, n0 = blockIdx.y * 64;
  int tx = threadIdx.x & 63, ty = threadIdx.x >> 6;
#pragma unroll
  for (int i = 0; i < 16; i++)
    t[ty + 4 * i][tx] = W[(size_t)(k0 + ty + 4 * i) * CD + n0 + tx];
  __syncthreads();
#pragma unroll
  for (int i = 0; i < 16; i++)
    WT[(size_t)(n0 + 4 * i + ty) * CD + k0 + tx] = (f16)t[tx][ty + 4 * i];
}

// ---------- per-batch f16 transpose: out[b][d][n] = in[b][n][d] ----------
__global__ __launch_bounds__(256) void transpose_kernel(const f16* __restrict__ in,
                                                        f16* __restrict__ out) {
  __shared__ f16 t[64][65];
  int n0 = blockIdx.x * 64, d0 = blockIdx.y * 64;
  size_t base = (size_t)blockIdx.z * CNK * CD;
  int tx = threadIdx.x & 63, ty = threadIdx.x >> 6;
#pragma unroll
  for (int i = 0; i < 16; i++)
    t[ty + 4 * i][tx] = in[base + (size_t)(n0 + ty + 4 * i) * CD + d0 + tx];
  __syncthreads();
#pragma unroll
  for (int i = 0; i < 16; i++)
    out[base + (size_t)(d0 + ty + 4 * i) * CNK + n0 + tx] = t[tx][ty + 4 * i];
}

// ---------- NT GEMM: C[m,n] = scale * sum_k A[m,k]*Bt[n,k] (m97 structure) ----------
// BK=32, 4 waves (2x2), 16x16x32 f16 MFMA, global_load_lds staging, 2-barrier loop.
template <int BM, int BN, int EPI>  // EPI 0: f32*scale, 1: f16
__global__ __launch_bounds__(256) void gemm_nt(
    const f16* __restrict__ A, const f16* __restrict__ Bt, void* __restrict__ C,
    int K, int lda, int ldb, int ldc,
    size_t sA, size_t sB, size_t sC, float scale) {
  constexpr int FM = BM / 32;          // 16x16 frags per wave (rows)
  constexpr int FN = BN / 32;          // (cols)
  constexpr int NA = BM / 16, NTOT = NA + BN / 16;
  __shared__ __attribute__((aligned(16))) f16 As[BM * 32];
  __shared__ __attribute__((aligned(16))) f16 Bs[BN * 32];

  const int lane = threadIdx.x & 63;
  const int wave = threadIdx.x >> 6;
  const int wr = wave >> 1, wc = wave & 1;
  const int m0 = blockIdx.x * BM, n0 = blockIdx.y * BN;
  A += sA * blockIdx.z;
  Bt += sB * blockIdx.z;

  const int srow = lane >> 2;          // staging: 4 lanes cover one 32-k row
  const int scol = (lane & 3) * 8;
  const int lrow = lane & 15;          // frag row within 16
  const int kg = lane >> 4;            // frag k-group (8 each)

  f32x4 acc[FM][FN] = {};

  for (int k0 = 0; k0 < K; k0 += 32) {
    __syncthreads();                   // all waves done reading LDS
#pragma unroll
    for (int i = wave; i < NTOT; i += 4) {
      if (i < NA)
        async16(A + (size_t)(m0 + i * 16 + srow) * lda + k0 + scol, &As[i * 512]);
      else
        async16(Bt + (size_t)(n0 + (i - NA) * 16 + srow) * ldb + k0 + scol,
                &Bs[(i - NA) * 512]);
    }
    __syncthreads();                   // barrier drains vmcnt(0) -> tiles ready

    f16x8 af[FM], bf[FN];
#pragma unroll
    for (int m = 0; m < FM; m++)
      af[m] = *reinterpret_cast<const f16x8*>(
          &As[(wr * (BM / 2) + m * 16 + lrow) * 32 + kg * 8]);
#pragma unroll
    for (int n = 0; n < FN; n++)
      bf[n] = *reinterpret_cast<const f16x8*>(
          &Bs[(wc * (BN / 2) + n * 16 + lrow) * 32 + kg * 8]);
#pragma unroll
    for (int m = 0; m < FM; m++)
#pragma unroll
      for (int n = 0; n < FN; n++)
        acc[m][n] = __builtin_amdgcn_mfma_f32_16x16x32_f16(af[m], bf[n], acc[m][n], 0, 0, 0);
  }

  // C/D layout: col = lane&15, row = (lane>>4)*4 + r
  const int crow = m0 + wr * (BM / 2) + (lane >> 4) * 4;
  const int ccol = n0 + wc * (BN / 2) + (lane & 15);
#pragma unroll
  for (int m = 0; m < FM; m++)
#pragma unroll
    for (int n = 0; n < FN; n++)
#pragma unroll
      for (int r = 0; r < 4; r++) {
        size_t off = sC * blockIdx.z + (size_t)(crow + m * 16 + r) * ldc + ccol + n * 16;
        if (EPI == 0) ((float*)C)[off] = acc[m][n][r] * scale;
        else          ((f16*)C)[off]   = (f16)acc[m][n][r];
      }
}

// ---------- LayerNorm row kernel: out = (x+bias - mean)*rstd*g + beta, f16 out ----------
__global__ __launch_bounds__(256) void ln_kernel(
    const f16* __restrict__ in, const float* __restrict__ bias,
    const float* __restrict__ g, const float* __restrict__ beta,
    f16* __restrict__ out) {
  __shared__ float rs_[4], rq_[4];
  const size_t row = blockIdx.x;
  const int t = threadIdx.x;
  f16x4 v = *reinterpret_cast<const f16x4*>(in + row * CD + t * 4);
  float y[4], s = 0.f, q = 0.f;
#pragma unroll
  for (int j = 0; j < 4; j++) {
    y[j] = (float)v[j] + bias[t * 4 + j];
    s += y[j]; q += y[j] * y[j];
  }
#pragma unroll
  for (int o = 32; o; o >>= 1) { s += __shfl_xor(s, o); q += __shfl_xor(q, o); }
  if ((t & 63) == 0) { rs_[t >> 6] = s; rq_[t >> 6] = q; }
  __syncthreads();
  s = rs_[0] + rs_[1] + rs_[2] + rs_[3];
  q = rq_[0] + rq_[1] + rq_[2] + rq_[3];
  const float mean = s * (1.0f / CD);
  const float var  = q * (1.0f / CD) - mean * mean;
  const float rstd = rsqrtf(var + 1e-5f);
  f16x4 o;
#pragma unroll
  for (int j = 0; j < 4; j++) {
    int c = t * 4 + j;
    o[j] = (f16)((y[j] - mean) * rstd * g[c] + beta[c]);
  }
  *reinterpret_cast<f16x4*>(out + row * CD + t * 4) = o;
}

// ---------- row softmax, in place on att slot `head`, plus f16 copy ----------
__global__ __launch_bounds__(256) void softmax_kernel(float* __restrict__ att,
                                                      f16* __restrict__ ob,
                                                      int head) {
  __shared__ float red[4];
  const int row = blockIdx.x;           // 0..8191
  const int b = row >> 11, n = row & (CNQ - 1);
  float* rp = att + ((size_t)((b << 1) + head) * CNQ + n) * CNK;
  const int t = threadIdx.x;
  float4 v0 = reinterpret_cast<float4*>(rp)[t * 2];
  float4 v1 = reinterpret_cast<float4*>(rp)[t * 2 + 1];
  float m = fmaxf(fmaxf(fmaxf(v0.x, v0.y), fmaxf(v0.z, v0.w)),
                  fmaxf(fmaxf(v1.x, v1.y), fmaxf(v1.z, v1.w)));
#pragma unroll
  for (int o = 32; o; o >>= 1) m = fmaxf(m, __shfl_xor(m, o));
  if ((t & 63) == 0) red[t >> 6] = m;
  __syncthreads();
  m = fmaxf(fmaxf(red[0], red[1]), fmaxf(red[2], red[3]));
  float e[8] = {__expf(v0.x - m), __expf(v0.y - m), __expf(v0.z - m), __expf(v0.w - m),
                __expf(v1.x - m), __expf(v1.y - m), __expf(v1.z - m), __expf(v1.w - m)};
  float s = ((e[0] + e[1]) + (e[2] + e[3])) + ((e[4] + e[5]) + (e[6] + e[7]));
#pragma unroll
  for (int o = 32; o; o >>= 1) s += __shfl_xor(s, o);
  __syncthreads();
  if ((t & 63) == 0) red[t >> 6] = s;
  __syncthreads();
  s = red[0] + red[1] + red[2] + red[3];
  const float inv = 1.0f / s;
  float4 w0 = {e[0] * inv, e[1] * inv, e[2] * inv, e[3] * inv};
  float4 w1 = {e[4] * inv, e[5] * inv, e[6] * inv, e[7] * inv};
  reinterpret_cast<float4*>(rp)[t * 2]     = w0;
  reinterpret_cast<float4*>(rp)[t * 2 + 1] = w1;
  f16x8 h = {(f16)w0.x, (f16)w0.y, (f16)w0.z, (f16)w0.w,
             (f16)w1.x, (f16)w1.y, (f16)w1.z, (f16)w1.w};
  *reinterpret_cast<f16x8*>(ob + (size_t)row * CNK + t * 8) = h;
}

// ---------- attn2: x' = x@Wp + bp; raw s2 = x'.pos^T / 8 into att head-1 slot ----------
// one wave per 16 q-rows
__global__ __launch_bounds__(64) void attn2_kernel(
    const float* __restrict__ x, const float* __restrict__ Wp,
    const float* __restrict__ bp, const f16* __restrict__ posb,
    float* __restrict__ att) {
  __shared__ float xs[16 * 64];
  __shared__ float Wps[64 * 64];
  __shared__ __attribute__((aligned(16))) f16 xpb[16 * 64];
  const int l = threadIdx.x;
  const int r0 = blockIdx.x * 16;
#pragma unroll
  for (int i = 0; i < 16; i++) xs[i * 64 + l] = x[(size_t)(r0 + i) * CP + l];
#pragma unroll 8
  for (int i = 0; i < 64; i++) Wps[i * 64 + l] = Wp[i * 64 + l];
  const float bpl = bp[l];
  __syncthreads();
#pragma unroll 2
  for (int i = 0; i < 16; i++) {       // row i, col l: x' = x @ Wp + bp
    float a = bpl;
#pragma unroll 8
    for (int p = 0; p < 64; p++) a = fmaf(xs[i * 64 + p], Wps[p * 64 + l], a);
    xpb[i * 64 + l] = (f16)a;
  }
  __syncthreads();
  const f16x8 af0 = *reinterpret_cast<const f16x8*>(&xpb[(l & 15) * 64 + (l >> 4) * 8]);
  const f16x8 af1 = *reinterpret_cast<const f16x8*>(&xpb[(l & 15) * 64 + 32 + (l >> 4) * 8]);
  const int b = r0 >> 11, nloc = r0 & (CNQ - 1);
  float* ob = att + ((size_t)((b << 1) + 1) * CNQ + nloc) * CNK;
  for (int jt = 0; jt < CNK / 64; jt++) {
#pragma unroll
    for (int q4 = 0; q4 < 4; q4++) {
      const int j = jt * 64 + q4 * 16 + (l & 15);
      const f16* pp = posb + (size_t)j * CP + (l >> 4) * 8;
      f16x8 b0 = *reinterpret_cast<const f16x8*>(pp);
      f16x8 b1 = *reinterpret_cast<const f16x8*>(pp + 32);
      f32x4 c = {};
      c = __builtin_amdgcn_mfma_f32_16x16x32_f16(af0, b0, c, 0, 0, 0);
      c = __builtin_amdgcn_mfma_f32_16x16x32_f16(af1, b1, c, 0, 0, 0);
#pragma unroll
      for (int r = 0; r < 4; r++)
        ob[(size_t)((l >> 4) * 4 + r) * CNK + j] = c[r] * 0.125f;
    }
  }
}

extern "C" void kernel_launch(void* const* d_in, const int* in_sizes, int n_in,
                              void* d_out, int out_size, void* d_ws, size_t ws_size,
                              hipStream_t stream) {
  (void)in_sizes; (void)n_in; (void)out_size; (void)ws_size;
  const float* q    = (const float*)d_in[0];
  const float* k    = (const float*)d_in[1];
  const float* Wq   = (const float*)d_in[2];
  const float* bq   = (const float*)d_in[3];
  const float* Wk   = (const float*)d_in[4];
  const float* bk   = (const float*)d_in[5];
  const float* Wv   = (const float*)d_in[6];
  const float* bv   = (const float*)d_in[7];
  const float* gq   = (const float*)d_in[8];
  const float* betaq= (const float*)d_in[9];
  const float* gk   = (const float*)d_in[10];
  const float* betak= (const float*)d_in[11];
  const float* gv   = (const float*)d_in[12];
  const float* betav= (const float*)d_in[13];
  const float* Wp   = (const float*)d_in[14];
  const float* bp   = (const float*)d_in[15];

  float* out = (float*)d_out;
  float* att = out + (size_t)CB * CNQ * CD;   // [B,2,NQ,NK]
  char* ws = (char*)d_ws;
  const size_t MB = 1ull << 20;

  // workspace layout (105 MB, with region reuse)
  f16* q16   = (f16*)(ws);                     // 16MB, dead after GEMM-q
  f16* k16   = (f16*)(ws + 16 * MB);           // 16MB, dead after GEMM-v
  f16* a1b   = (f16*)(ws);                     // 32MB, lives after q16/k16 die
  f16* a2b   = (f16*)(ws);                     // 32MB, lives after a1b dies
  f16* WqT   = (f16*)(ws + 32 * MB);           // 2MB each
  f16* WkT   = (f16*)(ws + 34 * MB);
  f16* WvT   = (f16*)(ws + 36 * MB);
  f16* posb  = (f16*)(ws + 38 * MB);           // 256KB
  f16* posTb = (f16*)(ws + 38 * MB + 256 * 1024); // 256KB
  float* xw  = (float*)(ws + 38 * MB + 512 * 1024); // 2MB  [8192][64]
  f16* tmp   = (f16*)(ws + 41 * MB);           // 16MB preLN scratch (x3)
  f16* vnT   = (f16*)(ws + 41 * MB);           // reuses tmp after LNs done
  f16* qn    = (f16*)(ws + 57 * MB);           // 16MB
  f16* kn    = (f16*)(ws + 73 * MB);           // 16MB
  f16* vn    = (f16*)(ws + 89 * MB);           // 16MB (ends 105MB)

  pos_kernel<<<(CP * CNK) / 256, 256, 0, stream>>>(posb, posTb);
  cvt_kernel<<<(CB * CNQ * CD / 4) / 256, 256, 0, stream>>>(q, q16);
  cvt_kernel<<<(CB * CNK * CD / 4) / 256, 256, 0, stream>>>(k, k16);
  cvtWT_kernel<<<dim3(16, 16), 256, 0, stream>>>(Wq, WqT);
  cvtWT_kernel<<<dim3(16, 16), 256, 0, stream>>>(Wk, WkT);
  cvtWT_kernel<<<dim3(16, 16), 256, 0, stream>>>(Wv, WvT);

  dim3 gIn(CB * CNQ / 128, CD / 128, 1);
  gemm_nt<128, 128, 1><<<gIn, 256, 0, stream>>>(q16, WqT, tmp, CD, CD, CD, CD, 0, 0, 0, 1.f);
  ln_kernel<<<CB * CNQ, 256, 0, stream>>>(tmp, bq, gq, betaq, qn);
  gemm_nt<128, 128, 1><<<gIn, 256, 0, stream>>>(k16, WkT, tmp, CD, CD, CD, CD, 0, 0, 0, 1.f);
  ln_kernel<<<CB * CNK, 256, 0, stream>>>(tmp, bk, gk, betak, kn);
  gemm_nt<128, 128, 1><<<gIn, 256, 0, stream>>>(k16, WvT, tmp, CD, CD, CD, CD, 0, 0, 0, 1.f);
  ln_kernel<<<CB * CNK, 256, 0, stream>>>(tmp, bv, gv, betav, vn);
  transpose_kernel<<<dim3(CNK / 64, CD / 64, CB), 256, 0, stream>>>(vn, vnT);

  // s1 = qn.kn^T / 32 -> att head-0 slots (raw), then softmax in place + f16 copy
  dim3 gS1(CNQ / 128, CNK / 128, CB);
  gemm_nt<128, 128, 0><<<gS1, 256, 0, stream>>>(qn, kn, att, CD, CD, CD, CNK,
      (size_t)CNQ * CD, (size_t)CNK * CD, 2ull * CNQ * CNK, 0.03125f);
  softmax_kernel<<<CB * CNQ, 256, 0, stream>>>(att, a1b, 0);

  // x = a1 @ pos  ([8192,2048] x [2048,64])
  gemm_nt<128, 64, 0><<<dim3(CB * CNQ / 128, 1, 1), 256, 0, stream>>>(
      a1b, posTb, xw, CNK, CNK, CNK, CP, 0, 0, 0, 1.f);
  // x' = x@Wp+bp; s2 -> att head-1 slots (raw), then softmax
  attn2_kernel<<<CB * CNQ / 16, 64, 0, stream>>>(xw, Wp, bp, posb, att);
  softmax_kernel<<<CB * CNQ, 256, 0, stream>>>(att, a2b, 1);

  // out = a2 @ vn  (NT against vnT)
  dim3 gO(CNQ / 128, CD / 128, CB);
  gemm_nt<128, 128, 0><<<gO, 256, 0, stream>>>(a2b, vnT, out, CNK, CNK, CNK, CD,
      (size_t)CNQ * CNK, (size_t)CD * CNK, (size_t)CNQ * CD, 1.f);
}

// Round 2
// 368.489 us; speedup vs baseline: 1.1121x; 1.1121x over previous
//
#include <hip/hip_runtime.h>
#include <math.h>
#include <stdint.h>

// BlindCrossAttention on MI355X (gfx950).
// Round 2: 8-phase-style 256-tile GEMM (T2 swizzle + prefetch + setprio + XCD swizzle),
// fused Wk|Wv GEMM, in-place LayerNorm.

typedef _Float16 f16;
typedef _Float16 f16x4 __attribute__((ext_vector_type(4)));
typedef _Float16 f16x8 __attribute__((ext_vector_type(8)));
typedef float f32x4 __attribute__((ext_vector_type(4)));

static constexpr int CB  = 4;
static constexpr int CNQ = 2048;
static constexpr int CNK = 2048;
static constexpr int CD  = 1024;
static constexpr int CP  = 64;

// ---------- async global->LDS, 16B/lane ----------
static __device__ __forceinline__ void async16(const f16* gp, f16* lp) {
  __builtin_amdgcn_global_load_lds(
      (const __attribute__((address_space(1))) void*)(uintptr_t)gp,
      (__attribute__((address_space(3))) void*)(uint32_t)(uintptr_t)lp,
      16, 0, 0);
}

// ---------- pos table ----------
__global__ __launch_bounds__(256) void pos_kernel(f16* __restrict__ posb,
                                                  f16* __restrict__ posTb) {
  int tid = blockIdx.x * 256 + threadIdx.x;
  int p = tid >> 11;
  int j = tid & (CNK - 1);
  int i = p & 31;
  float ph = (float)j * powf(10000.0f, -(float)i * (1.0f / 32.0f));
  float v = (p < 32) ? sinf(ph) : cosf(ph);
  posb[j * CP + p]   = (f16)v;
  posTb[p * CNK + j] = (f16)v;
}

// ---------- f32 -> f16 ----------
__global__ __launch_bounds__(256) void cvt_kernel(const float* __restrict__ in,
                                                  f16* __restrict__ out) {
  int tid = blockIdx.x * 256 + threadIdx.x;
  float4 v = reinterpret_cast<const float4*>(in)[tid];
  f16x4 o = {(f16)v.x, (f16)v.y, (f16)v.z, (f16)v.w};
  reinterpret_cast<f16x4*>(out)[tid] = o;
}

// ---------- W[k][n] f32 -> WT[n][k] f16 ----------
__global__ __launch_bounds__(256) void cvtWT_kernel(const float* __restrict__ W,
                                                    f16* __restrict__ WT) {
  __shared__ float t[64][65];
  int k0 = blockIdx.x * 64, n0 = blockIdx.y * 64;
  int tx = threadIdx.x & 63, ty = threadIdx.x >> 6;
#pragma unroll
  for (int i = 0; i < 16; i++)
    t[ty + 4 * i][tx] = W[(size_t)(k0 + ty + 4 * i) * CD + n0 + tx];
  __syncthreads();
#pragma unroll
  for (int i = 0; i < 16; i++)
    WT[(size_t)(n0 + 4 * i + ty) * CD + k0 + tx] = (f16)t[tx][ty + 4 * i];
}

// ---------- f16 transpose with input ld: out[b][d][n] = in[b][n][d] ----------
__global__ __launch_bounds__(256) void transpose_kernel(const f16* __restrict__ in,
                                                        f16* __restrict__ out,
                                                        int ldi) {
  __shared__ f16 t[64][65];
  int n0 = blockIdx.x * 64, d0 = blockIdx.y * 64;
  size_t ibase = (size_t)blockIdx.z * CNK * ldi;
  size_t obase = (size_t)blockIdx.z * CNK * CD;
  int tx = threadIdx.x & 63, ty = threadIdx.x >> 6;
#pragma unroll
  for (int i = 0; i < 16; i++)
    t[ty + 4 * i][tx] = in[ibase + (size_t)(n0 + ty + 4 * i) * ldi + d0 + tx];
  __syncthreads();
#pragma unroll
  for (int i = 0; i < 16; i++)
    out[obase + (size_t)(d0 + ty + 4 * i) * CNK + n0 + tx] = t[tx][ty + 4 * i];
}

// ================= 8-phase-style 256-tile NT GEMM =================
// C[m,n] = scale * sum_k A[m,k]*Bt[n,k].  8 waves (2x4), BK=64, dbuf LDS,
// T2 XOR-swizzle via pre-swizzled global source, prefetch-next-tile during
// compute phases, per-phase s_barrier pairs + setprio, per-tile vmcnt drain.
template <int BM, int BN, int EPI>  // EPI 0: f32*scale, 1: f16
__global__ __launch_bounds__(512, 2) void gemm8(
    const f16* __restrict__ A, const f16* __restrict__ Bt, void* __restrict__ C,
    int K, int lda, int ldb, int ldc, size_t sA, size_t sB, size_t sC,
    float scale, int gx, int gy) {
  constexpr int FM = BM / 32;          // per-wave m frags (wave owns BM/2 rows)
  constexpr int FN = BN / 64;          // per-wave n frags (wave owns BN/4 cols)
  constexpr int TI = (BM + BN) / 64;   // stage issues per K-tile (8KB each)
  __shared__ __attribute__((aligned(16))) f16 sm[2][(BM + BN) * 64];

  // T1: bijective chunked XCD swizzle (gridDim.x % 8 == 0 for all our launches)
  const int nwg = gridDim.x;
  const int qch = nwg >> 3;
  const int swz = (blockIdx.x & 7) * qch + (blockIdx.x >> 3);
  const int bz = swz / (gx * gy);
  const int rem = swz - bz * gx * gy;
  const int by = rem / gx;
  const int bx = rem - by * gx;
  const int m0 = bx * BM, n0 = by * BN;

  const f16* Ab = A + sA * bz;
  const f16* Bb = Bt + sB * bz;
  const int tid = threadIdx.x;
  const int lane = tid & 63, wid = tid >> 6;
  const int wr = wid >> 2, wc = wid & 3;
  const int lrow = lane & 15, kg = lane >> 4;

  // stage issue i of K-tile kt into buffer buf. LDS layout is XOR-swizzled
  // (byte ^= ((row&7)<<4)); global_load_lds writes linearly, so the GLOBAL
  // source column is pre-swizzled (m173/m201 both-sides pattern).
  auto stage = [&](int i, int kt, int buf) {
    const int s = i * 512 + tid;          // 16B slot
    const int row = s >> 3;               // 0..BM+BN-1
    const int cb = (s & 7) << 4;          // byte col in row (0..112)
    const int scb = cb ^ ((row & 7) << 4);
    const f16* src = (i < BM / 64)
        ? Ab + (size_t)(m0 + row) * lda + kt * 64 + (scb >> 1)
        : Bb + (size_t)(n0 + row - BM) * ldb + kt * 64 + (scb >> 1);
    async16(src, &sm[buf][(size_t)s * 8]);
  };

  f32x4 acc[FM][FN] = {};
  const int NT = K >> 6;

#pragma unroll
  for (int i = 0; i < TI; i++) stage(i, 0, 0);
  asm volatile("s_waitcnt vmcnt(0)" ::: "memory");
  __builtin_amdgcn_s_barrier();

  for (int t = 0; t < NT; ++t) {
    const int cur = t & 1;
    const bool pf = (t + 1 < NT);
    const f16* smA = sm[cur];
    const f16* smB = sm[cur] + BM * 64;
    f16x8 bf[2][FN];
#pragma unroll
    for (int p = 0; p < 4; ++p) {        // 4 phases per K-tile
      const int kk = p >> 1, mh = p & 1;
      if (pf) {
#pragma unroll
        for (int i = (p * TI) / 4; i < ((p + 1) * TI) / 4; ++i)
          stage(i, t + 1, cur ^ 1);
      }
      const int Cb = kk * 64 + kg * 16;  // byte col of this kk/kg fragment
      f16x8 af[FM / 2];
#pragma unroll
      for (int m = 0; m < FM / 2; ++m) {
        const int ar = wr * (BM / 2) + mh * (BM / 4) + m * 16 + lrow;
        af[m] = *reinterpret_cast<const f16x8*>(
            &smA[ar * 64 + ((Cb ^ ((ar & 7) << 4)) >> 1)]);
      }
      if (mh == 0) {
#pragma unroll
        for (int n = 0; n < FN; ++n) {
          const int br = wc * (BN / 4) + n * 16 + lrow;
          bf[kk][n] = *reinterpret_cast<const f16x8*>(
              &smB[br * 64 + ((Cb ^ ((br & 7) << 4)) >> 1)]);
        }
      }
      __builtin_amdgcn_s_barrier();
      __builtin_amdgcn_s_setprio(1);
#pragma unroll
      for (int m = 0; m < FM / 2; ++m)
#pragma unroll
        for (int n = 0; n < FN; ++n)
          acc[mh * (FM / 2) + m][n] = __builtin_amdgcn_mfma_f32_16x16x32_f16(
              af[m], bf[kk][n], acc[mh * (FM / 2) + m][n], 0, 0, 0);
      __builtin_amdgcn_s_setprio(0);
      if (p < 3) __builtin_amdgcn_s_barrier();
    }
    // per-tile counted drain: only next-tile loads are outstanding here
    asm volatile("s_waitcnt vmcnt(0)" ::: "memory");
    __builtin_amdgcn_s_barrier();
  }

  // C/D layout: col = lane&15, row = (lane>>4)*4 + r
  const int crow = m0 + wr * (BM / 2) + (lane >> 4) * 4;
  const int ccol = n0 + wc * (BN / 4) + lrow;
#pragma unroll
  for (int mg = 0; mg < FM; mg++)
#pragma unroll
    for (int n = 0; n < FN; n++)
#pragma unroll
      for (int r = 0; r < 4; r++) {
        size_t off = sC * bz + (size_t)(crow + mg * 16 + r) * ldc + ccol + n * 16;
        if (EPI == 0) ((float*)C)[off] = acc[mg][n][r] * scale;
        else          ((f16*)C)[off]   = (f16)acc[mg][n][r];
      }
}

// ---------- small m97-style NT GEMM (kept for x = a1 @ pos) ----------
template <int BM, int BN, int EPI>
__global__ __launch_bounds__(256) void gemm_nt(
    const f16* __restrict__ A, const f16* __restrict__ Bt, void* __restrict__ C,
    int K, int lda, int ldb, int ldc,
    size_t sA, size_t sB, size_t sC, float scale) {
  constexpr int FM = BM / 32;
  constexpr int FN = BN / 32;
  constexpr int NA = BM / 16, NTOT = NA + BN / 16;
  __shared__ __attribute__((aligned(16))) f16 As[BM * 32];
  __shared__ __attribute__((aligned(16))) f16 Bs[BN * 32];

  const int lane = threadIdx.x & 63;
  const int wave = threadIdx.x >> 6;
  const int wr = wave >> 1, wc = wave & 1;
  const int m0 = blockIdx.x * BM, n0 = blockIdx.y * BN;
  A += sA * blockIdx.z;
  Bt += sB * blockIdx.z;

  const int srow = lane >> 2;
  const int scol = (lane & 3) * 8;
  const int lrow = lane & 15;
  const int kg = lane >> 4;

  f32x4 acc[FM][FN] = {};

  for (int k0 = 0; k0 < K; k0 += 32) {
    __syncthreads();
#pragma unroll
    for (int i = wave; i < NTOT; i += 4) {
      if (i < NA)
        async16(A + (size_t)(m0 + i * 16 + srow) * lda + k0 + scol, &As[i * 512]);
      else
        async16(Bt + (size_t)(n0 + (i - NA) * 16 + srow) * ldb + k0 + scol,
                &Bs[(i - NA) * 512]);
    }
    __syncthreads();

    f16x8 af[FM], bfr[FN];
#pragma unroll
    for (int m = 0; m < FM; m++)
      af[m] = *reinterpret_cast<const f16x8*>(
          &As[(wr * (BM / 2) + m * 16 + lrow) * 32 + kg * 8]);
#pragma unroll
    for (int n = 0; n < FN; n++)
      bfr[n] = *reinterpret_cast<const f16x8*>(
          &Bs[(wc * (BN / 2) + n * 16 + lrow) * 32 + kg * 8]);
#pragma unroll
    for (int m = 0; m < FM; m++)
#pragma unroll
      for (int n = 0; n < FN; n++)
        acc[m][n] = __builtin_amdgcn_mfma_f32_16x16x32_f16(af[m], bfr[n], acc[m][n], 0, 0, 0);
  }

  const int crow = m0 + wr * (BM / 2) + (lane >> 4) * 4;
  const int ccol = n0 + wc * (BN / 2) + (lane & 15);
#pragma unroll
  for (int m = 0; m < FM; m++)
#pragma unroll
    for (int n = 0; n < FN; n++)
#pragma unroll
      for (int r = 0; r < 4; r++) {
        size_t off = sC * blockIdx.z + (size_t)(crow + m * 16 + r) * ldc + ccol + n * 16;
        if (EPI == 0) ((float*)C)[off] = acc[m][n][r] * scale;
        else          ((f16*)C)[off]   = (f16)acc[m][n][r];
      }
}

// ---------- in-place LayerNorm over 1024 cols at (row*ld + coff) ----------
__global__ __launch_bounds__(256) void ln_kernel(
    f16* __restrict__ buf, int ld, int coff, const float* __restrict__ bias,
    const float* __restrict__ g, const float* __restrict__ beta) {
  __shared__ float rs_[4], rq_[4];
  const size_t row = blockIdx.x;
  const int t = threadIdx.x;
  f16* rp = buf + row * ld + coff;
  f16x4 v = *reinterpret_cast<const f16x4*>(rp + t * 4);
  float y[4], s = 0.f, q = 0.f;
#pragma unroll
  for (int j = 0; j < 4; j++) {
    y[j] = (float)v[j] + bias[t * 4 + j];
    s += y[j]; q += y[j] * y[j];
  }
#pragma unroll
  for (int o = 32; o; o >>= 1) { s += __shfl_xor(s, o); q += __shfl_xor(q, o); }
  if ((t & 63) == 0) { rs_[t >> 6] = s; rq_[t >> 6] = q; }
  __syncthreads();
  s = rs_[0] + rs_[1] + rs_[2] + rs_[3];
  q = rq_[0] + rq_[1] + rq_[2] + rq_[3];
  const float mean = s * (1.0f / CD);
  const float var  = q * (1.0f / CD) - mean * mean;
  const float rstd = rsqrtf(var + 1e-5f);
  f16x4 o;
#pragma unroll
  for (int j = 0; j < 4; j++) {
    int c = t * 4 + j;
    o[j] = (f16)((y[j] - mean) * rstd * g[c] + beta[c]);
  }
  *reinterpret_cast<f16x4*>(rp + t * 4) = o;
}

// ---------- row softmax in place on att slot `head`, plus f16 copy ----------
__global__ __launch_bounds__(256) void softmax_kernel(float* __restrict__ att,
                                                      f16* __restrict__ ob,
                                                      int head) {
  __shared__ float red[4];
  const int row = blockIdx.x;
  const int b = row >> 11, n = row & (CNQ - 1);
  float* rp = att + ((size_t)((b << 1) + head) * CNQ + n) * CNK;
  const int t = threadIdx.x;
  float4 v0 = reinterpret_cast<float4*>(rp)[t * 2];
  float4 v1 = reinterpret_cast<float4*>(rp)[t * 2 + 1];
  float m = fmaxf(fmaxf(fmaxf(v0.x, v0.y), fmaxf(v0.z, v0.w)),
                  fmaxf(fmaxf(v1.x, v1.y), fmaxf(v1.z, v1.w)));
#pragma unroll
  for (int o = 32; o; o >>= 1) m = fmaxf(m, __shfl_xor(m, o));
  if ((t & 63) == 0) red[t >> 6] = m;
  __syncthreads();
  m = fmaxf(fmaxf(red[0], red[1]), fmaxf(red[2], red[3]));
  float e[8] = {__expf(v0.x - m), __expf(v0.y - m), __expf(v0.z - m), __expf(v0.w - m),
                __expf(v1.x - m), __expf(v1.y - m), __expf(v1.z - m), __expf(v1.w - m)};
  float s = ((e[0] + e[1]) + (e[2] + e[3])) + ((e[4] + e[5]) + (e[6] + e[7]));
#pragma unroll
  for (int o = 32; o; o >>= 1) s += __shfl_xor(s, o);
  __syncthreads();
  if ((t & 63) == 0) red[t >> 6] = s;
  __syncthreads();
  s = red[0] + red[1] + red[2] + red[3];
  const float inv = 1.0f / s;
  float4 w0 = {e[0] * inv, e[1] * inv, e[2] * inv, e[3] * inv};
  float4 w1 = {e[4] * inv, e[5] * inv, e[6] * inv, e[7] * inv};
  reinterpret_cast<float4*>(rp)[t * 2]     = w0;
  reinterpret_cast<float4*>(rp)[t * 2 + 1] = w1;
  f16x8 h = {(f16)w0.x, (f16)w0.y, (f16)w0.z, (f16)w0.w,
             (f16)w1.x, (f16)w1.y, (f16)w1.z, (f16)w1.w};
  *reinterpret_cast<f16x8*>(ob + (size_t)row * CNK + t * 8) = h;
}

// ---------- attn2: x' = x@Wp + bp; raw s2 = x'.pos^T / 8 into att head-1 ----------
__global__ __launch_bounds__(64) void attn2_kernel(
    const float* __restrict__ x, const float* __restrict__ Wp,
    const float* __restrict__ bp, const f16* __restrict__ posb,
    float* __restrict__ att) {
  __shared__ float xs[16 * 64];
  __shared__ float Wps[64 * 64];
  __shared__ __attribute__((aligned(16))) f16 xpb[16 * 64];
  const int l = threadIdx.x;
  const int r0 = blockIdx.x * 16;
#pragma unroll
  for (int i = 0; i < 16; i++) xs[i * 64 + l] = x[(size_t)(r0 + i) * CP + l];
#pragma unroll 8
  for (int i = 0; i < 64; i++) Wps[i * 64 + l] = Wp[i * 64 + l];
  const float bpl = bp[l];
  __syncthreads();
#pragma unroll 2
  for (int i = 0; i < 16; i++) {
    float a = bpl;
#pragma unroll 8
    for (int p = 0; p < 64; p++) a = fmaf(xs[i * 64 + p], Wps[p * 64 + l], a);
    xpb[i * 64 + l] = (f16)a;
  }
  __syncthreads();
  const f16x8 af0 = *reinterpret_cast<const f16x8*>(&xpb[(l & 15) * 64 + (l >> 4) * 8]);
  const f16x8 af1 = *reinterpret_cast<const f16x8*>(&xpb[(l & 15) * 64 + 32 + (l >> 4) * 8]);
  const int b = r0 >> 11, nloc = r0 & (CNQ - 1);
  float* ob = att + ((size_t)((b << 1) + 1) * CNQ + nloc) * CNK;
  for (int jt = 0; jt < CNK / 64; jt++) {
#pragma unroll
    for (int q4 = 0; q4 < 4; q4++) {
      const int j = jt * 64 + q4 * 16 + (l & 15);
      const f16* pp = posb + (size_t)j * CP + (l >> 4) * 8;
      f16x8 b0 = *reinterpret_cast<const f16x8*>(pp);
      f16x8 b1 = *reinterpret_cast<const f16x8*>(pp + 32);
      f32x4 c = {};
      c = __builtin_amdgcn_mfma_f32_16x16x32_f16(af0, b0, c, 0, 0, 0);
      c = __builtin_amdgcn_mfma_f32_16x16x32_f16(af1, b1, c, 0, 0, 0);
#pragma unroll
      for (int r = 0; r < 4; r++)
        ob[(size_t)((l >> 4) * 4 + r) * CNK + j] = c[r] * 0.125f;
    }
  }
}

extern "C" void kernel_launch(void* const* d_in, const int* in_sizes, int n_in,
                              void* d_out, int out_size, void* d_ws, size_t ws_size,
                              hipStream_t stream) {
  (void)in_sizes; (void)n_in; (void)out_size; (void)ws_size;
  const float* q    = (const float*)d_in[0];
  const float* k    = (const float*)d_in[1];
  const float* Wq   = (const float*)d_in[2];
  const float* bq   = (const float*)d_in[3];
  const float* Wk   = (const float*)d_in[4];
  const float* bk   = (const float*)d_in[5];
  const float* Wv   = (const float*)d_in[6];
  const float* bv   = (const float*)d_in[7];
  const float* gq   = (const float*)d_in[8];
  const float* betaq= (const float*)d_in[9];
  const float* gk   = (const float*)d_in[10];
  const float* betak= (const float*)d_in[11];
  const float* gv   = (const float*)d_in[12];
  const float* betav= (const float*)d_in[13];
  const float* Wp   = (const float*)d_in[14];
  const float* bp   = (const float*)d_in[15];

  float* out = (float*)d_out;
  float* att = out + (size_t)CB * CNQ * CD;   // [B,2,NQ,NK]
  char* ws = (char*)d_ws;
  const size_t MB = 1ull << 20;

  // workspace (105 MB, heavy reuse):
  f16* q16   = (f16*)(ws);                     // 0-16, dead after q-GEMM
  f16* k16   = (f16*)(ws + 16 * MB);           // 16-32, dead after kv-GEMM
  f16* a1b   = (f16*)(ws);                     // 0-32, after q16/k16 die
  f16* a2b   = (f16*)(ws);                     // 0-32, after a1b dies
  f16* WqT   = (f16*)(ws + 32 * MB);           // 2MB
  f16* WkvT  = (f16*)(ws + 34 * MB);           // 4MB [2048][1024]: Wk rows 0-1023, Wv 1024-2047
  f16* posb  = (f16*)(ws + 38 * MB);           // 256KB
  f16* posTb = (f16*)(ws + 38 * MB + 256 * 1024);
  float* xw  = (float*)(ws + 38 * MB + 512 * 1024); // 2MB
  f16* tmpq  = (f16*)(ws + 41 * MB);           // 16MB; qn in place; dead after s1
  f16* tmp2  = (f16*)(ws + 57 * MB);           // 32MB [8192][2048]; kn|vn in place
  f16* vnT   = (f16*)(ws + 89 * MB);           // 16MB (ends 105MB)
  f16* qn = tmpq;
  f16* kn = tmp2;            // ld 2048, cols 0-1023
  f16* vn = tmp2 + 1024;     // ld 2048, cols 1024-2047

  pos_kernel<<<(CP * CNK) / 256, 256, 0, stream>>>(posb, posTb);
  cvt_kernel<<<(CB * CNQ * CD / 4) / 256, 256, 0, stream>>>(q, q16);
  cvt_kernel<<<(CB * CNK * CD / 4) / 256, 256, 0, stream>>>(k, k16);
  cvtWT_kernel<<<dim3(16, 16), 256, 0, stream>>>(Wq, WqT);
  cvtWT_kernel<<<dim3(16, 16), 256, 0, stream>>>(Wk, WkvT);
  cvtWT_kernel<<<dim3(16, 16), 256, 0, stream>>>(Wv, WkvT + 1024 * 1024);

  // q@Wq -> tmpq (f16), LN in place -> qn
  gemm8<256, 128, 1><<<256, 512, 0, stream>>>(q16, WqT, tmpq, CD, CD, CD, CD,
                                              0, 0, 0, 1.f, 32, 8);
  ln_kernel<<<CB * CNQ, 256, 0, stream>>>(tmpq, CD, 0, bq, gq, betaq);
  // k@[Wk|Wv] -> tmp2 (f16, [8192][2048]), LN both halves in place
  gemm8<256, 256, 1><<<256, 512, 0, stream>>>(k16, WkvT, tmp2, CD, CD, CD, 2048,
                                              0, 0, 0, 1.f, 32, 8);
  ln_kernel<<<CB * CNK, 256, 0, stream>>>(tmp2, 2048, 0, bk, gk, betak);
  ln_kernel<<<CB * CNK, 256, 0, stream>>>(tmp2, 2048, 1024, bv, gv, betav);
  transpose_kernel<<<dim3(CNK / 64, CD / 64, CB), 256, 0, stream>>>(vn, vnT, 2048);

  // s1 = qn.kn^T / 32 -> att head-0 (raw), softmax in place + f16 copy
  gemm8<256, 256, 0><<<256, 512, 0, stream>>>(qn, kn, att, CD, CD, 2048, CNK,
      (size_t)CNQ * CD, (size_t)CNK * 2048, 2ull * CNQ * CNK, 0.03125f, 8, 8);
  softmax_kernel<<<CB * CNQ, 256, 0, stream>>>(att, a1b, 0);

  // x = a1 @ pos
  gemm_nt<64, 64, 0><<<dim3(CB * CNQ / 64, 1, 1), 256, 0, stream>>>(
      a1b, posTb, xw, CNK, CNK, CNK, CP, 0, 0, 0, 1.f);
  attn2_kernel<<<CB * CNQ / 16, 64, 0, stream>>>(xw, Wp, bp, posb, att);
  softmax_kernel<<<CB * CNQ, 256, 0, stream>>>(att, a2b, 1);

  // out = a2 @ vn  (NT against vnT)
  gemm8<256, 128, 0><<<256, 512, 0, stream>>>(a2b, vnT, out, CNK, CNK, CNK, CD,
      (size_t)CNQ * CNK, (size_t)CD * CNK, (size_t)CNQ * CD, 1.f, 8, 8);
}

// Round 4
// 335.131 us; speedup vs baseline: 1.2228x; 1.0995x over previous
//
#include <hip/hip_runtime.h>
#include <math.h>
#include <stdint.h>

// BlindCrossAttention on MI355X (gfx950).
// Round 4 = Round 3 with two fixes:
//  (1) kv GEMM launch gy=8 (was 4: half of tmp2 cols never written -> vn poison)
//  (2) epilogue LDS write->read sync uses __syncthreads() (raw s_barrier does
//      not drain lgkmcnt -> cross-wave LDS race)

typedef _Float16 f16;
typedef _Float16 f16x4 __attribute__((ext_vector_type(4)));
typedef _Float16 f16x8 __attribute__((ext_vector_type(8)));
typedef float f32x4 __attribute__((ext_vector_type(4)));

static constexpr int CB  = 4;
static constexpr int CNQ = 2048;
static constexpr int CNK = 2048;
static constexpr int CD  = 1024;
static constexpr int CP  = 64;

// ---------- async global->LDS, 16B/lane ----------
static __device__ __forceinline__ void async16(const f16* gp, f16* lp) {
  __builtin_amdgcn_global_load_lds(
      (const __attribute__((address_space(1))) void*)(uintptr_t)gp,
      (__attribute__((address_space(3))) void*)(uint32_t)(uintptr_t)lp,
      16, 0, 0);
}

// ---------- pos table ----------
__global__ __launch_bounds__(256) void pos_kernel(f16* __restrict__ posb,
                                                  f16* __restrict__ posTb) {
  int tid = blockIdx.x * 256 + threadIdx.x;
  int p = tid >> 11;
  int j = tid & (CNK - 1);
  int i = p & 31;
  float ph = (float)j * powf(10000.0f, -(float)i * (1.0f / 32.0f));
  float v = (p < 32) ? sinf(ph) : cosf(ph);
  posb[j * CP + p]   = (f16)v;
  posTb[p * CNK + j] = (f16)v;
}

// ---------- f32 -> f16 for q and k in one launch ----------
__global__ __launch_bounds__(256) void cvt2_kernel(const float* __restrict__ a,
                                                   const float* __restrict__ b,
                                                   f16* __restrict__ oa,
                                                   f16* __restrict__ ob) {
  const int NF4 = CB * CNQ * CD / 4;
  int tid = blockIdx.x * 256 + threadIdx.x;
  const float* src = (tid < NF4) ? a : b;
  f16* dst = (tid < NF4) ? oa : ob;
  int i = (tid < NF4) ? tid : tid - NF4;
  float4 v = reinterpret_cast<const float4*>(src)[i];
  f16x4 o = {(f16)v.x, (f16)v.y, (f16)v.z, (f16)v.w};
  reinterpret_cast<f16x4*>(dst)[i] = o;
}

// ---------- W[k][n] f32 -> WT[n][k] f16, all three weights (z) ----------
__global__ __launch_bounds__(256) void cvtWT_kernel(
    const float* __restrict__ Wq, const float* __restrict__ Wk,
    const float* __restrict__ Wv, f16* __restrict__ WqT, f16* __restrict__ WkvT) {
  __shared__ float t[64][65];
  const float* W = (blockIdx.z == 0) ? Wq : (blockIdx.z == 1) ? Wk : Wv;
  f16* WT = (blockIdx.z == 0) ? WqT : (blockIdx.z == 1) ? WkvT : WkvT + 1024 * 1024;
  int k0 = blockIdx.x * 64, n0 = blockIdx.y * 64;
  int tx = threadIdx.x & 63, ty = threadIdx.x >> 6;
#pragma unroll
  for (int i = 0; i < 16; i++)
    t[ty + 4 * i][tx] = W[(size_t)(k0 + ty + 4 * i) * CD + n0 + tx];
  __syncthreads();
#pragma unroll
  for (int i = 0; i < 16; i++)
    WT[(size_t)(n0 + 4 * i + ty) * CD + k0 + tx] = (f16)t[tx][ty + 4 * i];
}

// ---------- f16 transpose: out[b][d][n] = in[b][n][d] ----------
__global__ __launch_bounds__(256) void transpose_kernel(const f16* __restrict__ in,
                                                        f16* __restrict__ out,
                                                        int ldi) {
  __shared__ f16 t[64][65];
  int n0 = blockIdx.x * 64, d0 = blockIdx.y * 64;
  size_t ibase = (size_t)blockIdx.z * CNK * ldi;
  size_t obase = (size_t)blockIdx.z * CNK * CD;
  int tx = threadIdx.x & 63, ty = threadIdx.x >> 6;
#pragma unroll
  for (int i = 0; i < 16; i++)
    t[ty + 4 * i][tx] = in[ibase + (size_t)(n0 + ty + 4 * i) * ldi + d0 + tx];
  __syncthreads();
#pragma unroll
  for (int i = 0; i < 16; i++)
    out[obase + (size_t)(d0 + ty + 4 * i) * CNK + n0 + tx] = t[tx][ty + 4 * i];
}

// ================= counted-pipeline 256-tile NT GEMM =================
// C[m,n] = scale * sum_k A[m,k]*Bt[n,k].  8 waves (2x4), BK=64, dbuf LDS,
// T2 XOR-swizzle (pre-swizzled global source), FULL next-tile issue at tile
// head + counted vmcnt(TI), per-phase barrier pairs + setprio.
// EPI 1: f16 store.  EPI 2: exp()->f16 store + per-coltile row partial sums
// (aux = float PS[gy][CB*gx*BM]).  EPI 3: f32 store scaled by aux=inv[row].
template <int BM, int BN, int EPI>
__global__ __launch_bounds__(512) void gemm8(
    const f16* __restrict__ A, const f16* __restrict__ Bt, void* __restrict__ C,
    int K, int lda, int ldb, int ldc, size_t sA, size_t sB, size_t sC,
    float scale, int gx, int gy, void* __restrict__ aux) {
  constexpr int FM = BM / 32;          // wave rows/16 (wave owns BM/2 rows)
  constexpr int FN = BN / 64;          // wave cols/16 (wave owns BN/4 cols)
  constexpr int MH = (FN == 4) ? 2 : 1;
  constexpr int FMC = FM / MH;
  constexpr int TI = (BM + BN) / 64;   // stage chunks per K-tile
  __shared__ __attribute__((aligned(16))) f16 sm[2][(BM + BN) * 64];
  __shared__ float psum[BM];

  // T1 bijective XCD swizzle (all launches: gridDim.x == gx*gy*z, %8==0)
  const int nwg = gridDim.x;
  const int qch = nwg >> 3;
  const int swz = (blockIdx.x & 7) * qch + (blockIdx.x >> 3);
  const int bz = swz / (gx * gy);
  const int rem = swz - bz * gx * gy;
  const int by = rem / gx;
  const int bx = rem - by * gx;
  const int m0 = bx * BM, n0 = by * BN;

  const f16* Ab = A + sA * bz;
  const f16* Bb = Bt + sB * bz;
  const int tid = threadIdx.x;
  const int lane = tid & 63, wid = tid >> 6;
  const int wr = wid >> 2, wc = wid & 3;
  const int lrow = lane & 15, kg = lane >> 4;

  auto stage = [&](int i, int kt, int buf) {
    const int s = i * 512 + tid;          // 16B slot
    const int row = s >> 3;
    const int cb = (s & 7) << 4;
    const int scb = cb ^ ((row & 7) << 4);  // pre-swizzled global source col
    const f16* src = (i < BM / 64)
        ? Ab + (size_t)(m0 + row) * lda + kt * 64 + (scb >> 1)
        : Bb + (size_t)(n0 + row - BM) * ldb + kt * 64 + (scb >> 1);
    async16(src, &sm[buf][(size_t)s * 8]);
  };

  f32x4 acc[FM][FN] = {};
  const int NT = K >> 6;

#pragma unroll
  for (int i = 0; i < TI; i++) stage(i, 0, 0);

  for (int t = 0; t < NT; ++t) {
    const int cur = t & 1;
    if (t + 1 < NT) {
#pragma unroll
      for (int i = 0; i < TI; i++) stage(i, t + 1, cur ^ 1);
      if constexpr (TI == 8) asm volatile("s_waitcnt vmcnt(8)" ::: "memory");
      else                   asm volatile("s_waitcnt vmcnt(6)" ::: "memory");
    } else {
      asm volatile("s_waitcnt vmcnt(0)" ::: "memory");
    }
    __builtin_amdgcn_s_barrier();

    const f16* smA = sm[cur];
    const f16* smB = sm[cur] + BM * 64;
    f16x8 bf[2][FN];
#pragma unroll
    for (int p = 0; p < 2 * MH; ++p) {
      const int kk = p / MH, mh = p % MH;
      const int Cb = kk * 64 + kg * 16;
      f16x8 af[FMC];
#pragma unroll
      for (int m = 0; m < FMC; ++m) {
        const int ar = wr * (BM / 2) + mh * (FMC * 16) + m * 16 + lrow;
        af[m] = *reinterpret_cast<const f16x8*>(
            &smA[ar * 64 + ((Cb ^ ((ar & 7) << 4)) >> 1)]);
      }
      if (mh == 0) {
#pragma unroll
        for (int n = 0; n < FN; ++n) {
          const int br = wc * (BN / 4) + n * 16 + lrow;
          bf[kk][n] = *reinterpret_cast<const f16x8*>(
              &smB[br * 64 + ((Cb ^ ((br & 7) << 4)) >> 1)]);
        }
      }
      __builtin_amdgcn_s_barrier();
      __builtin_amdgcn_s_setprio(1);
#pragma unroll
      for (int m = 0; m < FMC; ++m)
#pragma unroll
        for (int n = 0; n < FN; ++n)
          acc[mh * FMC + m][n] = __builtin_amdgcn_mfma_f32_16x16x32_f16(
              af[m], bf[kk][n], acc[mh * FMC + m][n], 0, 0, 0);
      __builtin_amdgcn_s_setprio(0);
      __builtin_amdgcn_s_barrier();
    }
  }

  // ---------------- epilogues (LDS-staged, coalesced) ----------------
  const int rbase = wr * (BM / 2) + (lane >> 4) * 4;
  const int cbase = wc * (BN / 4) + lrow;

  if constexpr (EPI == 1 || EPI == 2) {
    f16* st = (f16*)sm;                  // BM x BN f16 tile (<=128KB)
    if constexpr (EPI == 2) { if (tid < BM) psum[tid] = 0.f; }
#pragma unroll
    for (int mg = 0; mg < FM; mg++)
#pragma unroll
      for (int n = 0; n < FN; n++)
#pragma unroll
        for (int r = 0; r < 4; r++) {
          float v = acc[mg][n][r];
          if constexpr (EPI == 2) v = __expf(v * scale);
          st[(rbase + mg * 16 + r) * BN + cbase + n * 16] = (f16)v;
        }
    __syncthreads();                     // drain LDS writes before cross-wave reads
    constexpr int CH = BM * BN / (512 * 8);   // 16B chunks per thread
    f16* Cp = (f16*)C + sC * bz;
#pragma unroll
    for (int c = 0; c < CH; c++) {
      const int idx = c * 512 + tid;
      const int row = idx / (BN / 8);
      const int cole = (idx % (BN / 8)) * 8;
      f16x8 v = *reinterpret_cast<const f16x8*>(&st[row * BN + cole]);
      *reinterpret_cast<f16x8*>(Cp + (size_t)(m0 + row) * ldc + n0 + cole) = v;
      if constexpr (EPI == 2) {
        float p = 0.f;
#pragma unroll
        for (int j = 0; j < 8; j++) p += (float)v[j];
#pragma unroll
        for (int o = 1; o < 32; o <<= 1) p += __shfl_xor(p, o);
        if ((lane & 31) == 0) atomicAdd(&psum[row], p);
      }
    }
    if constexpr (EPI == 2) {
      __syncthreads();                   // drain psum atomics
      if (tid < BM) {
        float* PS = (float*)aux;
        const int rowg = bz * (gx * BM) + m0 + tid;
        PS[(size_t)by * (CB * CNQ) + rowg] = psum[tid];
      }
    }
  } else {  // EPI == 3: f32, scaled by inv[globalrow]
    const float* inv = (const float*)aux;
    float* st = (float*)sm;              // (BM/2) x BN f32 per half-pass
    float* Cp = (float*)C + sC * bz;
#pragma unroll
    for (int half = 0; half < 2; half++) {
      __syncthreads();                   // prev reads done before overwrite
      if (wr == half) {
#pragma unroll
        for (int mg = 0; mg < FM; mg++)
#pragma unroll
          for (int r = 0; r < 4; r++) {
            const int rloc = (lane >> 4) * 4 + mg * 16 + r;
            const float iv = inv[bz * (gx * BM) + m0 + half * (BM / 2) + rloc];
#pragma unroll
            for (int n = 0; n < FN; n++)
              st[rloc * BN + cbase + n * 16] = acc[mg][n][r] * scale * iv;
          }
      }
      __syncthreads();                   // writes visible before reads
      constexpr int CH = (BM / 2) * BN / (512 * 4);
#pragma unroll
      for (int c = 0; c < CH; c++) {
        const int idx = c * 512 + tid;
        const int row = idx / (BN / 4);
        const int cole = (idx % (BN / 4)) * 4;
        float4 v = *reinterpret_cast<const float4*>(&st[row * BN + cole]);
        *reinterpret_cast<float4*>(
            Cp + (size_t)(m0 + half * (BM / 2) + row) * ldc + n0 + cole) = v;
      }
    }
  }
}

// ---------- small m97-style NT GEMM (x = e1 @ pos) ----------
template <int BM, int BN>
__global__ __launch_bounds__(256) void gemm_nt(
    const f16* __restrict__ A, const f16* __restrict__ Bt, float* __restrict__ C,
    int K, int lda, int ldb, int ldc) {
  constexpr int FM = BM / 32;
  constexpr int FN = BN / 32;
  constexpr int NA = BM / 16, NTOT = NA + BN / 16;
  __shared__ __attribute__((aligned(16))) f16 As[BM * 32];
  __shared__ __attribute__((aligned(16))) f16 Bs[BN * 32];

  const int lane = threadIdx.x & 63;
  const int wave = threadIdx.x >> 6;
  const int wr = wave >> 1, wc = wave & 1;
  const int m0 = blockIdx.x * BM, n0 = blockIdx.y * BN;
  const int srow = lane >> 2;
  const int scol = (lane & 3) * 8;
  const int lrow = lane & 15;
  const int kg = lane >> 4;

  f32x4 acc[FM][FN] = {};

  for (int k0 = 0; k0 < K; k0 += 32) {
    __syncthreads();
#pragma unroll
    for (int i = wave; i < NTOT; i += 4) {
      if (i < NA)
        async16(A + (size_t)(m0 + i * 16 + srow) * lda + k0 + scol, &As[i * 512]);
      else
        async16(Bt + (size_t)(n0 + (i - NA) * 16 + srow) * ldb + k0 + scol,
                &Bs[(i - NA) * 512]);
    }
    __syncthreads();

    f16x8 af[FM], bfr[FN];
#pragma unroll
    for (int m = 0; m < FM; m++)
      af[m] = *reinterpret_cast<const f16x8*>(
          &As[(wr * (BM / 2) + m * 16 + lrow) * 32 + kg * 8]);
#pragma unroll
    for (int n = 0; n < FN; n++)
      bfr[n] = *reinterpret_cast<const f16x8*>(
          &Bs[(wc * (BN / 2) + n * 16 + lrow) * 32 + kg * 8]);
#pragma unroll
    for (int m = 0; m < FM; m++)
#pragma unroll
      for (int n = 0; n < FN; n++)
        acc[m][n] = __builtin_amdgcn_mfma_f32_16x16x32_f16(af[m], bfr[n], acc[m][n], 0, 0, 0);
  }

  const int crow = m0 + wr * (BM / 2) + (lane >> 4) * 4;
  const int ccol = n0 + wc * (BN / 2) + (lane & 15);
#pragma unroll
  for (int m = 0; m < FM; m++)
#pragma unroll
    for (int n = 0; n < FN; n++)
#pragma unroll
      for (int r = 0; r < 4; r++)
        C[(size_t)(crow + m * 16 + r) * ldc + ccol + n * 16] = acc[m][n][r];
}

// ---------- in-place LayerNorm (q path) ----------
__global__ __launch_bounds__(256) void ln_kernel(
    f16* __restrict__ buf, const float* __restrict__ bias,
    const float* __restrict__ g, const float* __restrict__ beta) {
  __shared__ float rs_[4], rq_[4];
  const int t = threadIdx.x;
  f16* rp = buf + (size_t)blockIdx.x * CD;
  f16x4 v = *reinterpret_cast<const f16x4*>(rp + t * 4);
  float y[4], s = 0.f, q = 0.f;
#pragma unroll
  for (int j = 0; j < 4; j++) {
    y[j] = (float)v[j] + bias[t * 4 + j];
    s += y[j]; q += y[j] * y[j];
  }
#pragma unroll
  for (int o = 32; o; o >>= 1) { s += __shfl_xor(s, o); q += __shfl_xor(q, o); }
  if ((t & 63) == 0) { rs_[t >> 6] = s; rq_[t >> 6] = q; }
  __syncthreads();
  s = rs_[0] + rs_[1] + rs_[2] + rs_[3];
  q = rq_[0] + rq_[1] + rq_[2] + rq_[3];
  const float mean = s * (1.0f / CD);
  const float rstd = rsqrtf(q * (1.0f / CD) - mean * mean + 1e-5f);
  f16x4 o;
#pragma unroll
  for (int j = 0; j < 4; j++) {
    int c = t * 4 + j;
    o[j] = (f16)((y[j] - mean) * rstd * g[c] + beta[c]);
  }
  *reinterpret_cast<f16x4*>(rp + t * 4) = o;
}

// ---------- in-place LayerNorm for kn|vn halves of [8192][2048] ----------
__global__ __launch_bounds__(256) void lnkv_kernel(
    f16* __restrict__ buf,
    const float* __restrict__ bk, const float* __restrict__ gk, const float* __restrict__ bek,
    const float* __restrict__ bv, const float* __restrict__ gv, const float* __restrict__ bev) {
  __shared__ float rs_[4], rq_[4];
  const int z = blockIdx.y;
  const float* bias = z ? bv : bk;
  const float* g    = z ? gv : gk;
  const float* beta = z ? bev : bek;
  const int t = threadIdx.x;
  f16* rp = buf + (size_t)blockIdx.x * 2048 + z * 1024;
  f16x4 v = *reinterpret_cast<const f16x4*>(rp + t * 4);
  float y[4], s = 0.f, q = 0.f;
#pragma unroll
  for (int j = 0; j < 4; j++) {
    y[j] = (float)v[j] + bias[t * 4 + j];
    s += y[j]; q += y[j] * y[j];
  }
#pragma unroll
  for (int o = 32; o; o >>= 1) { s += __shfl_xor(s, o); q += __shfl_xor(q, o); }
  if ((t & 63) == 0) { rs_[t >> 6] = s; rq_[t >> 6] = q; }
  __syncthreads();
  s = rs_[0] + rs_[1] + rs_[2] + rs_[3];
  q = rq_[0] + rq_[1] + rq_[2] + rq_[3];
  const float mean = s * (1.0f / CD);
  const float rstd = rsqrtf(q * (1.0f / CD) - mean * mean + 1e-5f);
  f16x4 o;
#pragma unroll
  for (int j = 0; j < 4; j++) {
    int c = t * 4 + j;
    o[j] = (f16)((y[j] - mean) * rstd * g[c] + beta[c]);
  }
  *reinterpret_cast<f16x4*>(rp + t * 4) = o;
}

// ---------- normalize: att[head] = e * inv(rowsum) ----------
__global__ __launch_bounds__(256) void norm_kernel(
    const f16* __restrict__ e, const float* __restrict__ ps,
    const float* __restrict__ invin, float* __restrict__ invout,
    float* __restrict__ att, int head) {
  const int row = blockIdx.x;
  const int b = row >> 11, n = row & (CNQ - 1);
  float iv;
  if (ps) {
    float s = 0.f;
#pragma unroll
    for (int j = 0; j < 8; j++) s += ps[j * (CB * CNQ) + row];
    iv = 1.0f / s;
    if (threadIdx.x == 0) invout[row] = iv;
  } else {
    iv = invin[row];
  }
  const int t = threadIdx.x;
  float* rp = att + ((size_t)((b << 1) + head) * CNQ + n) * CNK;
  f16x8 v = *reinterpret_cast<const f16x8*>(e + (size_t)row * CNK + t * 8);
  float4 w0 = {(float)v[0] * iv, (float)v[1] * iv, (float)v[2] * iv, (float)v[3] * iv};
  float4 w1 = {(float)v[4] * iv, (float)v[5] * iv, (float)v[6] * iv, (float)v[7] * iv};
  reinterpret_cast<float4*>(rp)[t * 2]     = w0;
  reinterpret_cast<float4*>(rp)[t * 2 + 1] = w1;
}

// ---------- attn2: x' = (x*inv1)@Wp + bp; e2 = exp(x'.pos^T/8); inv2 ----------
__global__ __launch_bounds__(128) void attn2_kernel(
    const float* __restrict__ x, const float* __restrict__ Wp,
    const float* __restrict__ bp, const f16* __restrict__ posb,
    const float* __restrict__ inv1, f16* __restrict__ e2,
    float* __restrict__ inv2) {
  __shared__ float xs[32 * 64];
  __shared__ float Wps[64 * 64];
  __shared__ __attribute__((aligned(16))) f16 xpb[32 * 64];
  __shared__ __attribute__((aligned(16))) f16 elds[2][16 * 64];
  const int tid = threadIdx.x, l = tid & 63, w = tid >> 6;
  const int r0 = blockIdx.x * 32;
#pragma unroll
  for (int i = 0; i < 16; i++) {
    const int row = w * 16 + i;
    xs[row * 64 + l] = x[(size_t)(r0 + row) * CP + l] * inv1[r0 + row];
  }
#pragma unroll
  for (int i = w; i < 64; i += 2) Wps[i * 64 + l] = Wp[i * 64 + l];
  const float bpl = bp[l];
  __syncthreads();
  const int rb = w * 16;
#pragma unroll 2
  for (int i = 0; i < 16; i++) {
    float a = bpl;
#pragma unroll 8
    for (int p = 0; p < 64; p++) a = fmaf(xs[(rb + i) * 64 + p], Wps[p * 64 + l], a);
    xpb[(rb + i) * 64 + l] = (f16)a;
  }
  asm volatile("s_waitcnt lgkmcnt(0)" ::: "memory");
  const f16x8 af0 = *reinterpret_cast<const f16x8*>(&xpb[(rb + (l & 15)) * 64 + (l >> 4) * 8]);
  const f16x8 af1 = *reinterpret_cast<const f16x8*>(&xpb[(rb + (l & 15)) * 64 + 32 + (l >> 4) * 8]);
  float rs[4] = {0.f, 0.f, 0.f, 0.f};
  f16* eb = e2 + (size_t)(r0 + rb) * CNK;
  for (int jt = 0; jt < CNK / 64; jt++) {
#pragma unroll
    for (int q4 = 0; q4 < 4; q4++) {
      const int j = jt * 64 + q4 * 16 + (l & 15);
      const f16* pp = posb + (size_t)j * CP + (l >> 4) * 8;
      f16x8 b0 = *reinterpret_cast<const f16x8*>(pp);
      f16x8 b1 = *reinterpret_cast<const f16x8*>(pp + 32);
      f32x4 c = {};
      c = __builtin_amdgcn_mfma_f32_16x16x32_f16(af0, b0, c, 0, 0, 0);
      c = __builtin_amdgcn_mfma_f32_16x16x32_f16(af1, b1, c, 0, 0, 0);
#pragma unroll
      for (int r = 0; r < 4; r++) {
        float ev = __expf(c[r] * 0.125f);
        rs[r] += ev;
        elds[w][((l >> 4) * 4 + r) * 64 + q4 * 16 + (l & 15)] = (f16)ev;
      }
    }
    asm volatile("s_waitcnt lgkmcnt(0)" ::: "memory");
    f16x8 h0 = *reinterpret_cast<const f16x8*>(&elds[w][(l >> 2) * 64 + (l & 3) * 16]);
    f16x8 h1 = *reinterpret_cast<const f16x8*>(&elds[w][(l >> 2) * 64 + (l & 3) * 16 + 8]);
    f16* op = eb + (size_t)(l >> 2) * CNK + jt * 64 + (l & 3) * 16;
    *reinterpret_cast<f16x8*>(op)     = h0;
    *reinterpret_cast<f16x8*>(op + 8) = h1;
    asm volatile("s_waitcnt lgkmcnt(0)" ::: "memory");  // elds reuse next jt
  }
#pragma unroll
  for (int r = 0; r < 4; r++) {
#pragma unroll
    for (int o = 1; o < 16; o <<= 1) rs[r] += __shfl_xor(rs[r], o);
    if ((l & 15) == 0) inv2[r0 + rb + (l >> 4) * 4 + r] = 1.0f / rs[r];
  }
}

extern "C" void kernel_launch(void* const* d_in, const int* in_sizes, int n_in,
                              void* d_out, int out_size, void* d_ws, size_t ws_size,
                              hipStream_t stream) {
  (void)in_sizes; (void)n_in; (void)out_size; (void)ws_size;
  const float* q    = (const float*)d_in[0];
  const float* k    = (const float*)d_in[1];
  const float* Wq   = (const float*)d_in[2];
  const float* bq   = (const float*)d_in[3];
  const float* Wk   = (const float*)d_in[4];
  const float* bk   = (const float*)d_in[5];
  const float* Wv   = (const float*)d_in[6];
  const float* bv   = (const float*)d_in[7];
  const float* gq   = (const float*)d_in[8];
  const float* betaq= (const float*)d_in[9];
  const float* gk   = (const float*)d_in[10];
  const float* betak= (const float*)d_in[11];
  const float* gv   = (const float*)d_in[12];
  const float* betav= (const float*)d_in[13];
  const float* Wp   = (const float*)d_in[14];
  const float* bp   = (const float*)d_in[15];

  float* out = (float*)d_out;
  float* att = out + (size_t)CB * CNQ * CD;   // [B,2,NQ,NK]
  char* ws = (char*)d_ws;
  const size_t MB = 1ull << 20;

  f16* q16   = (f16*)(ws);                     // 0-16MB, dead after q-GEMM
  f16* k16   = (f16*)(ws + 16 * MB);           // 16-32, dead after kv-GEMM
  f16* e1    = (f16*)(ws);                     // 0-32 (after q16/k16 die)
  f16* e2    = (f16*)(ws);                     // 0-32 (after e1 dies)
  f16* WqT   = (f16*)(ws + 32 * MB);           // 2MB
  f16* WkvT  = (f16*)(ws + 34 * MB);           // 4MB
  f16* posb  = (f16*)(ws + 38 * MB);           // 256KB
  f16* posTb = (f16*)(ws + 38 * MB + 256 * 1024);
  float* xw  = (float*)(ws + 38 * MB + 512 * 1024); // 2MB
  float* PS  = (float*)(ws + 40 * MB + 512 * 1024); // 256KB [8][8192]
  float* inv1= (float*)(ws + 40 * MB + 768 * 1024); // 32KB
  float* inv2= (float*)(ws + 40 * MB + 800 * 1024); // 32KB
  f16* tmpq  = (f16*)(ws + 41 * MB);           // 16MB (qn in place)
  f16* tmp2  = (f16*)(ws + 57 * MB);           // 32MB (kn|vn in place)
  f16* vnT   = (f16*)(ws + 89 * MB);           // 16MB (ends 105MB)
  f16* qn = tmpq;
  f16* kn = tmp2;            // ld 2048, cols 0-1023
  f16* vn = tmp2 + 1024;     // ld 2048, cols 1024-2047

  pos_kernel<<<(CP * CNK) / 256, 256, 0, stream>>>(posb, posTb);
  cvt2_kernel<<<2 * (CB * CNQ * CD / 4) / 256, 256, 0, stream>>>(q, k, q16, k16);
  cvtWT_kernel<<<dim3(16, 16, 3), 256, 0, stream>>>(Wq, Wk, Wv, WqT, WkvT);

  gemm8<256, 128, 1><<<256, 512, 0, stream>>>(q16, WqT, tmpq, CD, CD, CD, CD,
                                              0, 0, 0, 1.f, 32, 8, nullptr);
  ln_kernel<<<CB * CNQ, 256, 0, stream>>>(tmpq, bq, gq, betaq);
  gemm8<256, 256, 1><<<256, 512, 0, stream>>>(k16, WkvT, tmp2, CD, CD, CD, 2048,
                                              0, 0, 0, 1.f, 32, 8, nullptr);
  lnkv_kernel<<<dim3(CB * CNK, 2), 256, 0, stream>>>(tmp2, bk, gk, betak, bv, gv, betav);
  transpose_kernel<<<dim3(CNK / 64, CD / 64, CB), 256, 0, stream>>>(vn, vnT, 2048);

  // s1: e1 = exp(qn.kn^T/32) f16 + per-coltile partials
  gemm8<256, 256, 2><<<256, 512, 0, stream>>>(qn, kn, e1, CD, CD, 2048, CNK,
      (size_t)CNQ * CD, (size_t)CNK * 2048, (size_t)CNQ * CNK, 0.03125f, 8, 8, PS);
  norm_kernel<<<CB * CNQ, 256, 0, stream>>>(e1, PS, nullptr, inv1, att, 0);

  // x = e1 @ pos (unnormalized; inv1 applied in attn2)
  gemm_nt<64, 64><<<dim3(CB * CNQ / 64, 1, 1), 256, 0, stream>>>(
      e1, posTb, xw, CNK, CNK, CNK, CP);
  attn2_kernel<<<CB * CNQ / 32, 128, 0, stream>>>(xw, Wp, bp, posb, inv1, e2, inv2);
  norm_kernel<<<CB * CNQ, 256, 0, stream>>>(e2, nullptr, inv2, nullptr, att, 1);

  // out = (e2 @ vn) * inv2
  gemm8<256, 128, 3><<<256, 512, 0, stream>>>(e2, vnT, out, CNK, CNK, CNK, CD,
      (size_t)CNQ * CNK, (size_t)CD * CNK, (size_t)CNQ * CD, 1.f, 8, 8, inv2);
}

// Round 5
// 324.083 us; speedup vs baseline: 1.2645x; 1.0341x over previous
//
#include <hip/hip_runtime.h>
#include <math.h>
#include <stdint.h>

// BlindCrossAttention on MI355X (gfx950).
// Round 5: 2-phase gemm_core, fused input GEMM (q+kv one launch), merged LN,
// attn2 writes normalized att+e2 (norm2 gone), K-split x-GEMM.

typedef _Float16 f16;
typedef _Float16 f16x4 __attribute__((ext_vector_type(4)));
typedef _Float16 f16x8 __attribute__((ext_vector_type(8)));
typedef float f32x4 __attribute__((ext_vector_type(4)));

static constexpr int CB  = 4;
static constexpr int CNQ = 2048;
static constexpr int CNK = 2048;
static constexpr int CD  = 1024;
static constexpr int CP  = 64;

// ---------- async global->LDS, 16B/lane ----------
static __device__ __forceinline__ void async16(const f16* gp, f16* lp) {
  __builtin_amdgcn_global_load_lds(
      (const __attribute__((address_space(1))) void*)(uintptr_t)gp,
      (__attribute__((address_space(3))) void*)(uint32_t)(uintptr_t)lp,
      16, 0, 0);
}

// ---------- pos table ----------
__global__ __launch_bounds__(256) void pos_kernel(f16* __restrict__ posb,
                                                  f16* __restrict__ posTb) {
  int tid = blockIdx.x * 256 + threadIdx.x;
  int p = tid >> 11;
  int j = tid & (CNK - 1);
  int i = p & 31;
  float ph = (float)j * powf(10000.0f, -(float)i * (1.0f / 32.0f));
  float v = (p < 32) ? sinf(ph) : cosf(ph);
  posb[j * CP + p]   = (f16)v;
  posTb[p * CNK + j] = (f16)v;
}

// ---------- f32 -> f16 for q and k ----------
__global__ __launch_bounds__(256) void cvt2_kernel(const float* __restrict__ a,
                                                   const float* __restrict__ b,
                                                   f16* __restrict__ oa,
                                                   f16* __restrict__ ob) {
  const int NF4 = CB * CNQ * CD / 4;
  int tid = blockIdx.x * 256 + threadIdx.x;
  const float* src = (tid < NF4) ? a : b;
  f16* dst = (tid < NF4) ? oa : ob;
  int i = (tid < NF4) ? tid : tid - NF4;
  float4 v = reinterpret_cast<const float4*>(src)[i];
  f16x4 o = {(f16)v.x, (f16)v.y, (f16)v.z, (f16)v.w};
  reinterpret_cast<f16x4*>(dst)[i] = o;
}

// ---------- W[k][n] f32 -> WT[n][k] f16, all three weights ----------
__global__ __launch_bounds__(256) void cvtWT_kernel(
    const float* __restrict__ Wq, const float* __restrict__ Wk,
    const float* __restrict__ Wv, f16* __restrict__ WqT, f16* __restrict__ WkvT) {
  __shared__ float t[64][65];
  const float* W = (blockIdx.z == 0) ? Wq : (blockIdx.z == 1) ? Wk : Wv;
  f16* WT = (blockIdx.z == 0) ? WqT : (blockIdx.z == 1) ? WkvT : WkvT + 1024 * 1024;
  int k0 = blockIdx.x * 64, n0 = blockIdx.y * 64;
  int tx = threadIdx.x & 63, ty = threadIdx.x >> 6;
#pragma unroll
  for (int i = 0; i < 16; i++)
    t[ty + 4 * i][tx] = W[(size_t)(k0 + ty + 4 * i) * CD + n0 + tx];
  __syncthreads();
#pragma unroll
  for (int i = 0; i < 16; i++)
    WT[(size_t)(n0 + 4 * i + ty) * CD + k0 + tx] = (f16)t[tx][ty + 4 * i];
}

// ---------- f16 transpose: out[b][d][n] = in[b][n][d] ----------
__global__ __launch_bounds__(256) void transpose_kernel(const f16* __restrict__ in,
                                                        f16* __restrict__ out,
                                                        int ldi) {
  __shared__ f16 t[64][65];
  int n0 = blockIdx.x * 64, d0 = blockIdx.y * 64;
  size_t ibase = (size_t)blockIdx.z * CNK * ldi;
  size_t obase = (size_t)blockIdx.z * CNK * CD;
  int tx = threadIdx.x & 63, ty = threadIdx.x >> 6;
#pragma unroll
  for (int i = 0; i < 16; i++)
    t[ty + 4 * i][tx] = in[ibase + (size_t)(n0 + ty + 4 * i) * ldi + d0 + tx];
  __syncthreads();
#pragma unroll
  for (int i = 0; i < 16; i++)
    out[obase + (size_t)(d0 + ty + 4 * i) * CNK + n0 + tx] = t[tx][ty + 4 * i];
}

// ================= 2-phase counted-pipeline GEMM core =================
// 8 waves (2x4), BK=64, dbuf LDS, T2 XOR swizzle via pre-swizzled global src,
// full next-tile issue at tile head + counted vmcnt(TI).
template <int BM, int BN>
__device__ __forceinline__ void gemm_core(
    const f16* __restrict__ Ab, const f16* __restrict__ Bb,
    int lda, int ldb, int K, int m0, int n0, f16* sm,
    f32x4 (&acc)[BM / 32][BN / 64]) {
  constexpr int FM = BM / 32, FN = BN / 64;
  constexpr int TI = (BM + BN) / 64;
  constexpr int bufsz = (BM + BN) * 64;
  const int tid = threadIdx.x;
  const int lane = tid & 63, wid = tid >> 6;
  const int wr = wid >> 2, wc = wid & 3;
  const int lrow = lane & 15, kg = lane >> 4;

  auto stage = [&](int i, int kt, int buf) {
    const int s = i * 512 + tid;          // 16B slot
    const int row = s >> 3;
    const int cb = (s & 7) << 4;
    const int scb = cb ^ ((row & 7) << 4);  // pre-swizzled global source col
    const f16* src = (i < BM / 64)
        ? Ab + (size_t)(m0 + row) * lda + kt * 64 + (scb >> 1)
        : Bb + (size_t)(n0 + row - BM) * ldb + kt * 64 + (scb >> 1);
    async16(src, &sm[buf * bufsz + s * 8]);
  };

  const int NT = K >> 6;
#pragma unroll
  for (int i = 0; i < TI; i++) stage(i, 0, 0);

  for (int t = 0; t < NT; ++t) {
    const int cur = t & 1;
    if (t + 1 < NT) {
#pragma unroll
      for (int i = 0; i < TI; i++) stage(i, t + 1, cur ^ 1);
      if constexpr (TI == 8) asm volatile("s_waitcnt vmcnt(8)" ::: "memory");
      else                   asm volatile("s_waitcnt vmcnt(6)" ::: "memory");
    } else {
      asm volatile("s_waitcnt vmcnt(0)" ::: "memory");
    }
    __builtin_amdgcn_s_barrier();

    const f16* smA = sm + cur * bufsz;
    const f16* smB = smA + BM * 64;
#pragma unroll
    for (int kk = 0; kk < 2; ++kk) {
      const int Cb = kk * 64 + kg * 16;
      f16x8 af[FM], bf[FN];
#pragma unroll
      for (int m = 0; m < FM; ++m) {
        const int ar = wr * (BM / 2) + m * 16 + lrow;
        af[m] = *reinterpret_cast<const f16x8*>(
            &smA[ar * 64 + ((Cb ^ ((ar & 7) << 4)) >> 1)]);
      }
#pragma unroll
      for (int n = 0; n < FN; ++n) {
        const int br = wc * (BN / 4) + n * 16 + lrow;
        bf[n] = *reinterpret_cast<const f16x8*>(
            &smB[br * 64 + ((Cb ^ ((br & 7) << 4)) >> 1)]);
      }
      __builtin_amdgcn_s_barrier();
      __builtin_amdgcn_s_setprio(1);
#pragma unroll
      for (int m = 0; m < FM; ++m)
#pragma unroll
        for (int n = 0; n < FN; ++n)
          acc[m][n] = __builtin_amdgcn_mfma_f32_16x16x32_f16(af[m], bf[n], acc[m][n], 0, 0, 0);
      __builtin_amdgcn_s_setprio(0);
      __builtin_amdgcn_s_barrier();
    }
  }
}

// ---------- epilogue: f16 store, LDS-staged ----------
template <int BM, int BN>
__device__ __forceinline__ void epi_f16(
    f32x4 (&acc)[BM / 32][BN / 64], f16* sm, f16* Cp, int ldc, int m0, int n0) {
  const int tid = threadIdx.x, lane = tid & 63, wid = tid >> 6;
  const int wr = wid >> 2, wc = wid & 3;
  const int rbase = wr * (BM / 2) + (lane >> 4) * 4;
  const int cbase = wc * (BN / 4) + (lane & 15);
  __syncthreads();
#pragma unroll
  for (int mg = 0; mg < BM / 32; mg++)
#pragma unroll
    for (int n = 0; n < BN / 64; n++)
#pragma unroll
      for (int r = 0; r < 4; r++)
        sm[(rbase + mg * 16 + r) * BN + cbase + n * 16] = (f16)acc[mg][n][r];
  __syncthreads();
  constexpr int CH = BM * BN / (512 * 8);
#pragma unroll
  for (int c = 0; c < CH; c++) {
    const int idx = c * 512 + tid;
    const int row = idx / (BN / 8);
    const int cole = (idx % (BN / 8)) * 8;
    f16x8 v = *reinterpret_cast<const f16x8*>(&sm[row * BN + cole]);
    *reinterpret_cast<f16x8*>(Cp + (size_t)(m0 + row) * ldc + n0 + cole) = v;
  }
}

// ---------- epilogue: exp()->f16 store + per-coltile row partial sums ----------
template <int BM, int BN>
__device__ __forceinline__ void epi_exp(
    f32x4 (&acc)[BM / 32][BN / 64], f16* sm, float* psum, f16* Cp, int ldc,
    int m0, int n0, float scale, float* PSrow) {
  const int tid = threadIdx.x, lane = tid & 63, wid = tid >> 6;
  const int wr = wid >> 2, wc = wid & 3;
  const int rbase = wr * (BM / 2) + (lane >> 4) * 4;
  const int cbase = wc * (BN / 4) + (lane & 15);
  __syncthreads();
  if (tid < BM) psum[tid] = 0.f;
#pragma unroll
  for (int mg = 0; mg < BM / 32; mg++)
#pragma unroll
    for (int n = 0; n < BN / 64; n++)
#pragma unroll
      for (int r = 0; r < 4; r++)
        sm[(rbase + mg * 16 + r) * BN + cbase + n * 16] =
            (f16)__expf(acc[mg][n][r] * scale);
  __syncthreads();
  constexpr int CH = BM * BN / (512 * 8);
#pragma unroll
  for (int c = 0; c < CH; c++) {
    const int idx = c * 512 + tid;
    const int row = idx / (BN / 8);
    const int cole = (idx % (BN / 8)) * 8;
    f16x8 v = *reinterpret_cast<const f16x8*>(&sm[row * BN + cole]);
    *reinterpret_cast<f16x8*>(Cp + (size_t)(m0 + row) * ldc + n0 + cole) = v;
    float p = 0.f;
#pragma unroll
    for (int j = 0; j < 8; j++) p += (float)v[j];
#pragma unroll
    for (int o = 1; o < 32; o <<= 1) p += __shfl_xor(p, o);
    if ((lane & 31) == 0) atomicAdd(&psum[row], p);
  }
  __syncthreads();
  if (tid < BM) PSrow[tid] = psum[tid];
}

// ---------- epilogue: f32 store, LDS-staged (two half-passes) ----------
template <int BM, int BN>
__device__ __forceinline__ void epi_f32(
    f32x4 (&acc)[BM / 32][BN / 64], f16* smh, float* Cp, int ldc, int m0, int n0) {
  float* st = (float*)smh;
  const int tid = threadIdx.x, lane = tid & 63, wid = tid >> 6;
  const int wr = wid >> 2, wc = wid & 3;
  const int cbase = wc * (BN / 4) + (lane & 15);
#pragma unroll
  for (int half = 0; half < 2; half++) {
    __syncthreads();
    if (wr == half) {
#pragma unroll
      for (int mg = 0; mg < BM / 32; mg++)
#pragma unroll
        for (int r = 0; r < 4; r++) {
          const int rloc = (lane >> 4) * 4 + mg * 16 + r;
#pragma unroll
          for (int n = 0; n < BN / 64; n++)
            st[rloc * BN + cbase + n * 16] = acc[mg][n][r];
        }
    }
    __syncthreads();
    constexpr int CH = (BM / 2) * BN / (512 * 4);
#pragma unroll
    for (int c = 0; c < CH; c++) {
      const int idx = c * 512 + tid;
      const int row = idx / (BN / 4);
      const int cole = (idx % (BN / 4)) * 4;
      float4 v = *reinterpret_cast<const float4*>(&st[row * BN + cole]);
      *reinterpret_cast<float4*>(
          Cp + (size_t)(m0 + half * (BM / 2) + row) * ldc + n0 + cole) = v;
    }
  }
}

// ---------- fused input GEMM: blocks 0-255 q@WqT, 256-767 k@WkvT ----------
__global__ __launch_bounds__(512) void gemmIn_kernel(
    const f16* __restrict__ q16, const f16* __restrict__ WqT, f16* __restrict__ tmpq,
    const f16* __restrict__ k16, const f16* __restrict__ WkvT, f16* __restrict__ tmp2) {
  __shared__ __attribute__((aligned(16))) f16 sm[2][(256 + 128) * 64];
  const int b = blockIdx.x;                       // 768
  const int swz = (b & 7) * 96 + (b >> 3);        // bijective XCD swizzle
  const f16 *A, *B;
  f16* C;
  int ldc, m0, n0;
  if (swz < 256) {
    const int by = swz >> 5, bx = swz & 31;
    A = q16; B = WqT; C = tmpq; ldc = 1024; m0 = bx * 256; n0 = by * 128;
  } else {
    const int idx = swz - 256;
    const int by = idx >> 5, bx = idx & 31;
    A = k16; B = WkvT; C = tmp2; ldc = 2048; m0 = bx * 256; n0 = by * 128;
  }
  f32x4 acc[8][2] = {};
  gemm_core<256, 128>(A, B, 1024, 1024, 1024, m0, n0, &sm[0][0], acc);
  epi_f16<256, 128>(acc, &sm[0][0], C, ldc, m0, n0);
}

// ---------- s1 GEMM: e1 = exp(qn.kn^T/32), partial row sums to PS ----------
__global__ __launch_bounds__(512) void gemmS1_kernel(
    const f16* __restrict__ qn, const f16* __restrict__ kn,
    f16* __restrict__ e1, float* __restrict__ PS) {
  __shared__ __attribute__((aligned(16))) f16 sm[2][(256 + 256) * 64];
  __shared__ float psum[256];
  const int b = blockIdx.x;                       // 256
  const int swz = (b & 7) * 32 + (b >> 3);
  const int bz = swz >> 6;
  const int rem = swz & 63;
  const int by = rem >> 3, bx = rem & 7;
  const int m0 = bx * 256, n0 = by * 256;
  const f16* Ab = qn + (size_t)bz * 2048 * 1024;
  const f16* Bb = kn + (size_t)bz * 2048 * 2048;
  f16* Cp = e1 + (size_t)bz * 2048 * 2048;
  f32x4 acc[8][4] = {};
  gemm_core<256, 256>(Ab, Bb, 1024, 2048, 1024, m0, n0, &sm[0][0], acc);
  epi_exp<256, 256>(acc, &sm[0][0], psum, Cp, 2048, m0, n0, 0.03125f,
                    PS + (size_t)by * 8192 + bz * 2048 + m0);
}

// ---------- out GEMM: out = e2n @ vn (e2 already normalized) ----------
__global__ __launch_bounds__(512) void gemmOut_kernel(
    const f16* __restrict__ e2, const f16* __restrict__ vnT, float* __restrict__ out) {
  __shared__ __attribute__((aligned(16))) f16 sm[2][(256 + 128) * 64];
  const int b = blockIdx.x;                       // 256
  const int swz = (b & 7) * 32 + (b >> 3);
  const int bz = swz >> 6;
  const int rem = swz & 63;
  const int by = rem >> 3, bx = rem & 7;
  const int m0 = bx * 256, n0 = by * 128;
  const f16* Ab = e2 + (size_t)bz * 2048 * 2048;
  const f16* Bb = vnT + (size_t)bz * 1024 * 2048;
  float* Cp = out + (size_t)bz * 2048 * 1024;
  f32x4 acc[8][2] = {};
  gemm_core<256, 128>(Ab, Bb, 2048, 2048, 2048, m0, n0, &sm[0][0], acc);
  epi_f32<256, 128>(acc, &sm[0][0], Cp, 1024, m0, n0);
}

// ---------- merged in-place LayerNorm: z=0 q, z=1 k, z=2 v ----------
__global__ __launch_bounds__(256) void ln3_kernel(
    f16* __restrict__ tmpq, f16* __restrict__ tmp2,
    const float* __restrict__ bq, const float* __restrict__ gq, const float* __restrict__ beq,
    const float* __restrict__ bk, const float* __restrict__ gk, const float* __restrict__ bek,
    const float* __restrict__ bv, const float* __restrict__ gv, const float* __restrict__ bev) {
  __shared__ float rs_[4], rq_[4];
  const int z = blockIdx.y;
  f16* rp;
  const float *bias, *g, *beta;
  if (z == 0)      { rp = tmpq + (size_t)blockIdx.x * 1024;        bias = bq; g = gq; beta = beq; }
  else if (z == 1) { rp = tmp2 + (size_t)blockIdx.x * 2048;        bias = bk; g = gk; beta = bek; }
  else             { rp = tmp2 + (size_t)blockIdx.x * 2048 + 1024; bias = bv; g = gv; beta = bev; }
  const int t = threadIdx.x;
  f16x4 v = *reinterpret_cast<const f16x4*>(rp + t * 4);
  float y[4], s = 0.f, q = 0.f;
#pragma unroll
  for (int j = 0; j < 4; j++) {
    y[j] = (float)v[j] + bias[t * 4 + j];
    s += y[j]; q += y[j] * y[j];
  }
#pragma unroll
  for (int o = 32; o; o >>= 1) { s += __shfl_xor(s, o); q += __shfl_xor(q, o); }
  if ((t & 63) == 0) { rs_[t >> 6] = s; rq_[t >> 6] = q; }
  __syncthreads();
  s = rs_[0] + rs_[1] + rs_[2] + rs_[3];
  q = rq_[0] + rq_[1] + rq_[2] + rq_[3];
  const float mean = s * (1.0f / CD);
  const float rstd = rsqrtf(q * (1.0f / CD) - mean * mean + 1e-5f);
  f16x4 o;
#pragma unroll
  for (int j = 0; j < 4; j++) {
    int c = t * 4 + j;
    o[j] = (f16)((y[j] - mean) * rstd * g[c] + beta[c]);
  }
  *reinterpret_cast<f16x4*>(rp + t * 4) = o;
}

// ---------- norm1: att0 = e1 * inv(rowsum); inv1 saved ----------
__global__ __launch_bounds__(256) void norm1_kernel(
    const f16* __restrict__ e1, const float* __restrict__ PS,
    float* __restrict__ inv1, float* __restrict__ att) {
  const int row = blockIdx.x;
  const int b = row >> 11, n = row & (CNQ - 1);
  float s = 0.f;
#pragma unroll
  for (int j = 0; j < 8; j++) s += PS[j * (CB * CNQ) + row];
  const float iv = 1.0f / s;
  if (threadIdx.x == 0) inv1[row] = iv;
  const int t = threadIdx.x;
  float* rp = att + ((size_t)(b << 1) * CNQ + n) * CNK;
  f16x8 v = *reinterpret_cast<const f16x8*>(e1 + (size_t)row * CNK + t * 8);
  float4 w0 = {(float)v[0] * iv, (float)v[1] * iv, (float)v[2] * iv, (float)v[3] * iv};
  float4 w1 = {(float)v[4] * iv, (float)v[5] * iv, (float)v[6] * iv, (float)v[7] * iv};
  reinterpret_cast<float4*>(rp)[t * 2]     = w0;
  reinterpret_cast<float4*>(rp)[t * 2 + 1] = w1;
}

// ---------- x-GEMM: xw[z] = e1[:, z*1024:+1024] @ pos[z*1024:+1024, :] ----------
__global__ __launch_bounds__(256) void xgemm_kernel(
    const f16* __restrict__ e1, const f16* __restrict__ posTb, float* __restrict__ xw) {
  constexpr int BM = 64, BN = 64;
  __shared__ __attribute__((aligned(16))) f16 As[BM * 32];
  __shared__ __attribute__((aligned(16))) f16 Bs[BN * 32];
  const int lane = threadIdx.x & 63;
  const int wave = threadIdx.x >> 6;
  const int wr = wave >> 1, wc = wave & 1;
  const int m0 = blockIdx.x * BM;
  const int kbase = blockIdx.z * 1024;
  const int srow = lane >> 2;
  const int scol = (lane & 3) * 8;
  const int lrow = lane & 15;
  const int kg = lane >> 4;
  f32x4 acc[2][2] = {};
  for (int k0 = 0; k0 < 1024; k0 += 32) {
    __syncthreads();
#pragma unroll
    for (int i = wave; i < 8; i += 4) {
      if (i < 4)
        async16(e1 + (size_t)(m0 + i * 16 + srow) * CNK + kbase + k0 + scol, &As[i * 512]);
      else
        async16(posTb + (size_t)((i - 4) * 16 + srow) * CNK + kbase + k0 + scol,
                &Bs[(i - 4) * 512]);
    }
    __syncthreads();
    f16x8 af[2], bfr[2];
#pragma unroll
    for (int m = 0; m < 2; m++)
      af[m] = *reinterpret_cast<const f16x8*>(&As[(wr * 32 + m * 16 + lrow) * 32 + kg * 8]);
#pragma unroll
    for (int n = 0; n < 2; n++)
      bfr[n] = *reinterpret_cast<const f16x8*>(&Bs[(wc * 32 + n * 16 + lrow) * 32 + kg * 8]);
#pragma unroll
    for (int m = 0; m < 2; m++)
#pragma unroll
      for (int n = 0; n < 2; n++)
        acc[m][n] = __builtin_amdgcn_mfma_f32_16x16x32_f16(af[m], bfr[n], acc[m][n], 0, 0, 0);
  }
  float* Cp = xw + (size_t)blockIdx.z * (CB * CNQ) * CP;
  const int crow = m0 + wr * 32 + (lane >> 4) * 4;
  const int ccol = wc * 32 + (lane & 15);
#pragma unroll
  for (int m = 0; m < 2; m++)
#pragma unroll
    for (int n = 0; n < 2; n++)
#pragma unroll
      for (int r = 0; r < 4; r++)
        Cp[(size_t)(crow + m * 16 + r) * CP + ccol + n * 16] = acc[m][n][r];
}

// ---------- attn2: x'=(x*inv1)@Wp+bp; e=exp(x'.pos^T/8); writes normalized
//            att head-1 (f32) and normalized e2 (f16). norm2 fused away. ----------
__global__ __launch_bounds__(128) void attn2_kernel(
    const float* __restrict__ xw, const float* __restrict__ Wp,
    const float* __restrict__ bp, const f16* __restrict__ posb,
    const float* __restrict__ inv1, f16* __restrict__ e2,
    float* __restrict__ att) {
  // 132KB shared: e2lds [32][2048] f16 (128KB) || xpb [32][64] f16 (4KB).
  // xs (8KB f32) and Wps (16KB f32) alias the head of e2lds (dead before use).
  __shared__ __attribute__((aligned(16))) f16 shm[32 * 2048 + 32 * 64];
  __shared__ float rsum[32];
  f16* e2lds = shm;
  f16* xpb = shm + 32 * 2048;
  float* xs = (float*)shm;              // [32][64]
  float* Wps = (float*)shm + 32 * 64;   // [64][64]
  const int tid = threadIdx.x, l = tid & 63, w = tid >> 6;
  const int r0 = blockIdx.x * 32;
#pragma unroll
  for (int i = 0; i < 16; i++) {
    const int row = w * 16 + i;
    const size_t gi = (size_t)(r0 + row) * CP + l;
    xs[row * 64 + l] = (xw[gi] + xw[(size_t)(CB * CNQ) * CP + gi]) * inv1[r0 + row];
  }
#pragma unroll
  for (int i = w; i < 64; i += 2) Wps[i * 64 + l] = Wp[i * 64 + l];
  const float bpl = bp[l];
  __syncthreads();
  const int rb = w * 16;
#pragma unroll 2
  for (int i = 0; i < 16; i++) {
    float a = bpl;
#pragma unroll 8
    for (int p = 0; p < 64; p++) a = fmaf(xs[(rb + i) * 64 + p], Wps[p * 64 + l], a);
    xpb[(rb + i) * 64 + l] = (f16)a;
  }
  __syncthreads();                       // xs/Wps dead; e2lds region free now
  const f16x8 af0 = *reinterpret_cast<const f16x8*>(&xpb[(rb + (l & 15)) * 64 + (l >> 4) * 8]);
  const f16x8 af1 = *reinterpret_cast<const f16x8*>(&xpb[(rb + (l & 15)) * 64 + 32 + (l >> 4) * 8]);
  float rs[4] = {0.f, 0.f, 0.f, 0.f};
  for (int jt = 0; jt < CNK / 64; jt++) {
#pragma unroll
    for (int q4 = 0; q4 < 4; q4++) {
      const int j = jt * 64 + q4 * 16 + (l & 15);
      const f16* pp = posb + (size_t)j * CP + (l >> 4) * 8;
      f16x8 b0 = *reinterpret_cast<const f16x8*>(pp);
      f16x8 b1 = *reinterpret_cast<const f16x8*>(pp + 32);
      f32x4 c = {};
      c = __builtin_amdgcn_mfma_f32_16x16x32_f16(af0, b0, c, 0, 0, 0);
      c = __builtin_amdgcn_mfma_f32_16x16x32_f16(af1, b1, c, 0, 0, 0);
#pragma unroll
      for (int r = 0; r < 4; r++) {
        float ev = __expf(c[r] * 0.125f);
        rs[r] += ev;
        e2lds[(rb + (l >> 4) * 4 + r) * 2048 + j] = (f16)ev;
      }
    }
  }
#pragma unroll
  for (int r = 0; r < 4; r++) {
#pragma unroll
    for (int o = 1; o < 16; o <<= 1) rs[r] += __shfl_xor(rs[r], o);
    if ((l & 15) == 0) rsum[rb + (l >> 4) * 4 + r] = rs[r];
  }
  __syncthreads();
  const int b = r0 >> 11, nloc = r0 & (CNQ - 1);
  float* attb = att + ((size_t)((b << 1) + 1) * CNQ + nloc) * CNK;
  f16* e2b = e2 + (size_t)r0 * CNK;
  for (int row = 0; row < 32; row++) {
    const float iv = 1.0f / rsum[row];
    const f16x8 a0 = *reinterpret_cast<const f16x8*>(&e2lds[row * 2048 + tid * 16]);
    const f16x8 a1 = *reinterpret_cast<const f16x8*>(&e2lds[row * 2048 + tid * 16 + 8]);
    float4 w0 = {(float)a0[0] * iv, (float)a0[1] * iv, (float)a0[2] * iv, (float)a0[3] * iv};
    float4 w1 = {(float)a0[4] * iv, (float)a0[5] * iv, (float)a0[6] * iv, (float)a0[7] * iv};
    float4 w2 = {(float)a1[0] * iv, (float)a1[1] * iv, (float)a1[2] * iv, (float)a1[3] * iv};
    float4 w3 = {(float)a1[4] * iv, (float)a1[5] * iv, (float)a1[6] * iv, (float)a1[7] * iv};
    float* ap = attb + (size_t)row * CNK + tid * 16;
    reinterpret_cast<float4*>(ap)[0] = w0;
    reinterpret_cast<float4*>(ap)[1] = w1;
    reinterpret_cast<float4*>(ap)[2] = w2;
    reinterpret_cast<float4*>(ap)[3] = w3;
    f16x8 h0 = {(f16)w0.x, (f16)w0.y, (f16)w0.z, (f16)w0.w,
                (f16)w1.x, (f16)w1.y, (f16)w1.z, (f16)w1.w};
    f16x8 h1 = {(f16)w2.x, (f16)w2.y, (f16)w2.z, (f16)w2.w,
                (f16)w3.x, (f16)w3.y, (f16)w3.z, (f16)w3.w};
    f16* ep = e2b + (size_t)row * CNK + tid * 16;
    *reinterpret_cast<f16x8*>(ep)     = h0;
    *reinterpret_cast<f16x8*>(ep + 8) = h1;
  }
}

extern "C" void kernel_launch(void* const* d_in, const int* in_sizes, int n_in,
                              void* d_out, int out_size, void* d_ws, size_t ws_size,
                              hipStream_t stream) {
  (void)in_sizes; (void)n_in; (void)out_size; (void)ws_size;
  const float* q    = (const float*)d_in[0];
  const float* k    = (const float*)d_in[1];
  const float* Wq   = (const float*)d_in[2];
  const float* bq   = (const float*)d_in[3];
  const float* Wk   = (const float*)d_in[4];
  const float* bk   = (const float*)d_in[5];
  const float* Wv   = (const float*)d_in[6];
  const float* bv   = (const float*)d_in[7];
  const float* gq   = (const float*)d_in[8];
  const float* betaq= (const float*)d_in[9];
  const float* gk   = (const float*)d_in[10];
  const float* betak= (const float*)d_in[11];
  const float* gv   = (const float*)d_in[12];
  const float* betav= (const float*)d_in[13];
  const float* Wp   = (const float*)d_in[14];
  const float* bp   = (const float*)d_in[15];

  float* out = (float*)d_out;
  float* att = out + (size_t)CB * CNQ * CD;   // [B,2,NQ,NK]
  char* ws = (char*)d_ws;
  const size_t MB = 1ull << 20;

  f16* q16   = (f16*)(ws);                     // 0-16MB, dead after gemmIn
  f16* k16   = (f16*)(ws + 16 * MB);           // 16-32, dead after gemmIn
  f16* e1    = (f16*)(ws);                     // 0-32 (after q16/k16 die)
  f16* e2    = (f16*)(ws);                     // 0-32 (after e1 dies)
  f16* WqT   = (f16*)(ws + 32 * MB);           // 2MB
  f16* WkvT  = (f16*)(ws + 34 * MB);           // 4MB
  f16* posb  = (f16*)(ws + 38 * MB);           // 256KB
  f16* posTb = (f16*)(ws + 38 * MB + 256 * 1024);
  float* xw  = (float*)(ws + 38 * MB + 512 * 1024); // 4MB [2][8192][64]
  float* PS  = (float*)(ws + 42 * MB + 512 * 1024); // 256KB [8][8192]
  float* inv1= (float*)(ws + 42 * MB + 768 * 1024); // 32KB
  f16* tmpq  = (f16*)(ws + 43 * MB);           // 16MB (qn in place)
  f16* tmp2  = (f16*)(ws + 59 * MB);           // 32MB (kn|vn in place)
  f16* vnT   = (f16*)(ws + 91 * MB);           // 16MB (ends 107MB)
  f16* qn = tmpq;
  f16* kn = tmp2;            // ld 2048, cols 0-1023
  f16* vn = tmp2 + 1024;     // ld 2048, cols 1024-2047

  pos_kernel<<<(CP * CNK) / 256, 256, 0, stream>>>(posb, posTb);
  cvt2_kernel<<<2 * (CB * CNQ * CD / 4) / 256, 256, 0, stream>>>(q, k, q16, k16);
  cvtWT_kernel<<<dim3(16, 16, 3), 256, 0, stream>>>(Wq, Wk, Wv, WqT, WkvT);

  gemmIn_kernel<<<768, 512, 0, stream>>>(q16, WqT, tmpq, k16, WkvT, tmp2);
  ln3_kernel<<<dim3(CB * CNQ, 3), 256, 0, stream>>>(
      tmpq, tmp2, bq, gq, betaq, bk, gk, betak, bv, gv, betav);
  transpose_kernel<<<dim3(CNK / 64, CD / 64, CB), 256, 0, stream>>>(vn, vnT, 2048);

  gemmS1_kernel<<<256, 512, 0, stream>>>(qn, kn, e1, PS);
  norm1_kernel<<<CB * CNQ, 256, 0, stream>>>(e1, PS, inv1, att);

  xgemm_kernel<<<dim3(CB * CNQ / 64, 1, 2), 256, 0, stream>>>(e1, posTb, xw);
  attn2_kernel<<<CB * CNQ / 32, 128, 0, stream>>>(xw, Wp, bp, posb, inv1, e2, att);

  gemmOut_kernel<<<256, 512, 0, stream>>>(e2, vnT, out);
}

// Round 7
// 323.736 us; speedup vs baseline: 1.2658x; 1.0011x over previous
//
#include <hip/hip_runtime.h>
#include <math.h>
#include <stdint.h>

// BlindCrossAttention on MI355X (gfx950).
// Round 7 = Round 6 with the epi_exp partial-sum fix: reduce width must be
// BN/8 slots-per-row (16 for BN=128), not hard-coded 32. Round 6's 32-lane
// butterfly left odd rows' psum at 0 -> inv=inf -> NaN chain.

typedef _Float16 f16;
typedef _Float16 f16x4 __attribute__((ext_vector_type(4)));
typedef _Float16 f16x8 __attribute__((ext_vector_type(8)));
typedef float f32x4 __attribute__((ext_vector_type(4)));

static constexpr int CB  = 4;
static constexpr int CNQ = 2048;
static constexpr int CNK = 2048;
static constexpr int CD  = 1024;
static constexpr int CP  = 64;

// ---------- async global->LDS, 16B/lane ----------
static __device__ __forceinline__ void async16(const f16* gp, f16* lp) {
  __builtin_amdgcn_global_load_lds(
      (const __attribute__((address_space(1))) void*)(uintptr_t)gp,
      (__attribute__((address_space(3))) void*)(uint32_t)(uintptr_t)lp,
      16, 0, 0);
}

// ---------- prep: pos table + cvt q,k -> f16 + transpose-cvt W's ----------
__global__ __launch_bounds__(256) void prep_kernel(
    const float* __restrict__ q, const float* __restrict__ k,
    const float* __restrict__ Wq, const float* __restrict__ Wk,
    const float* __restrict__ Wv,
    f16* __restrict__ q16, f16* __restrict__ k16,
    f16* __restrict__ WqT, f16* __restrict__ WkvT,
    f16* __restrict__ posb, f16* __restrict__ posTb) {
  const int b = blockIdx.x;
  if (b < 512) {                        // pos table
    int tid = b * 256 + threadIdx.x;
    int p = tid >> 11;
    int j = tid & (CNK - 1);
    int i = p & 31;
    float ph = (float)j * powf(10000.0f, -(float)i * (1.0f / 32.0f));
    float v = (p < 32) ? sinf(ph) : cosf(ph);
    posb[j * CP + p]   = (f16)v;
    posTb[p * CNK + j] = (f16)v;
  } else if (b < 512 + 16384) {         // cvt q,k
    const int NF4 = CB * CNQ * CD / 4;
    int tid = (b - 512) * 256 + threadIdx.x;
    const float* src = (tid < NF4) ? q : k;
    f16* dst = (tid < NF4) ? q16 : k16;
    int i = (tid < NF4) ? tid : tid - NF4;
    float4 v = reinterpret_cast<const float4*>(src)[i];
    f16x4 o = {(f16)v.x, (f16)v.y, (f16)v.z, (f16)v.w};
    reinterpret_cast<f16x4*>(dst)[i] = o;
  } else {                              // W -> WT f16
    __shared__ float t[64][65];
    const int idx = b - 16896;
    const int z = idx >> 8;
    const int rem = idx & 255;
    const float* W = (z == 0) ? Wq : (z == 1) ? Wk : Wv;
    f16* WT = (z == 0) ? WqT : (z == 1) ? WkvT : WkvT + 1024 * 1024;
    int k0 = (rem & 15) * 64, n0 = (rem >> 4) * 64;
    int tx = threadIdx.x & 63, ty = threadIdx.x >> 6;
#pragma unroll
    for (int i = 0; i < 16; i++)
      t[ty + 4 * i][tx] = W[(size_t)(k0 + ty + 4 * i) * CD + n0 + tx];
    __syncthreads();
#pragma unroll
    for (int i = 0; i < 16; i++)
      WT[(size_t)(n0 + 4 * i + ty) * CD + k0 + tx] = (f16)t[tx][ty + 4 * i];
  }
}

// ---------- f16 transpose: out[b][d][n] = in[b][n][d] ----------
__global__ __launch_bounds__(256) void transpose_kernel(const f16* __restrict__ in,
                                                        f16* __restrict__ out,
                                                        int ldi) {
  __shared__ f16 t[64][65];
  int n0 = blockIdx.x * 64, d0 = blockIdx.y * 64;
  size_t ibase = (size_t)blockIdx.z * CNK * ldi;
  size_t obase = (size_t)blockIdx.z * CNK * CD;
  int tx = threadIdx.x & 63, ty = threadIdx.x >> 6;
#pragma unroll
  for (int i = 0; i < 16; i++)
    t[ty + 4 * i][tx] = in[ibase + (size_t)(n0 + ty + 4 * i) * ldi + d0 + tx];
  __syncthreads();
#pragma unroll
  for (int i = 0; i < 16; i++)
    out[obase + (size_t)(d0 + ty + 4 * i) * CNK + n0 + tx] = t[tx][ty + 4 * i];
}

// ================= 3-stage counted-pipeline GEMM core (256x128) =================
// 8 waves (2x4), BK=64, TRIPLE-buffered LDS (two tiles always in flight),
// T2 XOR-swizzle via pre-swizzled global source, counted vmcnt(12/6/0).
template <int BM, int BN>
__device__ __forceinline__ void gemm_core3(
    const f16* __restrict__ Ab, const f16* __restrict__ Bb,
    int lda, int ldb, int K, int m0, int n0, f16* sm,
    f32x4 (&acc)[BM / 32][BN / 64]) {
  constexpr int FM = BM / 32, FN = BN / 64;     // 8, 2
  constexpr int TI = (BM + BN) / 64;            // 6
  constexpr int bufsz = (BM + BN) * 64;         // f16 elements per buffer
  const int tid = threadIdx.x;
  const int lane = tid & 63, wid = tid >> 6;
  const int wr = wid >> 2, wc = wid & 3;
  const int lrow = lane & 15, kg = lane >> 4;

  auto stage = [&](int i, int kt, int buf) {
    const int s = i * 512 + tid;          // 16B slot
    const int row = s >> 3;
    const int cb = (s & 7) << 4;
    const int scb = cb ^ ((row & 7) << 4);  // pre-swizzled global source col
    const f16* src = (i < BM / 64)
        ? Ab + (size_t)(m0 + row) * lda + kt * 64 + (scb >> 1)
        : Bb + (size_t)(n0 + row - BM) * ldb + kt * 64 + (scb >> 1);
    async16(src, &sm[buf * bufsz + s * 8]);
  };

  const int NT = K >> 6;
#pragma unroll
  for (int i = 0; i < TI; i++) stage(i, 0, 0);
#pragma unroll
  for (int i = 0; i < TI; i++) stage(i, 1, 1);

  for (int t = 0; t < NT; ++t) {
    if (t + 2 < NT) {
      const int b2 = (t + 2) % 3;
#pragma unroll
      for (int i = 0; i < TI; i++) stage(i, t + 2, b2);
      asm volatile("s_waitcnt vmcnt(12)" ::: "memory");
    } else if (t + 2 == NT) {
      asm volatile("s_waitcnt vmcnt(6)" ::: "memory");
    } else {
      asm volatile("s_waitcnt vmcnt(0)" ::: "memory");
    }
    __builtin_amdgcn_s_barrier();

    const f16* smA = sm + (t % 3) * bufsz;
    const f16* smB = smA + BM * 64;
#pragma unroll
    for (int kk = 0; kk < 2; ++kk) {
      const int Cb = kk * 64 + kg * 16;
      f16x8 af[FM], bf[FN];
#pragma unroll
      for (int m = 0; m < FM; ++m) {
        const int ar = wr * (BM / 2) + m * 16 + lrow;
        af[m] = *reinterpret_cast<const f16x8*>(
            &smA[ar * 64 + ((Cb ^ ((ar & 7) << 4)) >> 1)]);
      }
#pragma unroll
      for (int n = 0; n < FN; ++n) {
        const int br = wc * (BN / 4) + n * 16 + lrow;
        bf[n] = *reinterpret_cast<const f16x8*>(
            &smB[br * 64 + ((Cb ^ ((br & 7) << 4)) >> 1)]);
      }
      __builtin_amdgcn_s_barrier();
      __builtin_amdgcn_s_setprio(1);
#pragma unroll
      for (int m = 0; m < FM; ++m)
#pragma unroll
        for (int n = 0; n < FN; ++n)
          acc[m][n] = __builtin_amdgcn_mfma_f32_16x16x32_f16(af[m], bf[n], acc[m][n], 0, 0, 0);
      __builtin_amdgcn_s_setprio(0);
      __builtin_amdgcn_s_barrier();
    }
  }
}

// ---------- epilogue: f16 store, LDS-staged ----------
template <int BM, int BN>
__device__ __forceinline__ void epi_f16(
    f32x4 (&acc)[BM / 32][BN / 64], f16* sm, f16* Cp, int ldc, int m0, int n0) {
  const int tid = threadIdx.x, lane = tid & 63, wid = tid >> 6;
  const int wr = wid >> 2, wc = wid & 3;
  const int rbase = wr * (BM / 2) + (lane >> 4) * 4;
  const int cbase = wc * (BN / 4) + (lane & 15);
  __syncthreads();
#pragma unroll
  for (int mg = 0; mg < BM / 32; mg++)
#pragma unroll
    for (int n = 0; n < BN / 64; n++)
#pragma unroll
      for (int r = 0; r < 4; r++)
        sm[(rbase + mg * 16 + r) * BN + cbase + n * 16] = (f16)acc[mg][n][r];
  __syncthreads();
  constexpr int CH = BM * BN / (512 * 8);
#pragma unroll
  for (int c = 0; c < CH; c++) {
    const int idx = c * 512 + tid;
    const int row = idx / (BN / 8);
    const int cole = (idx % (BN / 8)) * 8;
    f16x8 v = *reinterpret_cast<const f16x8*>(&sm[row * BN + cole]);
    *reinterpret_cast<f16x8*>(Cp + (size_t)(m0 + row) * ldc + n0 + cole) = v;
  }
}

// ---------- epilogue: exp()->f16 store + per-coltile row sums ----------
// SL = BN/8 slots per row; each row is produced by exactly one SL-lane group.
template <int BM, int BN>
__device__ __forceinline__ void epi_exp(
    f32x4 (&acc)[BM / 32][BN / 64], f16* sm, float* psum, f16* Cp, int ldc,
    int m0, int n0, float scale, float* PSrow) {
  constexpr int SL = BN / 8;             // 16B slots per row
  const int tid = threadIdx.x, lane = tid & 63, wid = tid >> 6;
  const int wr = wid >> 2, wc = wid & 3;
  const int rbase = wr * (BM / 2) + (lane >> 4) * 4;
  const int cbase = wc * (BN / 4) + (lane & 15);
  __syncthreads();
#pragma unroll
  for (int mg = 0; mg < BM / 32; mg++)
#pragma unroll
    for (int n = 0; n < BN / 64; n++)
#pragma unroll
      for (int r = 0; r < 4; r++)
        sm[(rbase + mg * 16 + r) * BN + cbase + n * 16] =
            (f16)__expf(acc[mg][n][r] * scale);
  __syncthreads();
  constexpr int CH = BM * BN / (512 * 8);
#pragma unroll
  for (int c = 0; c < CH; c++) {
    const int idx = c * 512 + tid;
    const int row = idx / SL;
    const int cole = (idx % SL) * 8;
    f16x8 v = *reinterpret_cast<const f16x8*>(&sm[row * BN + cole]);
    *reinterpret_cast<f16x8*>(Cp + (size_t)(m0 + row) * ldc + n0 + cole) = v;
    float p = 0.f;
#pragma unroll
    for (int j = 0; j < 8; j++) p += (float)v[j];
#pragma unroll
    for (int o = 1; o < SL; o <<= 1) p += __shfl_xor(p, o);
    if ((lane & (SL - 1)) == 0) psum[row] = p;   // one writer per row
  }
  __syncthreads();
  if (tid < BM) PSrow[tid] = psum[tid];
}

// ---------- epilogue: f32 store, LDS-staged (two half-passes) ----------
template <int BM, int BN>
__device__ __forceinline__ void epi_f32(
    f32x4 (&acc)[BM / 32][BN / 64], f16* smh, float* Cp, int ldc, int m0, int n0) {
  float* st = (float*)smh;
  const int tid = threadIdx.x, lane = tid & 63, wid = tid >> 6;
  const int wr = wid >> 2, wc = wid & 3;
  const int cbase = wc * (BN / 4) + (lane & 15);
#pragma unroll
  for (int half = 0; half < 2; half++) {
    __syncthreads();
    if (wr == half) {
#pragma unroll
      for (int mg = 0; mg < BM / 32; mg++)
#pragma unroll
        for (int r = 0; r < 4; r++) {
          const int rloc = (lane >> 4) * 4 + mg * 16 + r;
#pragma unroll
          for (int n = 0; n < BN / 64; n++)
            st[rloc * BN + cbase + n * 16] = acc[mg][n][r];
        }
    }
    __syncthreads();
    constexpr int CH = (BM / 2) * BN / (512 * 4);
#pragma unroll
    for (int c = 0; c < CH; c++) {
      const int idx = c * 512 + tid;
      const int row = idx / (BN / 4);
      const int cole = (idx % (BN / 4)) * 4;
      float4 v = *reinterpret_cast<const float4*>(&st[row * BN + cole]);
      *reinterpret_cast<float4*>(
          Cp + (size_t)(m0 + half * (BM / 2) + row) * ldc + n0 + cole) = v;
    }
  }
}

// ---------- fused input GEMM: blocks 0-255 q@WqT, 256-767 k@WkvT ----------
__global__ __launch_bounds__(512) void gemmIn_kernel(
    const f16* __restrict__ q16, const f16* __restrict__ WqT, f16* __restrict__ tmpq,
    const f16* __restrict__ k16, const f16* __restrict__ WkvT, f16* __restrict__ tmp2) {
  __shared__ __attribute__((aligned(16))) f16 sm[3 * (256 + 128) * 64];
  const int b = blockIdx.x;                       // 768
  const int swz = (b & 7) * 96 + (b >> 3);        // bijective XCD swizzle
  const f16 *A, *B;
  f16* C;
  int ldc, m0, n0;
  if (swz < 256) {
    const int by = swz >> 5, bx = swz & 31;
    A = q16; B = WqT; C = tmpq; ldc = 1024; m0 = bx * 256; n0 = by * 128;
  } else {
    const int idx = swz - 256;
    const int by = idx >> 5, bx = idx & 31;
    A = k16; B = WkvT; C = tmp2; ldc = 2048; m0 = bx * 256; n0 = by * 128;
  }
  f32x4 acc[8][2] = {};
  gemm_core3<256, 128>(A, B, 1024, 1024, 1024, m0, n0, sm, acc);
  epi_f16<256, 128>(acc, sm, C, ldc, m0, n0);
}

// ---------- s1 GEMM: e1 = exp(qn.kn^T/32), 16 col-tile partial sums ----------
__global__ __launch_bounds__(512) void gemmS1_kernel(
    const f16* __restrict__ qn, const f16* __restrict__ kn,
    f16* __restrict__ e1, float* __restrict__ PS) {
  __shared__ __attribute__((aligned(16))) f16 sm[3 * (256 + 128) * 64];
  __shared__ float psum[256];
  const int b = blockIdx.x;                       // 512
  const int swz = (b & 7) * 64 + (b >> 3);
  const int bz = swz >> 7;
  const int rem = swz & 127;
  const int by = rem >> 3, bx = rem & 7;
  const int m0 = bx * 256, n0 = by * 128;
  const f16* Ab = qn + (size_t)bz * 2048 * 1024;
  const f16* Bb = kn + (size_t)bz * 2048 * 2048;
  f16* Cp = e1 + (size_t)bz * 2048 * 2048;
  f32x4 acc[8][2] = {};
  gemm_core3<256, 128>(Ab, Bb, 1024, 2048, 1024, m0, n0, sm, acc);
  epi_exp<256, 128>(acc, sm, psum, Cp, 2048, m0, n0, 0.03125f,
                    PS + (size_t)by * 8192 + bz * 2048 + m0);
}

// ---------- out GEMM: out = e2n @ vn ----------
__global__ __launch_bounds__(512) void gemmOut_kernel(
    const f16* __restrict__ e2, const f16* __restrict__ vnT, float* __restrict__ out) {
  __shared__ __attribute__((aligned(16))) f16 sm[3 * (256 + 128) * 64];
  const int b = blockIdx.x;                       // 256
  const int swz = (b & 7) * 32 + (b >> 3);
  const int bz = swz >> 6;
  const int rem = swz & 63;
  const int by = rem >> 3, bx = rem & 7;
  const int m0 = bx * 256, n0 = by * 128;
  const f16* Ab = e2 + (size_t)bz * 2048 * 2048;
  const f16* Bb = vnT + (size_t)bz * 1024 * 2048;
  float* Cp = out + (size_t)bz * 2048 * 1024;
  f32x4 acc[8][2] = {};
  gemm_core3<256, 128>(Ab, Bb, 2048, 2048, 2048, m0, n0, sm, acc);
  epi_f32<256, 128>(acc, sm, Cp, 1024, m0, n0);
}

// ---------- merged in-place LayerNorm: z=0 q, z=1 k, z=2 v ----------
__global__ __launch_bounds__(256) void ln3_kernel(
    f16* __restrict__ tmpq, f16* __restrict__ tmp2,
    const float* __restrict__ bq, const float* __restrict__ gq, const float* __restrict__ beq,
    const float* __restrict__ bk, const float* __restrict__ gk, const float* __restrict__ bek,
    const float* __restrict__ bv, const float* __restrict__ gv, const float* __restrict__ bev) {
  __shared__ float rs_[4], rq_[4];
  const int z = blockIdx.y;
  f16* rp;
  const float *bias, *g, *beta;
  if (z == 0)      { rp = tmpq + (size_t)blockIdx.x * 1024;        bias = bq; g = gq; beta = beq; }
  else if (z == 1) { rp = tmp2 + (size_t)blockIdx.x * 2048;        bias = bk; g = gk; beta = bek; }
  else             { rp = tmp2 + (size_t)blockIdx.x * 2048 + 1024; bias = bv; g = gv; beta = bev; }
  const int t = threadIdx.x;
  f16x4 v = *reinterpret_cast<const f16x4*>(rp + t * 4);
  float y[4], s = 0.f, q = 0.f;
#pragma unroll
  for (int j = 0; j < 4; j++) {
    y[j] = (float)v[j] + bias[t * 4 + j];
    s += y[j]; q += y[j] * y[j];
  }
#pragma unroll
  for (int o = 32; o; o >>= 1) { s += __shfl_xor(s, o); q += __shfl_xor(q, o); }
  if ((t & 63) == 0) { rs_[t >> 6] = s; rq_[t >> 6] = q; }
  __syncthreads();
  s = rs_[0] + rs_[1] + rs_[2] + rs_[3];
  q = rq_[0] + rq_[1] + rq_[2] + rq_[3];
  const float mean = s * (1.0f / CD);
  const float rstd = rsqrtf(q * (1.0f / CD) - mean * mean + 1e-5f);
  f16x4 o;
#pragma unroll
  for (int j = 0; j < 4; j++) {
    int c = t * 4 + j;
    o[j] = (f16)((y[j] - mean) * rstd * g[c] + beta[c]);
  }
  *reinterpret_cast<f16x4*>(rp + t * 4) = o;
}

// ---------- x-GEMM: xw[z] = e1 @ pos (K half z); also writes att0 = e1*inv1 ----------
__global__ __launch_bounds__(256) void xgemm_kernel(
    const f16* __restrict__ e1, const f16* __restrict__ posTb,
    const float* __restrict__ PS, float* __restrict__ xw, float* __restrict__ att) {
  constexpr int BM = 64, BN = 64;
  __shared__ __attribute__((aligned(16))) f16 As[BM * 32];
  __shared__ __attribute__((aligned(16))) f16 Bs[BN * 32];
  __shared__ float invs[BM];
  const int tid = threadIdx.x;
  const int lane = tid & 63;
  const int wave = tid >> 6;
  const int wr = wave >> 1, wc = wave & 1;
  const int m0 = blockIdx.x * BM;
  const int kbase = blockIdx.z * 1024;
  const int srow = lane >> 2;
  const int scol = (lane & 3) * 8;
  const int lrow = lane & 15;
  const int kg = lane >> 4;

  if (tid < BM) {                 // inv1 for this row block, from PS partials
    float s = 0.f;
#pragma unroll
    for (int j = 0; j < 16; j++) s += PS[j * (CB * CNQ) + m0 + tid];
    invs[tid] = 1.0f / s;
  }

  // att0 row-block base: all 64 rows share the same batch (2048 % 64 == 0)
  const int bb = m0 >> 11, nloc = m0 & (CNQ - 1);
  float* attb = att + ((size_t)(bb << 1) * CNQ + nloc) * CNK + kbase;
  const int arow = tid >> 2, acol = (tid & 3) * 8;

  f32x4 acc[2][2] = {};
  for (int k0 = 0; k0 < 1024; k0 += 32) {
    __syncthreads();
#pragma unroll
    for (int i = wave; i < 8; i += 4) {
      if (i < 4)
        async16(e1 + (size_t)(m0 + i * 16 + srow) * CNK + kbase + k0 + scol, &As[i * 512]);
      else
        async16(posTb + (size_t)((i - 4) * 16 + srow) * CNK + kbase + k0 + scol,
                &Bs[(i - 4) * 512]);
    }
    __syncthreads();
    f16x8 af[2], bfr[2];
#pragma unroll
    for (int m = 0; m < 2; m++)
      af[m] = *reinterpret_cast<const f16x8*>(&As[(wr * 32 + m * 16 + lrow) * 32 + kg * 8]);
#pragma unroll
    for (int n = 0; n < 2; n++)
      bfr[n] = *reinterpret_cast<const f16x8*>(&Bs[(wc * 32 + n * 16 + lrow) * 32 + kg * 8]);
#pragma unroll
    for (int m = 0; m < 2; m++)
#pragma unroll
      for (int n = 0; n < 2; n++)
        acc[m][n] = __builtin_amdgcn_mfma_f32_16x16x32_f16(af[m], bfr[n], acc[m][n], 0, 0, 0);
    // att0 write from the staged e1 tile: row arow, cols acol..+7 of this k-chunk
    {
      const float iv = invs[arow];
      f16x8 v = *reinterpret_cast<const f16x8*>(&As[arow * 32 + acol]);
      float4 w0 = {(float)v[0] * iv, (float)v[1] * iv, (float)v[2] * iv, (float)v[3] * iv};
      float4 w1 = {(float)v[4] * iv, (float)v[5] * iv, (float)v[6] * iv, (float)v[7] * iv};
      float* ap = attb + (size_t)arow * CNK + k0 + acol;
      reinterpret_cast<float4*>(ap)[0] = w0;
      reinterpret_cast<float4*>(ap)[1] = w1;
    }
  }
  float* Cp = xw + (size_t)blockIdx.z * (CB * CNQ) * CP;
  const int crow = m0 + wr * 32 + (lane >> 4) * 4;
  const int ccol = wc * 32 + (lane & 15);
#pragma unroll
  for (int m = 0; m < 2; m++)
#pragma unroll
    for (int n = 0; n < 2; n++)
#pragma unroll
      for (int r = 0; r < 4; r++)
        Cp[(size_t)(crow + m * 16 + r) * CP + ccol + n * 16] = acc[m][n][r];
}

// ---------- attn2: x'=(x*inv1)@Wp+bp; e=exp(x'.pos^T/8); writes normalized
//            att head-1 (f32) and normalized e2 (f16) ----------
__global__ __launch_bounds__(128) void attn2_kernel(
    const float* __restrict__ xw, const float* __restrict__ Wp,
    const float* __restrict__ bp, const f16* __restrict__ posb,
    const float* __restrict__ PS, f16* __restrict__ e2,
    float* __restrict__ att) {
  // e2lds [32][2048] f16 (128KB) || xpb [32][64] f16 (4KB);
  // xs (8KB f32) + Wps (16KB f32) alias e2lds head (dead before e2lds use).
  __shared__ __attribute__((aligned(16))) f16 shm[32 * 2048 + 32 * 64];
  __shared__ float rsum[32];
  __shared__ float invs[32];
  f16* e2lds = shm;
  f16* xpb = shm + 32 * 2048;
  float* xs = (float*)shm;              // [32][64]
  float* Wps = (float*)shm + 32 * 64;   // [64][64]
  const int tid = threadIdx.x, l = tid & 63, w = tid >> 6;
  const int r0 = blockIdx.x * 32;
  if (tid < 32) {
    float s = 0.f;
#pragma unroll
    for (int j = 0; j < 16; j++) s += PS[j * (CB * CNQ) + r0 + tid];
    invs[tid] = 1.0f / s;
  }
  __syncthreads();
#pragma unroll
  for (int i = 0; i < 16; i++) {
    const int row = w * 16 + i;
    const size_t gi = (size_t)(r0 + row) * CP + l;
    xs[row * 64 + l] = (xw[gi] + xw[(size_t)(CB * CNQ) * CP + gi]) * invs[row];
  }
#pragma unroll
  for (int i = w; i < 64; i += 2) Wps[i * 64 + l] = Wp[i * 64 + l];
  const float bpl = bp[l];
  __syncthreads();
  const int rb = w * 16;
#pragma unroll 2
  for (int i = 0; i < 16; i++) {
    float a = bpl;
#pragma unroll 8
    for (int p = 0; p < 64; p++) a = fmaf(xs[(rb + i) * 64 + p], Wps[p * 64 + l], a);
    xpb[(rb + i) * 64 + l] = (f16)a;
  }
  __syncthreads();                       // xs/Wps dead; e2lds region free now
  const f16x8 af0 = *reinterpret_cast<const f16x8*>(&xpb[(rb + (l & 15)) * 64 + (l >> 4) * 8]);
  const f16x8 af1 = *reinterpret_cast<const f16x8*>(&xpb[(rb + (l & 15)) * 64 + 32 + (l >> 4) * 8]);
  float rs[4] = {0.f, 0.f, 0.f, 0.f};
  for (int jt = 0; jt < CNK / 64; jt++) {
#pragma unroll
    for (int q4 = 0; q4 < 4; q4++) {
      const int j = jt * 64 + q4 * 16 + (l & 15);
      const f16* pp = posb + (size_t)j * CP + (l >> 4) * 8;
      f16x8 b0 = *reinterpret_cast<const f16x8*>(pp);
      f16x8 b1 = *reinterpret_cast<const f16x8*>(pp + 32);
      f32x4 c = {};
      c = __builtin_amdgcn_mfma_f32_16x16x32_f16(af0, b0, c, 0, 0, 0);
      c = __builtin_amdgcn_mfma_f32_16x16x32_f16(af1, b1, c, 0, 0, 0);
#pragma unroll
      for (int r = 0; r < 4; r++) {
        float ev = __expf(c[r] * 0.125f);
        rs[r] += ev;
        e2lds[(rb + (l >> 4) * 4 + r) * 2048 + j] = (f16)ev;
      }
    }
  }
#pragma unroll
  for (int r = 0; r < 4; r++) {
#pragma unroll
    for (int o = 1; o < 16; o <<= 1) rs[r] += __shfl_xor(rs[r], o);
    if ((l & 15) == 0) rsum[rb + (l >> 4) * 4 + r] = rs[r];
  }
  __syncthreads();
  const int b = r0 >> 11, nloc = r0 & (CNQ - 1);
  float* attb = att + ((size_t)((b << 1) + 1) * CNQ + nloc) * CNK;
  f16* e2b = e2 + (size_t)r0 * CNK;
  for (int row = 0; row < 32; row++) {
    const float iv = 1.0f / rsum[row];
    const f16x8 a0 = *reinterpret_cast<const f16x8*>(&e2lds[row * 2048 + tid * 16]);
    const f16x8 a1 = *reinterpret_cast<const f16x8*>(&e2lds[row * 2048 + tid * 16 + 8]);
    float4 w0 = {(float)a0[0] * iv, (float)a0[1] * iv, (float)a0[2] * iv, (float)a0[3] * iv};
    float4 w1 = {(float)a0[4] * iv, (float)a0[5] * iv, (float)a0[6] * iv, (float)a0[7] * iv};
    float4 w2 = {(float)a1[0] * iv, (float)a1[1] * iv, (float)a1[2] * iv, (float)a1[3] * iv};
    float4 w3 = {(float)a1[4] * iv, (float)a1[5] * iv, (float)a1[6] * iv, (float)a1[7] * iv};
    float* ap = attb + (size_t)row * CNK + tid * 16;
    reinterpret_cast<float4*>(ap)[0] = w0;
    reinterpret_cast<float4*>(ap)[1] = w1;
    reinterpret_cast<float4*>(ap)[2] = w2;
    reinterpret_cast<float4*>(ap)[3] = w3;
    f16x8 h0 = {(f16)w0.x, (f16)w0.y, (f16)w0.z, (f16)w0.w,
                (f16)w1.x, (f16)w1.y, (f16)w1.z, (f16)w1.w};
    f16x8 h1 = {(f16)w2.x, (f16)w2.y, (f16)w2.z, (f16)w2.w,
                (f16)w3.x, (f16)w3.y, (f16)w3.z, (f16)w3.w};
    f16* ep = e2b + (size_t)row * CNK + tid * 16;
    *reinterpret_cast<f16x8*>(ep)     = h0;
    *reinterpret_cast<f16x8*>(ep + 8) = h1;
  }
}

extern "C" void kernel_launch(void* const* d_in, const int* in_sizes, int n_in,
                              void* d_out, int out_size, void* d_ws, size_t ws_size,
                              hipStream_t stream) {
  (void)in_sizes; (void)n_in; (void)out_size; (void)ws_size;
  const float* q    = (const float*)d_in[0];
  const float* k    = (const float*)d_in[1];
  const float* Wq   = (const float*)d_in[2];
  const float* bq   = (const float*)d_in[3];
  const float* Wk   = (const float*)d_in[4];
  const float* bk   = (const float*)d_in[5];
  const float* Wv   = (const float*)d_in[6];
  const float* bv   = (const float*)d_in[7];
  const float* gq   = (const float*)d_in[8];
  const float* betaq= (const float*)d_in[9];
  const float* gk   = (const float*)d_in[10];
  const float* betak= (const float*)d_in[11];
  const float* gv   = (const float*)d_in[12];
  const float* betav= (const float*)d_in[13];
  const float* Wp   = (const float*)d_in[14];
  const float* bp   = (const float*)d_in[15];

  float* out = (float*)d_out;
  float* att = out + (size_t)CB * CNQ * CD;   // [B,2,NQ,NK]
  char* ws = (char*)d_ws;
  const size_t MB = 1ull << 20;

  f16* q16   = (f16*)(ws);                     // 0-16MB, dead after gemmIn
  f16* k16   = (f16*)(ws + 16 * MB);           // 16-32, dead after gemmIn
  f16* e1    = (f16*)(ws);                     // 0-32 (after q16/k16 die)
  f16* e2    = (f16*)(ws);                     // 0-32 (after e1 dies)
  f16* WqT   = (f16*)(ws + 32 * MB);           // 2MB
  f16* WkvT  = (f16*)(ws + 34 * MB);           // 4MB
  f16* posb  = (f16*)(ws + 38 * MB);           // 256KB
  f16* posTb = (f16*)(ws + 38 * MB + 256 * 1024);
  float* xw  = (float*)(ws + 38 * MB + 512 * 1024); // 4MB [2][8192][64]
  float* PS  = (float*)(ws + 42 * MB + 512 * 1024); // 512KB [16][8192]
  f16* tmpq  = (f16*)(ws + 43 * MB);           // 16MB (qn in place)
  f16* tmp2  = (f16*)(ws + 59 * MB);           // 32MB (kn|vn in place)
  f16* vnT   = (f16*)(ws + 91 * MB);           // 16MB (ends 107MB)
  f16* qn = tmpq;
  f16* kn = tmp2;            // ld 2048, cols 0-1023
  f16* vn = tmp2 + 1024;     // ld 2048, cols 1024-2047

  prep_kernel<<<512 + 16384 + 768, 256, 0, stream>>>(
      q, k, Wq, Wk, Wv, q16, k16, WqT, WkvT, posb, posTb);

  gemmIn_kernel<<<768, 512, 0, stream>>>(q16, WqT, tmpq, k16, WkvT, tmp2);
  ln3_kernel<<<dim3(CB * CNQ, 3), 256, 0, stream>>>(
      tmpq, tmp2, bq, gq, betaq, bk, gk, betak, bv, gv, betav);
  transpose_kernel<<<dim3(CNK / 64, CD / 64, CB), 256, 0, stream>>>(vn, vnT, 2048);

  gemmS1_kernel<<<512, 512, 0, stream>>>(qn, kn, e1, PS);

  xgemm_kernel<<<dim3(CB * CNQ / 64, 1, 2), 256, 0, stream>>>(e1, posTb, PS, xw, att);
  attn2_kernel<<<CB * CNQ / 32, 128, 0, stream>>>(xw, Wp, bp, posb, PS, e2, att);

  gemmOut_kernel<<<256, 512, 0, stream>>>(e2, vnT, out);
}

// Round 8
// 296.759 us; speedup vs baseline: 1.3809x; 1.0909x over previous
//
#include <hip/hip_runtime.h>
#include <math.h>
#include <stdint.h>

// BlindCrossAttention on MI355X (gfx950).
// Round 8: fatter per-wave tiles (In/Out 128x256, S1 256x256 -> less LDS/FLOP),
// counted full-tile prefetch dbuf core (round-5-verified inner structure),
// attn2 4-wave j-split. PS = 8 partials everywhere.

typedef _Float16 f16;
typedef _Float16 f16x4 __attribute__((ext_vector_type(4)));
typedef _Float16 f16x8 __attribute__((ext_vector_type(8)));
typedef float f32x4 __attribute__((ext_vector_type(4)));

static constexpr int CB  = 4;
static constexpr int CNQ = 2048;
static constexpr int CNK = 2048;
static constexpr int CD  = 1024;
static constexpr int CP  = 64;

// ---------- async global->LDS, 16B/lane ----------
static __device__ __forceinline__ void async16(const f16* gp, f16* lp) {
  __builtin_amdgcn_global_load_lds(
      (const __attribute__((address_space(1))) void*)(uintptr_t)gp,
      (__attribute__((address_space(3))) void*)(uint32_t)(uintptr_t)lp,
      16, 0, 0);
}

// ---------- prep: pos table + cvt q,k -> f16 + transpose-cvt W's ----------
__global__ __launch_bounds__(256) void prep_kernel(
    const float* __restrict__ q, const float* __restrict__ k,
    const float* __restrict__ Wq, const float* __restrict__ Wk,
    const float* __restrict__ Wv,
    f16* __restrict__ q16, f16* __restrict__ k16,
    f16* __restrict__ WqT, f16* __restrict__ WkvT,
    f16* __restrict__ posb, f16* __restrict__ posTb) {
  const int b = blockIdx.x;
  if (b < 512) {                        // pos table
    int tid = b * 256 + threadIdx.x;
    int p = tid >> 11;
    int j = tid & (CNK - 1);
    int i = p & 31;
    float ph = (float)j * powf(10000.0f, -(float)i * (1.0f / 32.0f));
    float v = (p < 32) ? sinf(ph) : cosf(ph);
    posb[j * CP + p]   = (f16)v;
    posTb[p * CNK + j] = (f16)v;
  } else if (b < 512 + 16384) {         // cvt q,k
    const int NF4 = CB * CNQ * CD / 4;
    int tid = (b - 512) * 256 + threadIdx.x;
    const float* src = (tid < NF4) ? q : k;
    f16* dst = (tid < NF4) ? q16 : k16;
    int i = (tid < NF4) ? tid : tid - NF4;
    float4 v = reinterpret_cast<const float4*>(src)[i];
    f16x4 o = {(f16)v.x, (f16)v.y, (f16)v.z, (f16)v.w};
    reinterpret_cast<f16x4*>(dst)[i] = o;
  } else {                              // W -> WT f16
    __shared__ float t[64][65];
    const int idx = b - 16896;
    const int z = idx >> 8;
    const int rem = idx & 255;
    const float* W = (z == 0) ? Wq : (z == 1) ? Wk : Wv;
    f16* WT = (z == 0) ? WqT : (z == 1) ? WkvT : WkvT + 1024 * 1024;
    int k0 = (rem & 15) * 64, n0 = (rem >> 4) * 64;
    int tx = threadIdx.x & 63, ty = threadIdx.x >> 6;
#pragma unroll
    for (int i = 0; i < 16; i++)
      t[ty + 4 * i][tx] = W[(size_t)(k0 + ty + 4 * i) * CD + n0 + tx];
    __syncthreads();
#pragma unroll
    for (int i = 0; i < 16; i++)
      WT[(size_t)(n0 + 4 * i + ty) * CD + k0 + tx] = (f16)t[tx][ty + 4 * i];
  }
}

// ---------- f16 transpose: out[b][d][n] = in[b][n][d] ----------
__global__ __launch_bounds__(256) void transpose_kernel(const f16* __restrict__ in,
                                                        f16* __restrict__ out,
                                                        int ldi) {
  __shared__ f16 t[64][65];
  int n0 = blockIdx.x * 64, d0 = blockIdx.y * 64;
  size_t ibase = (size_t)blockIdx.z * CNK * ldi;
  size_t obase = (size_t)blockIdx.z * CNK * CD;
  int tx = threadIdx.x & 63, ty = threadIdx.x >> 6;
#pragma unroll
  for (int i = 0; i < 16; i++)
    t[ty + 4 * i][tx] = in[ibase + (size_t)(n0 + ty + 4 * i) * ldi + d0 + tx];
  __syncthreads();
#pragma unroll
  for (int i = 0; i < 16; i++)
    out[obase + (size_t)(d0 + ty + 4 * i) * CNK + n0 + tx] = t[tx][ty + 4 * i];
}

// ============ counted-prefetch dbuf GEMM core, wide waves (FN==4) ============
// 8 waves (2x4), per-wave output (BM/2)x64.  BK=64, double-buffered LDS,
// T2 XOR-swizzle via pre-swizzled global src, full next-tile issue at tile
// head + counted vmcnt(TI).  Inner 4-phase MH structure (round-5-verified).
template <int BM, int BN>
__device__ __forceinline__ void gemm_core(
    const f16* __restrict__ Ab, const f16* __restrict__ Bb,
    int lda, int ldb, int K, int m0, int n0, f16* sm,
    f32x4 (&acc)[BM / 32][4]) {
  constexpr int FM = BM / 32;           // 4 or 8
  constexpr int FMC = FM / 2;
  constexpr int TI = (BM + BN) / 64;    // 6 or 8
  constexpr int bufsz = (BM + BN) * 64;
  const int tid = threadIdx.x;
  const int lane = tid & 63, wid = tid >> 6;
  const int wr = wid >> 2, wc = wid & 3;
  const int lrow = lane & 15, kg = lane >> 4;

  auto stage = [&](int i, int kt, int buf) {
    const int s = i * 512 + tid;          // 16B slot
    const int row = s >> 3;
    const int cb = (s & 7) << 4;
    const int scb = cb ^ ((row & 7) << 4);  // pre-swizzled global source col
    const f16* src = (i < BM / 64)
        ? Ab + (size_t)(m0 + row) * lda + kt * 64 + (scb >> 1)
        : Bb + (size_t)(n0 + row - BM) * ldb + kt * 64 + (scb >> 1);
    async16(src, &sm[buf * bufsz + s * 8]);
  };

  const int NTk = K >> 6;
#pragma unroll
  for (int i = 0; i < TI; i++) stage(i, 0, 0);

  for (int t = 0; t < NTk; ++t) {
    const int cur = t & 1;
    if (t + 1 < NTk) {
#pragma unroll
      for (int i = 0; i < TI; i++) stage(i, t + 1, cur ^ 1);
      if constexpr (TI == 8) asm volatile("s_waitcnt vmcnt(8)" ::: "memory");
      else                   asm volatile("s_waitcnt vmcnt(6)" ::: "memory");
    } else {
      asm volatile("s_waitcnt vmcnt(0)" ::: "memory");
    }
    __builtin_amdgcn_s_barrier();

    const f16* smA = sm + cur * bufsz;
    const f16* smB = smA + BM * 64;
    f16x8 bf[2][4];
#pragma unroll
    for (int p = 0; p < 4; ++p) {
      const int kk = p >> 1, mh = p & 1;
      const int Cb = kk * 64 + kg * 16;
      f16x8 af[FMC];
#pragma unroll
      for (int m = 0; m < FMC; ++m) {
        const int ar = wr * (BM / 2) + mh * (FMC * 16) + m * 16 + lrow;
        af[m] = *reinterpret_cast<const f16x8*>(
            &smA[ar * 64 + ((Cb ^ ((ar & 7) << 4)) >> 1)]);
      }
      if (mh == 0) {
#pragma unroll
        for (int n = 0; n < 4; ++n) {
          const int br = wc * 64 + n * 16 + lrow;
          bf[kk][n] = *reinterpret_cast<const f16x8*>(
              &smB[br * 64 + ((Cb ^ ((br & 7) << 4)) >> 1)]);
        }
      }
      __builtin_amdgcn_s_barrier();
      __builtin_amdgcn_s_setprio(1);
#pragma unroll
      for (int m = 0; m < FMC; ++m)
#pragma unroll
        for (int n = 0; n < 4; ++n)
          acc[mh * FMC + m][n] = __builtin_amdgcn_mfma_f32_16x16x32_f16(
              af[m], bf[kk][n], acc[mh * FMC + m][n], 0, 0, 0);
      __builtin_amdgcn_s_setprio(0);
      __builtin_amdgcn_s_barrier();
    }
  }
}

// ---------- epilogue: f16 store, LDS-staged ----------
template <int BM, int BN>
__device__ __forceinline__ void epi_f16(
    f32x4 (&acc)[BM / 32][4], f16* sm, f16* Cp, int ldc, int m0, int n0) {
  const int tid = threadIdx.x, lane = tid & 63, wid = tid >> 6;
  const int wr = wid >> 2, wc = wid & 3;
  const int rbase = wr * (BM / 2) + (lane >> 4) * 4;
  const int cbase = wc * 64 + (lane & 15);
  __syncthreads();
#pragma unroll
  for (int mg = 0; mg < BM / 32; mg++)
#pragma unroll
    for (int n = 0; n < 4; n++)
#pragma unroll
      for (int r = 0; r < 4; r++)
        sm[(rbase + mg * 16 + r) * BN + cbase + n * 16] = (f16)acc[mg][n][r];
  __syncthreads();
  constexpr int CH = BM * BN / (512 * 8);
#pragma unroll
  for (int c = 0; c < CH; c++) {
    const int idx = c * 512 + tid;
    const int row = idx / (BN / 8);
    const int cole = (idx % (BN / 8)) * 8;
    f16x8 v = *reinterpret_cast<const f16x8*>(&sm[row * BN + cole]);
    *reinterpret_cast<f16x8*>(Cp + (size_t)(m0 + row) * ldc + n0 + cole) = v;
  }
}

// ---------- epilogue: exp()->f16 store + per-coltile row sums ----------
template <int BM, int BN>
__device__ __forceinline__ void epi_exp(
    f32x4 (&acc)[BM / 32][4], f16* sm, float* psum, f16* Cp, int ldc,
    int m0, int n0, float scale, float* PSrow) {
  constexpr int SL = BN / 8;             // 16B slots per row
  const int tid = threadIdx.x, lane = tid & 63, wid = tid >> 6;
  const int wr = wid >> 2, wc = wid & 3;
  const int rbase = wr * (BM / 2) + (lane >> 4) * 4;
  const int cbase = wc * 64 + (lane & 15);
  __syncthreads();
#pragma unroll
  for (int mg = 0; mg < BM / 32; mg++)
#pragma unroll
    for (int n = 0; n < 4; n++)
#pragma unroll
      for (int r = 0; r < 4; r++)
        sm[(rbase + mg * 16 + r) * BN + cbase + n * 16] =
            (f16)__expf(acc[mg][n][r] * scale);
  __syncthreads();
  constexpr int CH = BM * BN / (512 * 8);
#pragma unroll
  for (int c = 0; c < CH; c++) {
    const int idx = c * 512 + tid;
    const int row = idx / SL;
    const int cole = (idx % SL) * 8;
    f16x8 v = *reinterpret_cast<const f16x8*>(&sm[row * BN + cole]);
    *reinterpret_cast<f16x8*>(Cp + (size_t)(m0 + row) * ldc + n0 + cole) = v;
    float p = 0.f;
#pragma unroll
    for (int j = 0; j < 8; j++) p += (float)v[j];
#pragma unroll
    for (int o = 1; o < SL; o <<= 1) p += __shfl_xor(p, o);
    if ((lane & (SL - 1)) == 0) psum[row] = p;   // one writer per row
  }
  __syncthreads();
  if (tid < BM) PSrow[tid] = psum[tid];
}

// ---------- epilogue: f32 store, LDS-staged (two half-passes) ----------
template <int BM, int BN>
__device__ __forceinline__ void epi_f32(
    f32x4 (&acc)[BM / 32][4], f16* smh, float* Cp, int ldc, int m0, int n0) {
  float* st = (float*)smh;               // (BM/2) x BN f32 per half-pass
  const int tid = threadIdx.x, lane = tid & 63, wid = tid >> 6;
  const int wr = wid >> 2, wc = wid & 3;
  const int cbase = wc * 64 + (lane & 15);
#pragma unroll
  for (int half = 0; half < 2; half++) {
    __syncthreads();
    if (wr == half) {
#pragma unroll
      for (int mg = 0; mg < BM / 32; mg++)
#pragma unroll
        for (int r = 0; r < 4; r++) {
          const int rloc = (lane >> 4) * 4 + mg * 16 + r;
#pragma unroll
          for (int n = 0; n < 4; n++)
            st[rloc * BN + cbase + n * 16] = acc[mg][n][r];
        }
    }
    __syncthreads();
    constexpr int CH = (BM / 2) * BN / (512 * 4);
#pragma unroll
    for (int c = 0; c < CH; c++) {
      const int idx = c * 512 + tid;
      const int row = idx / (BN / 4);
      const int cole = (idx % (BN / 4)) * 4;
      float4 v = *reinterpret_cast<const float4*>(&st[row * BN + cole]);
      *reinterpret_cast<float4*>(
          Cp + (size_t)(m0 + half * (BM / 2) + row) * ldc + n0 + cole) = v;
    }
  }
}

// ---------- fused input GEMM (128x256): blocks 0-255 q@WqT, 256-767 k@WkvT ----------
__global__ __launch_bounds__(512) void gemmIn_kernel(
    const f16* __restrict__ q16, const f16* __restrict__ WqT, f16* __restrict__ tmpq,
    const f16* __restrict__ k16, const f16* __restrict__ WkvT, f16* __restrict__ tmp2) {
  __shared__ __attribute__((aligned(16))) f16 sm[2 * (128 + 256) * 64];  // 96KB
  const int b = blockIdx.x;                       // 768
  const int swz = (b & 7) * 96 + (b >> 3);        // bijective XCD swizzle
  const f16 *A, *B;
  f16* C;
  int ldc, m0, n0;
  if (swz < 256) {                                // q: 64 m-tiles x 4 n-tiles
    const int bx = swz & 63, by = swz >> 6;
    A = q16; B = WqT; C = tmpq; ldc = 1024; m0 = bx * 128; n0 = by * 256;
  } else {                                        // kv: 64 m-tiles x 8 n-tiles
    const int idx = swz - 256;
    const int bx = idx & 63, by = idx >> 6;
    A = k16; B = WkvT; C = tmp2; ldc = 2048; m0 = bx * 128; n0 = by * 256;
  }
  f32x4 acc[4][4] = {};
  gemm_core<128, 256>(A, B, 1024, 1024, 1024, m0, n0, sm, acc);
  epi_f16<128, 256>(acc, sm, C, ldc, m0, n0);
}

// ---------- s1 GEMM (256x256): e1 = exp(qn.kn^T/32), 8 col-tile partials ----------
__global__ __launch_bounds__(512) void gemmS1_kernel(
    const f16* __restrict__ qn, const f16* __restrict__ kn,
    f16* __restrict__ e1, float* __restrict__ PS) {
  __shared__ __attribute__((aligned(16))) f16 sm[2 * (256 + 256) * 64];  // 128KB
  __shared__ float psum[256];
  const int b = blockIdx.x;                       // 256
  const int swz = (b & 7) * 32 + (b >> 3);
  const int bz = swz >> 6;
  const int rem = swz & 63;
  const int bx = rem & 7, by = rem >> 3;          // 8 m x 8 n per batch
  const int m0 = bx * 256, n0 = by * 256;
  const f16* Ab = qn + (size_t)bz * 2048 * 1024;
  const f16* Bb = kn + (size_t)bz * 2048 * 2048;
  f16* Cp = e1 + (size_t)bz * 2048 * 2048;
  f32x4 acc[8][4] = {};
  gemm_core<256, 256>(Ab, Bb, 1024, 2048, 1024, m0, n0, sm, acc);
  epi_exp<256, 256>(acc, sm, psum, Cp, 2048, m0, n0, 0.03125f,
                    PS + (size_t)by * (CB * CNQ) + bz * 2048 + m0);
}

// ---------- out GEMM (128x256): out = e2n @ vn ----------
__global__ __launch_bounds__(512) void gemmOut_kernel(
    const f16* __restrict__ e2, const f16* __restrict__ vnT, float* __restrict__ out) {
  __shared__ __attribute__((aligned(16))) f16 sm[2 * (128 + 256) * 64];  // 96KB
  const int b = blockIdx.x;                       // 256
  const int swz = (b & 7) * 32 + (b >> 3);
  const int bz = swz >> 6;
  const int rem = swz & 63;
  const int bx = rem & 15, by = rem >> 4;         // 16 m x 4 n per batch
  const int m0 = bx * 128, n0 = by * 256;
  const f16* Ab = e2 + (size_t)bz * 2048 * 2048;
  const f16* Bb = vnT + (size_t)bz * 1024 * 2048;
  float* Cp = out + (size_t)bz * 2048 * 1024;
  f32x4 acc[4][4] = {};
  gemm_core<128, 256>(Ab, Bb, 2048, 2048, 2048, m0, n0, sm, acc);
  epi_f32<128, 256>(acc, sm, Cp, 1024, m0, n0);
}

// ---------- merged in-place LayerNorm: z=0 q, z=1 k, z=2 v ----------
__global__ __launch_bounds__(256) void ln3_kernel(
    f16* __restrict__ tmpq, f16* __restrict__ tmp2,
    const float* __restrict__ bq, const float* __restrict__ gq, const float* __restrict__ beq,
    const float* __restrict__ bk, const float* __restrict__ gk, const float* __restrict__ bek,
    const float* __restrict__ bv, const float* __restrict__ gv, const float* __restrict__ bev) {
  __shared__ float rs_[4], rq_[4];
  const int z = blockIdx.y;
  f16* rp;
  const float *bias, *g, *beta;
  if (z == 0)      { rp = tmpq + (size_t)blockIdx.x * 1024;        bias = bq; g = gq; beta = beq; }
  else if (z == 1) { rp = tmp2 + (size_t)blockIdx.x * 2048;        bias = bk; g = gk; beta = bek; }
  else             { rp = tmp2 + (size_t)blockIdx.x * 2048 + 1024; bias = bv; g = gv; beta = bev; }
  const int t = threadIdx.x;
  f16x4 v = *reinterpret_cast<const f16x4*>(rp + t * 4);
  float y[4], s = 0.f, q = 0.f;
#pragma unroll
  for (int j = 0; j < 4; j++) {
    y[j] = (float)v[j] + bias[t * 4 + j];
    s += y[j]; q += y[j] * y[j];
  }
#pragma unroll
  for (int o = 32; o; o >>= 1) { s += __shfl_xor(s, o); q += __shfl_xor(q, o); }
  if ((t & 63) == 0) { rs_[t >> 6] = s; rq_[t >> 6] = q; }
  __syncthreads();
  s = rs_[0] + rs_[1] + rs_[2] + rs_[3];
  q = rq_[0] + rq_[1] + rq_[2] + rq_[3];
  const float mean = s * (1.0f / CD);
  const float rstd = rsqrtf(q * (1.0f / CD) - mean * mean + 1e-5f);
  f16x4 o;
#pragma unroll
  for (int j = 0; j < 4; j++) {
    int c = t * 4 + j;
    o[j] = (f16)((y[j] - mean) * rstd * g[c] + beta[c]);
  }
  *reinterpret_cast<f16x4*>(rp + t * 4) = o;
}

// ---------- x-GEMM: xw[z] = e1 @ pos (K half z); also writes att0 = e1*inv1 ----------
__global__ __launch_bounds__(256) void xgemm_kernel(
    const f16* __restrict__ e1, const f16* __restrict__ posTb,
    const float* __restrict__ PS, float* __restrict__ xw, float* __restrict__ att) {
  constexpr int BM = 64, BN = 64;
  __shared__ __attribute__((aligned(16))) f16 As[BM * 32];
  __shared__ __attribute__((aligned(16))) f16 Bs[BN * 32];
  __shared__ float invs[BM];
  const int tid = threadIdx.x;
  const int lane = tid & 63;
  const int wave = tid >> 6;
  const int wr = wave >> 1, wc = wave & 1;
  const int m0 = blockIdx.x * BM;
  const int kbase = blockIdx.z * 1024;
  const int srow = lane >> 2;
  const int scol = (lane & 3) * 8;
  const int lrow = lane & 15;
  const int kg = lane >> 4;

  if (tid < BM) {                 // inv1 from the 8 PS partials
    float s = 0.f;
#pragma unroll
    for (int j = 0; j < 8; j++) s += PS[j * (CB * CNQ) + m0 + tid];
    invs[tid] = 1.0f / s;
  }

  const int bb = m0 >> 11, nloc = m0 & (CNQ - 1);
  float* attb = att + ((size_t)(bb << 1) * CNQ + nloc) * CNK + kbase;
  const int arow = tid >> 2, acol = (tid & 3) * 8;

  f32x4 acc[2][2] = {};
  for (int k0 = 0; k0 < 1024; k0 += 32) {
    __syncthreads();
#pragma unroll
    for (int i = wave; i < 8; i += 4) {
      if (i < 4)
        async16(e1 + (size_t)(m0 + i * 16 + srow) * CNK + kbase + k0 + scol, &As[i * 512]);
      else
        async16(posTb + (size_t)((i - 4) * 16 + srow) * CNK + kbase + k0 + scol,
                &Bs[(i - 4) * 512]);
    }
    __syncthreads();
    f16x8 af[2], bfr[2];
#pragma unroll
    for (int m = 0; m < 2; m++)
      af[m] = *reinterpret_cast<const f16x8*>(&As[(wr * 32 + m * 16 + lrow) * 32 + kg * 8]);
#pragma unroll
    for (int n = 0; n < 2; n++)
      bfr[n] = *reinterpret_cast<const f16x8*>(&Bs[(wc * 32 + n * 16 + lrow) * 32 + kg * 8]);
#pragma unroll
    for (int m = 0; m < 2; m++)
#pragma unroll
      for (int n = 0; n < 2; n++)
        acc[m][n] = __builtin_amdgcn_mfma_f32_16x16x32_f16(af[m], bfr[n], acc[m][n], 0, 0, 0);
    {   // att0 write from staged e1 tile
      const float iv = invs[arow];
      f16x8 v = *reinterpret_cast<const f16x8*>(&As[arow * 32 + acol]);
      float4 w0 = {(float)v[0] * iv, (float)v[1] * iv, (float)v[2] * iv, (float)v[3] * iv};
      float4 w1 = {(float)v[4] * iv, (float)v[5] * iv, (float)v[6] * iv, (float)v[7] * iv};
      float* ap = attb + (size_t)arow * CNK + k0 + acol;
      reinterpret_cast<float4*>(ap)[0] = w0;
      reinterpret_cast<float4*>(ap)[1] = w1;
    }
  }
  float* Cp = xw + (size_t)blockIdx.z * (CB * CNQ) * CP;
  const int crow = m0 + wr * 32 + (lane >> 4) * 4;
  const int ccol = wc * 32 + (lane & 15);
#pragma unroll
  for (int m = 0; m < 2; m++)
#pragma unroll
    for (int n = 0; n < 2; n++)
#pragma unroll
      for (int r = 0; r < 4; r++)
        Cp[(size_t)(crow + m * 16 + r) * CP + ccol + n * 16] = acc[m][n][r];
}

// ---------- attn2 (4 waves, j-split): x'=(x*inv1)@Wp+bp; e=exp(x'.pos^T/8);
//            writes normalized att head-1 (f32) and normalized e2 (f16) ----------
__global__ __launch_bounds__(256) void attn2_kernel(
    const float* __restrict__ xw, const float* __restrict__ Wp,
    const float* __restrict__ bp, const f16* __restrict__ posb,
    const float* __restrict__ PS, f16* __restrict__ e2,
    float* __restrict__ att) {
  // e2lds [32][2048] f16 (128KB) || xpb [32][64] f16 (4KB);
  // xs (8KB f32) + Wps (16KB f32) alias e2lds head (dead before e2lds use).
  __shared__ __attribute__((aligned(16))) f16 shm[32 * 2048 + 32 * 64];
  __shared__ float rsum2[2][32];
  __shared__ float invs[32];
  f16* e2lds = shm;
  f16* xpb = shm + 32 * 2048;
  float* xs = (float*)shm;              // [32][64]
  float* Wps = (float*)shm + 32 * 64;   // [64][64]
  const int tid = threadIdx.x, l = tid & 63, w = tid >> 6;
  const int r0 = blockIdx.x * 32;
  if (tid < 32) {
    float s = 0.f;
#pragma unroll
    for (int j = 0; j < 8; j++) s += PS[j * (CB * CNQ) + r0 + tid];
    invs[tid] = 1.0f / s;
  }
  __syncthreads();
  if (w < 2) {
#pragma unroll
    for (int i = 0; i < 16; i++) {
      const int row = w * 16 + i;
      const size_t gi = (size_t)(r0 + row) * CP + l;
      xs[row * 64 + l] = (xw[gi] + xw[(size_t)(CB * CNQ) * CP + gi]) * invs[row];
    }
#pragma unroll
    for (int i = w; i < 64; i += 2) Wps[i * 64 + l] = Wp[i * 64 + l];
  }
  const float bpl = bp[l];
  __syncthreads();
  const int rb = (w & 1) * 16, jh = w >> 1;
  if (w < 2) {
#pragma unroll 2
    for (int i = 0; i < 16; i++) {
      float a = bpl;
#pragma unroll 8
      for (int p = 0; p < 64; p++) a = fmaf(xs[(w * 16 + i) * 64 + p], Wps[p * 64 + l], a);
      xpb[(w * 16 + i) * 64 + l] = (f16)a;
    }
  }
  __syncthreads();                       // xpb ready; xs/Wps dead -> e2lds free
  const f16x8 af0 = *reinterpret_cast<const f16x8*>(&xpb[(rb + (l & 15)) * 64 + (l >> 4) * 8]);
  const f16x8 af1 = *reinterpret_cast<const f16x8*>(&xpb[(rb + (l & 15)) * 64 + 32 + (l >> 4) * 8]);
  float rs[4] = {0.f, 0.f, 0.f, 0.f};
  for (int jt = jh * 16; jt < jh * 16 + 16; jt++) {
#pragma unroll
    for (int q4 = 0; q4 < 4; q4++) {
      const int j = jt * 64 + q4 * 16 + (l & 15);
      const f16* pp = posb + (size_t)j * CP + (l >> 4) * 8;
      f16x8 b0 = *reinterpret_cast<const f16x8*>(pp);
      f16x8 b1 = *reinterpret_cast<const f16x8*>(pp + 32);
      f32x4 c = {};
      c = __builtin_amdgcn_mfma_f32_16x16x32_f16(af0, b0, c, 0, 0, 0);
      c = __builtin_amdgcn_mfma_f32_16x16x32_f16(af1, b1, c, 0, 0, 0);
#pragma unroll
      for (int r = 0; r < 4; r++) {
        float ev = __expf(c[r] * 0.125f);
        rs[r] += ev;
        e2lds[(rb + (l >> 4) * 4 + r) * 2048 + j] = (f16)ev;
      }
    }
  }
#pragma unroll
  for (int r = 0; r < 4; r++) {
#pragma unroll
    for (int o = 1; o < 16; o <<= 1) rs[r] += __shfl_xor(rs[r], o);
    if ((l & 15) == 0) rsum2[jh][rb + (l >> 4) * 4 + r] = rs[r];
  }
  __syncthreads();
  const int b = r0 >> 11, nloc = r0 & (CNQ - 1);
  float* attb = att + ((size_t)((b << 1) + 1) * CNQ + nloc) * CNK;
  f16* e2b = e2 + (size_t)r0 * CNK;
  // 256 threads: 2 rows per iteration, 128 threads per row
  for (int it = 0; it < 16; it++) {
    const int row = it * 2 + (tid >> 7);
    const int col = (tid & 127) * 16;
    const float iv = 1.0f / (rsum2[0][row] + rsum2[1][row]);
    const f16x8 a0 = *reinterpret_cast<const f16x8*>(&e2lds[row * 2048 + col]);
    const f16x8 a1 = *reinterpret_cast<const f16x8*>(&e2lds[row * 2048 + col + 8]);
    float4 w0 = {(float)a0[0] * iv, (float)a0[1] * iv, (float)a0[2] * iv, (float)a0[3] * iv};
    float4 w1 = {(float)a0[4] * iv, (float)a0[5] * iv, (float)a0[6] * iv, (float)a0[7] * iv};
    float4 w2 = {(float)a1[0] * iv, (float)a1[1] * iv, (float)a1[2] * iv, (float)a1[3] * iv};
    float4 w3 = {(float)a1[4] * iv, (float)a1[5] * iv, (float)a1[6] * iv, (float)a1[7] * iv};
    float* ap = attb + (size_t)row * CNK + col;
    reinterpret_cast<float4*>(ap)[0] = w0;
    reinterpret_cast<float4*>(ap)[1] = w1;
    reinterpret_cast<float4*>(ap)[2] = w2;
    reinterpret_cast<float4*>(ap)[3] = w3;
    f16x8 h0 = {(f16)w0.x, (f16)w0.y, (f16)w0.z, (f16)w0.w,
                (f16)w1.x, (f16)w1.y, (f16)w1.z, (f16)w1.w};
    f16x8 h1 = {(f16)w2.x, (f16)w2.y, (f16)w2.z, (f16)w2.w,
                (f16)w3.x, (f16)w3.y, (f16)w3.z, (f16)w3.w};
    f16* ep = e2b + (size_t)row * CNK + col;
    *reinterpret_cast<f16x8*>(ep)     = h0;
    *reinterpret_cast<f16x8*>(ep + 8) = h1;
  }
}

extern "C" void kernel_launch(void* const* d_in, const int* in_sizes, int n_in,
                              void* d_out, int out_size, void* d_ws, size_t ws_size,
                              hipStream_t stream) {
  (void)in_sizes; (void)n_in; (void)out_size; (void)ws_size;
  const float* q    = (const float*)d_in[0];
  const float* k    = (const float*)d_in[1];
  const float* Wq   = (const float*)d_in[2];
  const float* bq   = (const float*)d_in[3];
  const float* Wk   = (const float*)d_in[4];
  const float* bk   = (const float*)d_in[5];
  const float* Wv   = (const float*)d_in[6];
  const float* bv   = (const float*)d_in[7];
  const float* gq   = (const float*)d_in[8];
  const float* betaq= (const float*)d_in[9];
  const float* gk   = (const float*)d_in[10];
  const float* betak= (const float*)d_in[11];
  const float* gv   = (const float*)d_in[12];
  const float* betav= (const float*)d_in[13];
  const float* Wp   = (const float*)d_in[14];
  const float* bp   = (const float*)d_in[15];

  float* out = (float*)d_out;
  float* att = out + (size_t)CB * CNQ * CD;   // [B,2,NQ,NK]
  char* ws = (char*)d_ws;
  const size_t MB = 1ull << 20;

  f16* q16   = (f16*)(ws);                     // 0-16MB, dead after gemmIn
  f16* k16   = (f16*)(ws + 16 * MB);           // 16-32, dead after gemmIn
  f16* e1    = (f16*)(ws);                     // 0-32 (after q16/k16 die)
  f16* e2    = (f16*)(ws);                     // 0-32 (after e1 dies)
  f16* WqT   = (f16*)(ws + 32 * MB);           // 2MB
  f16* WkvT  = (f16*)(ws + 34 * MB);           // 4MB
  f16* posb  = (f16*)(ws + 38 * MB);           // 256KB
  f16* posTb = (f16*)(ws + 38 * MB + 256 * 1024);
  float* xw  = (float*)(ws + 38 * MB + 512 * 1024); // 4MB [2][8192][64]
  float* PS  = (float*)(ws + 42 * MB + 512 * 1024); // 256KB [8][8192]
  f16* tmpq  = (f16*)(ws + 43 * MB);           // 16MB (qn in place)
  f16* tmp2  = (f16*)(ws + 59 * MB);           // 32MB (kn|vn in place)
  f16* vnT   = (f16*)(ws + 91 * MB);           // 16MB (ends 107MB)
  f16* qn = tmpq;
  f16* kn = tmp2;            // ld 2048, cols 0-1023
  f16* vn = tmp2 + 1024;     // ld 2048, cols 1024-2047

  prep_kernel<<<512 + 16384 + 768, 256, 0, stream>>>(
      q, k, Wq, Wk, Wv, q16, k16, WqT, WkvT, posb, posTb);

  gemmIn_kernel<<<768, 512, 0, stream>>>(q16, WqT, tmpq, k16, WkvT, tmp2);
  ln3_kernel<<<dim3(CB * CNQ, 3), 256, 0, stream>>>(
      tmpq, tmp2, bq, gq, betaq, bk, gk, betak, bv, gv, betav);
  transpose_kernel<<<dim3(CNK / 64, CD / 64, CB), 256, 0, stream>>>(vn, vnT, 2048);

  gemmS1_kernel<<<256, 512, 0, stream>>>(qn, kn, e1, PS);

  xgemm_kernel<<<dim3(CB * CNQ / 64, 1, 2), 256, 0, stream>>>(e1, posTb, PS, xw, att);
  attn2_kernel<<<CB * CNQ / 32, 256, 0, stream>>>(xw, Wp, bp, posb, PS, e2, att);

  gemmOut_kernel<<<256, 512, 0, stream>>>(e2, vnT, out);
}

// Round 9
// 292.466 us; speedup vs baseline: 1.4012x; 1.0147x over previous
//
#include <hip/hip_runtime.h>
#include <math.h>
#include <stdint.h>

// BlindCrossAttention on MI355X (gfx950).
// Round 9: attn2 8-wave 4-way j-split; uniform 2-phase GEMM core (5 barriers
// per K-tile); v-LN folded into transpose (ln3 z=2 = stats only).

typedef _Float16 f16;
typedef _Float16 f16x4 __attribute__((ext_vector_type(4)));
typedef _Float16 f16x8 __attribute__((ext_vector_type(8)));
typedef float f32x4 __attribute__((ext_vector_type(4)));

static constexpr int CB  = 4;
static constexpr int CNQ = 2048;
static constexpr int CNK = 2048;
static constexpr int CD  = 1024;
static constexpr int CP  = 64;

// ---------- async global->LDS, 16B/lane ----------
static __device__ __forceinline__ void async16(const f16* gp, f16* lp) {
  __builtin_amdgcn_global_load_lds(
      (const __attribute__((address_space(1))) void*)(uintptr_t)gp,
      (__attribute__((address_space(3))) void*)(uint32_t)(uintptr_t)lp,
      16, 0, 0);
}

// ---------- prep: pos table + cvt q,k -> f16 + transpose-cvt W's ----------
__global__ __launch_bounds__(256) void prep_kernel(
    const float* __restrict__ q, const float* __restrict__ k,
    const float* __restrict__ Wq, const float* __restrict__ Wk,
    const float* __restrict__ Wv,
    f16* __restrict__ q16, f16* __restrict__ k16,
    f16* __restrict__ WqT, f16* __restrict__ WkvT,
    f16* __restrict__ posb, f16* __restrict__ posTb) {
  const int b = blockIdx.x;
  if (b < 512) {                        // pos table
    int tid = b * 256 + threadIdx.x;
    int p = tid >> 11;
    int j = tid & (CNK - 1);
    int i = p & 31;
    float ph = (float)j * powf(10000.0f, -(float)i * (1.0f / 32.0f));
    float v = (p < 32) ? sinf(ph) : cosf(ph);
    posb[j * CP + p]   = (f16)v;
    posTb[p * CNK + j] = (f16)v;
  } else if (b < 512 + 16384) {         // cvt q,k
    const int NF4 = CB * CNQ * CD / 4;
    int tid = (b - 512) * 256 + threadIdx.x;
    const float* src = (tid < NF4) ? q : k;
    f16* dst = (tid < NF4) ? q16 : k16;
    int i = (tid < NF4) ? tid : tid - NF4;
    float4 v = reinterpret_cast<const float4*>(src)[i];
    f16x4 o = {(f16)v.x, (f16)v.y, (f16)v.z, (f16)v.w};
    reinterpret_cast<f16x4*>(dst)[i] = o;
  } else {                              // W -> WT f16
    __shared__ float t[64][65];
    const int idx = b - 16896;
    const int z = idx >> 8;
    const int rem = idx & 255;
    const float* W = (z == 0) ? Wq : (z == 1) ? Wk : Wv;
    f16* WT = (z == 0) ? WqT : (z == 1) ? WkvT : WkvT + 1024 * 1024;
    int k0 = (rem & 15) * 64, n0 = (rem >> 4) * 64;
    int tx = threadIdx.x & 63, ty = threadIdx.x >> 6;
#pragma unroll
    for (int i = 0; i < 16; i++)
      t[ty + 4 * i][tx] = W[(size_t)(k0 + ty + 4 * i) * CD + n0 + tx];
    __syncthreads();
#pragma unroll
    for (int i = 0; i < 16; i++)
      WT[(size_t)(n0 + 4 * i + ty) * CD + k0 + tx] = (f16)t[tx][ty + 4 * i];
  }
}

// ============ 2-phase counted-prefetch dbuf GEMM core (wide waves) ============
// 8 waves (2x4), per-wave output (BM/2)x64.  BK=64, double-buffered LDS,
// T2 XOR-swizzle via pre-swizzled global src, full next-tile issue at tile
// head + counted vmcnt(TI).  2 phases per K-tile (kk=0,1) -> 5 barriers/tile.
template <int BM, int BN>
__device__ __forceinline__ void gemm_core2(
    const f16* __restrict__ Ab, const f16* __restrict__ Bb,
    int lda, int ldb, int K, int m0, int n0, f16* sm,
    f32x4 (&acc)[BM / 32][4]) {
  constexpr int FM = BM / 32;           // 4 or 8
  constexpr int TI = (BM + BN) / 64;    // 6 or 8
  constexpr int bufsz = (BM + BN) * 64;
  const int tid = threadIdx.x;
  const int lane = tid & 63, wid = tid >> 6;
  const int wr = wid >> 2, wc = wid & 3;
  const int lrow = lane & 15, kg = lane >> 4;

  auto stage = [&](int i, int kt, int buf) {
    const int s = i * 512 + tid;          // 16B slot
    const int row = s >> 3;
    const int cb = (s & 7) << 4;
    const int scb = cb ^ ((row & 7) << 4);  // pre-swizzled global source col
    const f16* src = (i < BM / 64)
        ? Ab + (size_t)(m0 + row) * lda + kt * 64 + (scb >> 1)
        : Bb + (size_t)(n0 + row - BM) * ldb + kt * 64 + (scb >> 1);
    async16(src, &sm[buf * bufsz + s * 8]);
  };

  const int NTk = K >> 6;
#pragma unroll
  for (int i = 0; i < TI; i++) stage(i, 0, 0);

  for (int t = 0; t < NTk; ++t) {
    const int cur = t & 1;
    if (t + 1 < NTk) {
#pragma unroll
      for (int i = 0; i < TI; i++) stage(i, t + 1, cur ^ 1);
      if constexpr (TI == 8) asm volatile("s_waitcnt vmcnt(8)" ::: "memory");
      else                   asm volatile("s_waitcnt vmcnt(6)" ::: "memory");
    } else {
      asm volatile("s_waitcnt vmcnt(0)" ::: "memory");
    }
    __builtin_amdgcn_s_barrier();

    const f16* smA = sm + cur * bufsz;
    const f16* smB = smA + BM * 64;
#pragma unroll
    for (int kk = 0; kk < 2; ++kk) {
      const int Cb = kk * 64 + kg * 16;
      f16x8 af[FM], bf[4];
#pragma unroll
      for (int m = 0; m < FM; ++m) {
        const int ar = wr * (BM / 2) + m * 16 + lrow;
        af[m] = *reinterpret_cast<const f16x8*>(
            &smA[ar * 64 + ((Cb ^ ((ar & 7) << 4)) >> 1)]);
      }
#pragma unroll
      for (int n = 0; n < 4; ++n) {
        const int br = wc * 64 + n * 16 + lrow;
        bf[n] = *reinterpret_cast<const f16x8*>(
            &smB[br * 64 + ((Cb ^ ((br & 7) << 4)) >> 1)]);
      }
      __builtin_amdgcn_s_barrier();
      __builtin_amdgcn_s_setprio(1);
#pragma unroll
      for (int m = 0; m < FM; ++m)
#pragma unroll
        for (int n = 0; n < 4; ++n)
          acc[m][n] = __builtin_amdgcn_mfma_f32_16x16x32_f16(af[m], bf[n], acc[m][n], 0, 0, 0);
      __builtin_amdgcn_s_setprio(0);
      __builtin_amdgcn_s_barrier();
    }
  }
}

// ---------- epilogue: f16 store, LDS-staged ----------
template <int BM, int BN>
__device__ __forceinline__ void epi_f16(
    f32x4 (&acc)[BM / 32][4], f16* sm, f16* Cp, int ldc, int m0, int n0) {
  const int tid = threadIdx.x, lane = tid & 63, wid = tid >> 6;
  const int wr = wid >> 2, wc = wid & 3;
  const int rbase = wr * (BM / 2) + (lane >> 4) * 4;
  const int cbase = wc * 64 + (lane & 15);
  __syncthreads();
#pragma unroll
  for (int mg = 0; mg < BM / 32; mg++)
#pragma unroll
    for (int n = 0; n < 4; n++)
#pragma unroll
      for (int r = 0; r < 4; r++)
        sm[(rbase + mg * 16 + r) * BN + cbase + n * 16] = (f16)acc[mg][n][r];
  __syncthreads();
  constexpr int CH = BM * BN / (512 * 8);
#pragma unroll
  for (int c = 0; c < CH; c++) {
    const int idx = c * 512 + tid;
    const int row = idx / (BN / 8);
    const int cole = (idx % (BN / 8)) * 8;
    f16x8 v = *reinterpret_cast<const f16x8*>(&sm[row * BN + cole]);
    *reinterpret_cast<f16x8*>(Cp + (size_t)(m0 + row) * ldc + n0 + cole) = v;
  }
}

// ---------- epilogue: exp()->f16 store + per-coltile row sums ----------
template <int BM, int BN>
__device__ __forceinline__ void epi_exp(
    f32x4 (&acc)[BM / 32][4], f16* sm, float* psum, f16* Cp, int ldc,
    int m0, int n0, float scale, float* PSrow) {
  constexpr int SL = BN / 8;             // 16B slots per row
  const int tid = threadIdx.x, lane = tid & 63, wid = tid >> 6;
  const int wr = wid >> 2, wc = wid & 3;
  const int rbase = wr * (BM / 2) + (lane >> 4) * 4;
  const int cbase = wc * 64 + (lane & 15);
  __syncthreads();
#pragma unroll
  for (int mg = 0; mg < BM / 32; mg++)
#pragma unroll
    for (int n = 0; n < 4; n++)
#pragma unroll
      for (int r = 0; r < 4; r++)
        sm[(rbase + mg * 16 + r) * BN + cbase + n * 16] =
            (f16)__expf(acc[mg][n][r] * scale);
  __syncthreads();
  constexpr int CH = BM * BN / (512 * 8);
#pragma unroll
  for (int c = 0; c < CH; c++) {
    const int idx = c * 512 + tid;
    const int row = idx / SL;
    const int cole = (idx % SL) * 8;
    f16x8 v = *reinterpret_cast<const f16x8*>(&sm[row * BN + cole]);
    *reinterpret_cast<f16x8*>(Cp + (size_t)(m0 + row) * ldc + n0 + cole) = v;
    float p = 0.f;
#pragma unroll
    for (int j = 0; j < 8; j++) p += (float)v[j];
#pragma unroll
    for (int o = 1; o < SL; o <<= 1) p += __shfl_xor(p, o);
    if ((lane & (SL - 1)) == 0) psum[row] = p;   // one writer per row
  }
  __syncthreads();
  if (tid < BM) PSrow[tid] = psum[tid];
}

// ---------- epilogue: f32 store, LDS-staged (two half-passes) ----------
template <int BM, int BN>
__device__ __forceinline__ void epi_f32(
    f32x4 (&acc)[BM / 32][4], f16* smh, float* Cp, int ldc, int m0, int n0) {
  float* st = (float*)smh;               // (BM/2) x BN f32 per half-pass
  const int tid = threadIdx.x, lane = tid & 63, wid = tid >> 6;
  const int wr = wid >> 2, wc = wid & 3;
  const int cbase = wc * 64 + (lane & 15);
#pragma unroll
  for (int half = 0; half < 2; half++) {
    __syncthreads();
    if (wr == half) {
#pragma unroll
      for (int mg = 0; mg < BM / 32; mg++)
#pragma unroll
        for (int r = 0; r < 4; r++) {
          const int rloc = (lane >> 4) * 4 + mg * 16 + r;
#pragma unroll
          for (int n = 0; n < 4; n++)
            st[rloc * BN + cbase + n * 16] = acc[mg][n][r];
        }
    }
    __syncthreads();
    constexpr int CH = (BM / 2) * BN / (512 * 4);
#pragma unroll
    for (int c = 0; c < CH; c++) {
      const int idx = c * 512 + tid;
      const int row = idx / (BN / 4);
      const int cole = (idx % (BN / 4)) * 4;
      float4 v = *reinterpret_cast<const float4*>(&st[row * BN + cole]);
      *reinterpret_cast<float4*>(
          Cp + (size_t)(m0 + half * (BM / 2) + row) * ldc + n0 + cole) = v;
    }
  }
}

// ---------- fused input GEMM (128x256): blocks 0-255 q@WqT, 256-767 k@WkvT ----------
__global__ __launch_bounds__(512) void gemmIn_kernel(
    const f16* __restrict__ q16, const f16* __restrict__ WqT, f16* __restrict__ tmpq,
    const f16* __restrict__ k16, const f16* __restrict__ WkvT, f16* __restrict__ tmp2) {
  __shared__ __attribute__((aligned(16))) f16 sm[2 * (128 + 256) * 64];  // 96KB
  const int b = blockIdx.x;                       // 768
  const int swz = (b & 7) * 96 + (b >> 3);        // bijective XCD swizzle
  const f16 *A, *B;
  f16* C;
  int ldc, m0, n0;
  if (swz < 256) {                                // q: 64 m-tiles x 4 n-tiles
    const int bx = swz & 63, by = swz >> 6;
    A = q16; B = WqT; C = tmpq; ldc = 1024; m0 = bx * 128; n0 = by * 256;
  } else {                                        // kv: 64 m-tiles x 8 n-tiles
    const int idx = swz - 256;
    const int bx = idx & 63, by = idx >> 6;
    A = k16; B = WkvT; C = tmp2; ldc = 2048; m0 = bx * 128; n0 = by * 256;
  }
  f32x4 acc[4][4] = {};
  gemm_core2<128, 256>(A, B, 1024, 1024, 1024, m0, n0, sm, acc);
  epi_f16<128, 256>(acc, sm, C, ldc, m0, n0);
}

// ---------- s1 GEMM (256x256): e1 = exp(qn.kn^T/32), 8 col-tile partials ----------
__global__ __launch_bounds__(512) void gemmS1_kernel(
    const f16* __restrict__ qn, const f16* __restrict__ kn,
    f16* __restrict__ e1, float* __restrict__ PS) {
  __shared__ __attribute__((aligned(16))) f16 sm[2 * (256 + 256) * 64];  // 128KB
  __shared__ float psum[256];
  const int b = blockIdx.x;                       // 256
  const int swz = (b & 7) * 32 + (b >> 3);
  const int bz = swz >> 6;
  const int rem = swz & 63;
  const int bx = rem & 7, by = rem >> 3;          // 8 m x 8 n per batch
  const int m0 = bx * 256, n0 = by * 256;
  const f16* Ab = qn + (size_t)bz * 2048 * 1024;
  const f16* Bb = kn + (size_t)bz * 2048 * 2048;
  f16* Cp = e1 + (size_t)bz * 2048 * 2048;
  f32x4 acc[8][4] = {};
  gemm_core2<256, 256>(Ab, Bb, 1024, 2048, 1024, m0, n0, sm, acc);
  epi_exp<256, 256>(acc, sm, psum, Cp, 2048, m0, n0, 0.03125f,
                    PS + (size_t)by * (CB * CNQ) + bz * 2048 + m0);
}

// ---------- out GEMM (128x256): out = e2n @ vn ----------
__global__ __launch_bounds__(512) void gemmOut_kernel(
    const f16* __restrict__ e2, const f16* __restrict__ vnT, float* __restrict__ out) {
  __shared__ __attribute__((aligned(16))) f16 sm[2 * (128 + 256) * 64];  // 96KB
  const int b = blockIdx.x;                       // 256
  const int swz = (b & 7) * 32 + (b >> 3);
  const int bz = swz >> 6;
  const int rem = swz & 63;
  const int bx = rem & 15, by = rem >> 4;         // 16 m x 4 n per batch
  const int m0 = bx * 128, n0 = by * 256;
  const f16* Ab = e2 + (size_t)bz * 2048 * 2048;
  const f16* Bb = vnT + (size_t)bz * 1024 * 2048;
  float* Cp = out + (size_t)bz * 2048 * 1024;
  f32x4 acc[4][4] = {};
  gemm_core2<128, 256>(Ab, Bb, 2048, 2048, 2048, m0, n0, sm, acc);
  epi_f32<128, 256>(acc, sm, Cp, 1024, m0, n0);
}

// ---------- merged LayerNorm: z=0 q in place, z=1 k in place, z=2 v STATS only ----------
__global__ __launch_bounds__(256) void ln3_kernel(
    f16* __restrict__ tmpq, f16* __restrict__ tmp2, float* __restrict__ vstat,
    const float* __restrict__ bq, const float* __restrict__ gq, const float* __restrict__ beq,
    const float* __restrict__ bk, const float* __restrict__ gk, const float* __restrict__ bek,
    const float* __restrict__ bv) {
  __shared__ float rs_[4], rq_[4];
  const int z = blockIdx.y;
  f16* rp;
  const float *bias, *g, *beta;
  if (z == 0)      { rp = tmpq + (size_t)blockIdx.x * 1024;        bias = bq; g = gq; beta = beq; }
  else if (z == 1) { rp = tmp2 + (size_t)blockIdx.x * 2048;        bias = bk; g = gk; beta = bek; }
  else             { rp = tmp2 + (size_t)blockIdx.x * 2048 + 1024; bias = bv; g = nullptr; beta = nullptr; }
  const int t = threadIdx.x;
  f16x4 v = *reinterpret_cast<const f16x4*>(rp + t * 4);
  float y[4], s = 0.f, q = 0.f;
#pragma unroll
  for (int j = 0; j < 4; j++) {
    y[j] = (float)v[j] + bias[t * 4 + j];
    s += y[j]; q += y[j] * y[j];
  }
#pragma unroll
  for (int o = 32; o; o >>= 1) { s += __shfl_xor(s, o); q += __shfl_xor(q, o); }
  if ((t & 63) == 0) { rs_[t >> 6] = s; rq_[t >> 6] = q; }
  __syncthreads();
  s = rs_[0] + rs_[1] + rs_[2] + rs_[3];
  q = rq_[0] + rq_[1] + rq_[2] + rq_[3];
  const float mean = s * (1.0f / CD);
  const float rstd = rsqrtf(q * (1.0f / CD) - mean * mean + 1e-5f);
  if (z == 2) {                          // stats only; transpose applies LN
    if (t == 0) { vstat[blockIdx.x] = mean; vstat[CB * CNK + blockIdx.x] = rstd; }
    return;
  }
  f16x4 o;
#pragma unroll
  for (int j = 0; j < 4; j++) {
    int c = t * 4 + j;
    o[j] = (f16)((y[j] - mean) * rstd * g[c] + beta[c]);
  }
  *reinterpret_cast<f16x4*>(rp + t * 4) = o;
}

// ---------- transpose + apply v-LN: vnT[b][d][n] = LN(tmp2v[b][n][d]) ----------
__global__ __launch_bounds__(256) void transposeLN_kernel(
    const f16* __restrict__ tmp2, f16* __restrict__ vnT,
    const float* __restrict__ vstat, const float* __restrict__ bv,
    const float* __restrict__ gv, const float* __restrict__ bev) {
  __shared__ f16 t[64][65];
  __shared__ float ms[64], rs[64];
  int n0 = blockIdx.x * 64, d0 = blockIdx.y * 64;
  size_t ibase = (size_t)blockIdx.z * CNK * 2048;
  size_t obase = (size_t)blockIdx.z * CNK * CD;
  int tx = threadIdx.x & 63, ty = threadIdx.x >> 6;
  const int tokbase = blockIdx.z * CNK + n0;
  if (threadIdx.x < 64) {
    ms[threadIdx.x] = vstat[tokbase + threadIdx.x];
    rs[threadIdx.x] = vstat[CB * CNK + tokbase + threadIdx.x];
  }
#pragma unroll
  for (int i = 0; i < 16; i++)
    t[ty + 4 * i][tx] = tmp2[ibase + (size_t)(n0 + ty + 4 * i) * 2048 + 1024 + d0 + tx];
  __syncthreads();
#pragma unroll
  for (int i = 0; i < 16; i++) {
    const int dim = d0 + 4 * i + ty;
    const float yv = (float)t[tx][ty + 4 * i] + bv[dim];
    vnT[obase + (size_t)dim * CNK + n0 + tx] =
        (f16)((yv - ms[tx]) * rs[tx] * gv[dim] + bev[dim]);
  }
}

// ---------- x-GEMM: xw[z] = e1 @ pos (K half z); also writes att0 = e1*inv1 ----------
__global__ __launch_bounds__(256) void xgemm_kernel(
    const f16* __restrict__ e1, const f16* __restrict__ posTb,
    const float* __restrict__ PS, float* __restrict__ xw, float* __restrict__ att) {
  constexpr int BM = 64, BN = 64;
  __shared__ __attribute__((aligned(16))) f16 As[BM * 32];
  __shared__ __attribute__((aligned(16))) f16 Bs[BN * 32];
  __shared__ float invs[BM];
  const int tid = threadIdx.x;
  const int lane = tid & 63;
  const int wave = tid >> 6;
  const int wr = wave >> 1, wc = wave & 1;
  const int m0 = blockIdx.x * BM;
  const int kbase = blockIdx.z * 1024;
  const int srow = lane >> 2;
  const int scol = (lane & 3) * 8;
  const int lrow = lane & 15;
  const int kg = lane >> 4;

  if (tid < BM) {                 // inv1 from the 8 PS partials
    float s = 0.f;
#pragma unroll
    for (int j = 0; j < 8; j++) s += PS[j * (CB * CNQ) + m0 + tid];
    invs[tid] = 1.0f / s;
  }

  const int bb = m0 >> 11, nloc = m0 & (CNQ - 1);
  float* attb = att + ((size_t)(bb << 1) * CNQ + nloc) * CNK + kbase;
  const int arow = tid >> 2, acol = (tid & 3) * 8;

  f32x4 acc[2][2] = {};
  for (int k0 = 0; k0 < 1024; k0 += 32) {
    __syncthreads();
#pragma unroll
    for (int i = wave; i < 8; i += 4) {
      if (i < 4)
        async16(e1 + (size_t)(m0 + i * 16 + srow) * CNK + kbase + k0 + scol, &As[i * 512]);
      else
        async16(posTb + (size_t)((i - 4) * 16 + srow) * CNK + kbase + k0 + scol,
                &Bs[(i - 4) * 512]);
    }
    __syncthreads();
    f16x8 af[2], bfr[2];
#pragma unroll
    for (int m = 0; m < 2; m++)
      af[m] = *reinterpret_cast<const f16x8*>(&As[(wr * 32 + m * 16 + lrow) * 32 + kg * 8]);
#pragma unroll
    for (int n = 0; n < 2; n++)
      bfr[n] = *reinterpret_cast<const f16x8*>(&Bs[(wc * 32 + n * 16 + lrow) * 32 + kg * 8]);
#pragma unroll
    for (int m = 0; m < 2; m++)
#pragma unroll
      for (int n = 0; n < 2; n++)
        acc[m][n] = __builtin_amdgcn_mfma_f32_16x16x32_f16(af[m], bfr[n], acc[m][n], 0, 0, 0);
    {   // att0 write from staged e1 tile
      const float iv = invs[arow];
      f16x8 v = *reinterpret_cast<const f16x8*>(&As[arow * 32 + acol]);
      float4 w0 = {(float)v[0] * iv, (float)v[1] * iv, (float)v[2] * iv, (float)v[3] * iv};
      float4 w1 = {(float)v[4] * iv, (float)v[5] * iv, (float)v[6] * iv, (float)v[7] * iv};
      float* ap = attb + (size_t)arow * CNK + k0 + acol;
      reinterpret_cast<float4*>(ap)[0] = w0;
      reinterpret_cast<float4*>(ap)[1] = w1;
    }
  }
  float* Cp = xw + (size_t)blockIdx.z * (CB * CNQ) * CP;
  const int crow = m0 + wr * 32 + (lane >> 4) * 4;
  const int ccol = wc * 32 + (lane & 15);
#pragma unroll
  for (int m = 0; m < 2; m++)
#pragma unroll
    for (int n = 0; n < 2; n++)
#pragma unroll
      for (int r = 0; r < 4; r++)
        Cp[(size_t)(crow + m * 16 + r) * CP + ccol + n * 16] = acc[m][n][r];
}

// ---------- attn2 (8 waves, 4-way j-split): x'=(x*inv1)@Wp+bp;
//            e=exp(x'.pos^T/8); writes normalized att head-1 + e2 ----------
__global__ __launch_bounds__(512) void attn2_kernel(
    const float* __restrict__ xw, const float* __restrict__ Wp,
    const float* __restrict__ bp, const f16* __restrict__ posb,
    const float* __restrict__ PS, f16* __restrict__ e2,
    float* __restrict__ att) {
  // e2lds [32][2048] f16 (128KB) || xpb [32][64] f16 (4KB);
  // xs (8KB f32) + Wps (16KB f32) alias e2lds head (dead before e2lds use).
  __shared__ __attribute__((aligned(16))) f16 shm[32 * 2048 + 32 * 64];
  __shared__ float rsum4[4][32];
  __shared__ float invs[32];
  f16* e2lds = shm;
  f16* xpb = shm + 32 * 2048;
  float* xs = (float*)shm;              // [32][64]
  float* Wps = (float*)shm + 32 * 64;   // [64][64]
  const int tid = threadIdx.x, l = tid & 63, w = tid >> 6;   // w 0..7
  const int r0 = blockIdx.x * 32;
  if (tid < 32) {
    float s = 0.f;
#pragma unroll
    for (int j = 0; j < 8; j++) s += PS[j * (CB * CNQ) + r0 + tid];
    invs[tid] = 1.0f / s;
  }
  __syncthreads();
  if (w < 2) {
#pragma unroll
    for (int i = 0; i < 16; i++) {
      const int row = w * 16 + i;
      const size_t gi = (size_t)(r0 + row) * CP + l;
      xs[row * 64 + l] = (xw[gi] + xw[(size_t)(CB * CNQ) * CP + gi]) * invs[row];
    }
#pragma unroll
    for (int i = w; i < 64; i += 2) Wps[i * 64 + l] = Wp[i * 64 + l];
  }
  const float bpl = bp[l];
  __syncthreads();
  if (w < 2) {
#pragma unroll 2
    for (int i = 0; i < 16; i++) {
      float a = bpl;
#pragma unroll 8
      for (int p = 0; p < 64; p++) a = fmaf(xs[(w * 16 + i) * 64 + p], Wps[p * 64 + l], a);
      xpb[(w * 16 + i) * 64 + l] = (f16)a;
    }
  }
  __syncthreads();                       // xpb ready; xs/Wps dead -> e2lds free
  const int rb = (w & 1) * 16, jh = w >> 1;   // rb: row half, jh: j quarter
  const f16x8 af0 = *reinterpret_cast<const f16x8*>(&xpb[(rb + (l & 15)) * 64 + (l >> 4) * 8]);
  const f16x8 af1 = *reinterpret_cast<const f16x8*>(&xpb[(rb + (l & 15)) * 64 + 32 + (l >> 4) * 8]);
  float rs[4] = {0.f, 0.f, 0.f, 0.f};
  for (int jt = jh * 8; jt < jh * 8 + 8; jt++) {
#pragma unroll
    for (int q4 = 0; q4 < 4; q4++) {
      const int j = jt * 64 + q4 * 16 + (l & 15);
      const f16* pp = posb + (size_t)j * CP + (l >> 4) * 8;
      f16x8 b0 = *reinterpret_cast<const f16x8*>(pp);
      f16x8 b1 = *reinterpret_cast<const f16x8*>(pp + 32);
      f32x4 c = {};
      c = __builtin_amdgcn_mfma_f32_16x16x32_f16(af0, b0, c, 0, 0, 0);
      c = __builtin_amdgcn_mfma_f32_16x16x32_f16(af1, b1, c, 0, 0, 0);
#pragma unroll
      for (int r = 0; r < 4; r++) {
        float ev = __expf(c[r] * 0.125f);
        rs[r] += ev;
        e2lds[(rb + (l >> 4) * 4 + r) * 2048 + j] = (f16)ev;
      }
    }
  }
#pragma unroll
  for (int r = 0; r < 4; r++) {
#pragma unroll
    for (int o = 1; o < 16; o <<= 1) rs[r] += __shfl_xor(rs[r], o);
    if ((l & 15) == 0) rsum4[jh][rb + (l >> 4) * 4 + r] = rs[r];
  }
  __syncthreads();
  const int b = r0 >> 11, nloc = r0 & (CNQ - 1);
  float* attb = att + ((size_t)((b << 1) + 1) * CNQ + nloc) * CNK;
  f16* e2b = e2 + (size_t)r0 * CNK;
  // 512 threads: 4 rows per iteration, 128 threads per row
  for (int it = 0; it < 8; it++) {
    const int row = it * 4 + (tid >> 7);
    const int col = (tid & 127) * 16;
    const float iv = 1.0f / (rsum4[0][row] + rsum4[1][row] + rsum4[2][row] + rsum4[3][row]);
    const f16x8 a0 = *reinterpret_cast<const f16x8*>(&e2lds[row * 2048 + col]);
    const f16x8 a1 = *reinterpret_cast<const f16x8*>(&e2lds[row * 2048 + col + 8]);
    float4 w0 = {(float)a0[0] * iv, (float)a0[1] * iv, (float)a0[2] * iv, (float)a0[3] * iv};
    float4 w1 = {(float)a0[4] * iv, (float)a0[5] * iv, (float)a0[6] * iv, (float)a0[7] * iv};
    float4 w2 = {(float)a1[0] * iv, (float)a1[1] * iv, (float)a1[2] * iv, (float)a1[3] * iv};
    float4 w3 = {(float)a1[4] * iv, (float)a1[5] * iv, (float)a1[6] * iv, (float)a1[7] * iv};
    float* ap = attb + (size_t)row * CNK + col;
    reinterpret_cast<float4*>(ap)[0] = w0;
    reinterpret_cast<float4*>(ap)[1] = w1;
    reinterpret_cast<float4*>(ap)[2] = w2;
    reinterpret_cast<float4*>(ap)[3] = w3;
    f16x8 h0 = {(f16)w0.x, (f16)w0.y, (f16)w0.z, (f16)w0.w,
                (f16)w1.x, (f16)w1.y, (f16)w1.z, (f16)w1.w};
    f16x8 h1 = {(f16)w2.x, (f16)w2.y, (f16)w2.z, (f16)w2.w,
                (f16)w3.x, (f16)w3.y, (f16)w3.z, (f16)w3.w};
    f16* ep = e2b + (size_t)row * CNK + col;
    *reinterpret_cast<f16x8*>(ep)     = h0;
    *reinterpret_cast<f16x8*>(ep + 8) = h1;
  }
}

extern "C" void kernel_launch(void* const* d_in, const int* in_sizes, int n_in,
                              void* d_out, int out_size, void* d_ws, size_t ws_size,
                              hipStream_t stream) {
  (void)in_sizes; (void)n_in; (void)out_size; (void)ws_size;
  const float* q    = (const float*)d_in[0];
  const float* k    = (const float*)d_in[1];
  const float* Wq   = (const float*)d_in[2];
  const float* bq   = (const float*)d_in[3];
  const float* Wk   = (const float*)d_in[4];
  const float* bk   = (const float*)d_in[5];
  const float* Wv   = (const float*)d_in[6];
  const float* bv   = (const float*)d_in[7];
  const float* gq   = (const float*)d_in[8];
  const float* betaq= (const float*)d_in[9];
  const float* gk   = (const float*)d_in[10];
  const float* betak= (const float*)d_in[11];
  const float* gv   = (const float*)d_in[12];
  const float* betav= (const float*)d_in[13];
  const float* Wp   = (const float*)d_in[14];
  const float* bp   = (const float*)d_in[15];

  float* out = (float*)d_out;
  float* att = out + (size_t)CB * CNQ * CD;   // [B,2,NQ,NK]
  char* ws = (char*)d_ws;
  const size_t MB = 1ull << 20;

  f16* q16   = (f16*)(ws);                     // 0-16MB, dead after gemmIn
  f16* k16   = (f16*)(ws + 16 * MB);           // 16-32, dead after gemmIn
  f16* e1    = (f16*)(ws);                     // 0-32 (after q16/k16 die)
  f16* e2    = (f16*)(ws);                     // 0-32 (after e1 dies)
  f16* WqT   = (f16*)(ws + 32 * MB);           // 2MB
  f16* WkvT  = (f16*)(ws + 34 * MB);           // 4MB
  f16* posb  = (f16*)(ws + 38 * MB);           // 256KB
  f16* posTb = (f16*)(ws + 38 * MB + 256 * 1024);
  float* xw  = (float*)(ws + 38 * MB + 512 * 1024); // 4MB [2][8192][64]
  float* PS  = (float*)(ws + 42 * MB + 512 * 1024); // 256KB [8][8192]
  float* vstat = (float*)(ws + 42 * MB + 768 * 1024); // 64KB [2][8192]
  f16* tmpq  = (f16*)(ws + 43 * MB);           // 16MB (qn in place)
  f16* tmp2  = (f16*)(ws + 59 * MB);           // 32MB (kn in place | v raw)
  f16* vnT   = (f16*)(ws + 91 * MB);           // 16MB (ends 107MB)
  f16* qn = tmpq;
  f16* kn = tmp2;            // ld 2048, cols 0-1023

  prep_kernel<<<512 + 16384 + 768, 256, 0, stream>>>(
      q, k, Wq, Wk, Wv, q16, k16, WqT, WkvT, posb, posTb);

  gemmIn_kernel<<<768, 512, 0, stream>>>(q16, WqT, tmpq, k16, WkvT, tmp2);
  ln3_kernel<<<dim3(CB * CNQ, 3), 256, 0, stream>>>(
      tmpq, tmp2, vstat, bq, gq, betaq, bk, gk, betak, bv);
  transposeLN_kernel<<<dim3(CNK / 64, CD / 64, CB), 256, 0, stream>>>(
      tmp2, vnT, vstat, bv, gv, betav);

  gemmS1_kernel<<<256, 512, 0, stream>>>(qn, kn, e1, PS);

  xgemm_kernel<<<dim3(CB * CNQ / 64, 1, 2), 256, 0, stream>>>(e1, posTb, PS, xw, att);
  attn2_kernel<<<CB * CNQ / 32, 512, 0, stream>>>(xw, Wp, bp, posb, PS, e2, att);

  gemmOut_kernel<<<256, 512, 0, stream>>>(e2, vnT, out);
}

// Round 10
// 289.472 us; speedup vs baseline: 1.4157x; 1.0103x over previous
//
#include <hip/hip_runtime.h>
#include <math.h>
#include <stdint.h>

// BlindCrossAttention on MI355X (gfx950).
// Round 10 = Round 9 with ONE change: gemm_core2 drops the per-kk barrier
// pairs (5 -> 2 barriers per K-tile). Intra-tile barriers were perf-shaping
// only; hazards are covered by (a) head vmcnt+barrier (tile data ready) and
// (b) end-of-tile barrier (all reads of buf[cur] done before t+2 overwrites).
// Removing them lets the compiler pipeline ds_reads under MFMAs per-wave.

typedef _Float16 f16;
typedef _Float16 f16x4 __attribute__((ext_vector_type(4)));
typedef _Float16 f16x8 __attribute__((ext_vector_type(8)));
typedef float f32x4 __attribute__((ext_vector_type(4)));

static constexpr int CB  = 4;
static constexpr int CNQ = 2048;
static constexpr int CNK = 2048;
static constexpr int CD  = 1024;
static constexpr int CP  = 64;

// ---------- async global->LDS, 16B/lane ----------
static __device__ __forceinline__ void async16(const f16* gp, f16* lp) {
  __builtin_amdgcn_global_load_lds(
      (const __attribute__((address_space(1))) void*)(uintptr_t)gp,
      (__attribute__((address_space(3))) void*)(uint32_t)(uintptr_t)lp,
      16, 0, 0);
}

// ---------- prep: pos table + cvt q,k -> f16 + transpose-cvt W's ----------
__global__ __launch_bounds__(256) void prep_kernel(
    const float* __restrict__ q, const float* __restrict__ k,
    const float* __restrict__ Wq, const float* __restrict__ Wk,
    const float* __restrict__ Wv,
    f16* __restrict__ q16, f16* __restrict__ k16,
    f16* __restrict__ WqT, f16* __restrict__ WkvT,
    f16* __restrict__ posb, f16* __restrict__ posTb) {
  const int b = blockIdx.x;
  if (b < 512) {                        // pos table
    int tid = b * 256 + threadIdx.x;
    int p = tid >> 11;
    int j = tid & (CNK - 1);
    int i = p & 31;
    float ph = (float)j * powf(10000.0f, -(float)i * (1.0f / 32.0f));
    float v = (p < 32) ? sinf(ph) : cosf(ph);
    posb[j * CP + p]   = (f16)v;
    posTb[p * CNK + j] = (f16)v;
  } else if (b < 512 + 16384) {         // cvt q,k
    const int NF4 = CB * CNQ * CD / 4;
    int tid = (b - 512) * 256 + threadIdx.x;
    const float* src = (tid < NF4) ? q : k;
    f16* dst = (tid < NF4) ? q16 : k16;
    int i = (tid < NF4) ? tid : tid - NF4;
    float4 v = reinterpret_cast<const float4*>(src)[i];
    f16x4 o = {(f16)v.x, (f16)v.y, (f16)v.z, (f16)v.w};
    reinterpret_cast<f16x4*>(dst)[i] = o;
  } else {                              // W -> WT f16
    __shared__ float t[64][65];
    const int idx = b - 16896;
    const int z = idx >> 8;
    const int rem = idx & 255;
    const float* W = (z == 0) ? Wq : (z == 1) ? Wk : Wv;
    f16* WT = (z == 0) ? WqT : (z == 1) ? WkvT : WkvT + 1024 * 1024;
    int k0 = (rem & 15) * 64, n0 = (rem >> 4) * 64;
    int tx = threadIdx.x & 63, ty = threadIdx.x >> 6;
#pragma unroll
    for (int i = 0; i < 16; i++)
      t[ty + 4 * i][tx] = W[(size_t)(k0 + ty + 4 * i) * CD + n0 + tx];
    __syncthreads();
#pragma unroll
    for (int i = 0; i < 16; i++)
      WT[(size_t)(n0 + 4 * i + ty) * CD + k0 + tx] = (f16)t[tx][ty + 4 * i];
  }
}

// ============ 2-barrier counted-prefetch dbuf GEMM core (wide waves) ============
// 8 waves (2x4), per-wave output (BM/2)x64.  BK=64, double-buffered LDS,
// T2 XOR-swizzle via pre-swizzled global src, full next-tile issue at tile
// head + counted vmcnt(TI).  NO intra-tile barriers: compiler pipelines
// ds_reads under MFMAs; one end-of-tile barrier protects buf reuse.
template <int BM, int BN>
__device__ __forceinline__ void gemm_core2(
    const f16* __restrict__ Ab, const f16* __restrict__ Bb,
    int lda, int ldb, int K, int m0, int n0, f16* sm,
    f32x4 (&acc)[BM / 32][4]) {
  constexpr int FM = BM / 32;           // 4 or 8
  constexpr int TI = (BM + BN) / 64;    // 6 or 8
  constexpr int bufsz = (BM + BN) * 64;
  const int tid = threadIdx.x;
  const int lane = tid & 63, wid = tid >> 6;
  const int wr = wid >> 2, wc = wid & 3;
  const int lrow = lane & 15, kg = lane >> 4;

  auto stage = [&](int i, int kt, int buf) {
    const int s = i * 512 + tid;          // 16B slot
    const int row = s >> 3;
    const int cb = (s & 7) << 4;
    const int scb = cb ^ ((row & 7) << 4);  // pre-swizzled global source col
    const f16* src = (i < BM / 64)
        ? Ab + (size_t)(m0 + row) * lda + kt * 64 + (scb >> 1)
        : Bb + (size_t)(n0 + row - BM) * ldb + kt * 64 + (scb >> 1);
    async16(src, &sm[buf * bufsz + s * 8]);
  };

  const int NTk = K >> 6;
#pragma unroll
  for (int i = 0; i < TI; i++) stage(i, 0, 0);

  for (int t = 0; t < NTk; ++t) {
    const int cur = t & 1;
    if (t + 1 < NTk) {
#pragma unroll
      for (int i = 0; i < TI; i++) stage(i, t + 1, cur ^ 1);
      if constexpr (TI == 8) asm volatile("s_waitcnt vmcnt(8)" ::: "memory");
      else                   asm volatile("s_waitcnt vmcnt(6)" ::: "memory");
    } else {
      asm volatile("s_waitcnt vmcnt(0)" ::: "memory");
    }
    __builtin_amdgcn_s_barrier();        // tile t data ready in buf[cur]

    const f16* smA = sm + cur * bufsz;
    const f16* smB = smA + BM * 64;
    __builtin_amdgcn_s_setprio(1);
#pragma unroll
    for (int kk = 0; kk < 2; ++kk) {
      const int Cb = kk * 64 + kg * 16;
      f16x8 af[FM], bf[4];
#pragma unroll
      for (int m = 0; m < FM; ++m) {
        const int ar = wr * (BM / 2) + m * 16 + lrow;
        af[m] = *reinterpret_cast<const f16x8*>(
            &smA[ar * 64 + ((Cb ^ ((ar & 7) << 4)) >> 1)]);
      }
#pragma unroll
      for (int n = 0; n < 4; ++n) {
        const int br = wc * 64 + n * 16 + lrow;
        bf[n] = *reinterpret_cast<const f16x8*>(
            &smB[br * 64 + ((Cb ^ ((br & 7) << 4)) >> 1)]);
      }
#pragma unroll
      for (int m = 0; m < FM; ++m)
#pragma unroll
        for (int n = 0; n < 4; ++n)
          acc[m][n] = __builtin_amdgcn_mfma_f32_16x16x32_f16(af[m], bf[n], acc[m][n], 0, 0, 0);
    }
    __builtin_amdgcn_s_setprio(0);
    __builtin_amdgcn_s_barrier();        // all reads of buf[cur] done
  }
}

// ---------- epilogue: f16 store, LDS-staged ----------
template <int BM, int BN>
__device__ __forceinline__ void epi_f16(
    f32x4 (&acc)[BM / 32][4], f16* sm, f16* Cp, int ldc, int m0, int n0) {
  const int tid = threadIdx.x, lane = tid & 63, wid = tid >> 6;
  const int wr = wid >> 2, wc = wid & 3;
  const int rbase = wr * (BM / 2) + (lane >> 4) * 4;
  const int cbase = wc * 64 + (lane & 15);
  __syncthreads();
#pragma unroll
  for (int mg = 0; mg < BM / 32; mg++)
#pragma unroll
    for (int n = 0; n < 4; n++)
#pragma unroll
      for (int r = 0; r < 4; r++)
        sm[(rbase + mg * 16 + r) * BN + cbase + n * 16] = (f16)acc[mg][n][r];
  __syncthreads();
  constexpr int CH = BM * BN / (512 * 8);
#pragma unroll
  for (int c = 0; c < CH; c++) {
    const int idx = c * 512 + tid;
    const int row = idx / (BN / 8);
    const int cole = (idx % (BN / 8)) * 8;
    f16x8 v = *reinterpret_cast<const f16x8*>(&sm[row * BN + cole]);
    *reinterpret_cast<f16x8*>(Cp + (size_t)(m0 + row) * ldc + n0 + cole) = v;
  }
}

// ---------- epilogue: exp()->f16 store + per-coltile row sums ----------
template <int BM, int BN>
__device__ __forceinline__ void epi_exp(
    f32x4 (&acc)[BM / 32][4], f16* sm, float* psum, f16* Cp, int ldc,
    int m0, int n0, float scale, float* PSrow) {
  constexpr int SL = BN / 8;             // 16B slots per row
  const int tid = threadIdx.x, lane = tid & 63, wid = tid >> 6;
  const int wr = wid >> 2, wc = wid & 3;
  const int rbase = wr * (BM / 2) + (lane >> 4) * 4;
  const int cbase = wc * 64 + (lane & 15);
  __syncthreads();
#pragma unroll
  for (int mg = 0; mg < BM / 32; mg++)
#pragma unroll
    for (int n = 0; n < 4; n++)
#pragma unroll
      for (int r = 0; r < 4; r++)
        sm[(rbase + mg * 16 + r) * BN + cbase + n * 16] =
            (f16)__expf(acc[mg][n][r] * scale);
  __syncthreads();
  constexpr int CH = BM * BN / (512 * 8);
#pragma unroll
  for (int c = 0; c < CH; c++) {
    const int idx = c * 512 + tid;
    const int row = idx / SL;
    const int cole = (idx % SL) * 8;
    f16x8 v = *reinterpret_cast<const f16x8*>(&sm[row * BN + cole]);
    *reinterpret_cast<f16x8*>(Cp + (size_t)(m0 + row) * ldc + n0 + cole) = v;
    float p = 0.f;
#pragma unroll
    for (int j = 0; j < 8; j++) p += (float)v[j];
#pragma unroll
    for (int o = 1; o < SL; o <<= 1) p += __shfl_xor(p, o);
    if ((lane & (SL - 1)) == 0) psum[row] = p;   // one writer per row
  }
  __syncthreads();
  if (tid < BM) PSrow[tid] = psum[tid];
}

// ---------- epilogue: f32 store, LDS-staged (two half-passes) ----------
template <int BM, int BN>
__device__ __forceinline__ void epi_f32(
    f32x4 (&acc)[BM / 32][4], f16* smh, float* Cp, int ldc, int m0, int n0) {
  float* st = (float*)smh;               // (BM/2) x BN f32 per half-pass
  const int tid = threadIdx.x, lane = tid & 63, wid = tid >> 6;
  const int wr = wid >> 2, wc = wid & 3;
  const int cbase = wc * 64 + (lane & 15);
#pragma unroll
  for (int half = 0; half < 2; half++) {
    __syncthreads();
    if (wr == half) {
#pragma unroll
      for (int mg = 0; mg < BM / 32; mg++)
#pragma unroll
        for (int r = 0; r < 4; r++) {
          const int rloc = (lane >> 4) * 4 + mg * 16 + r;
#pragma unroll
          for (int n = 0; n < 4; n++)
            st[rloc * BN + cbase + n * 16] = acc[mg][n][r];
        }
    }
    __syncthreads();
    constexpr int CH = (BM / 2) * BN / (512 * 4);
#pragma unroll
    for (int c = 0; c < CH; c++) {
      const int idx = c * 512 + tid;
      const int row = idx / (BN / 4);
      const int cole = (idx % (BN / 4)) * 4;
      float4 v = *reinterpret_cast<const float4*>(&st[row * BN + cole]);
      *reinterpret_cast<float4*>(
          Cp + (size_t)(m0 + half * (BM / 2) + row) * ldc + n0 + cole) = v;
    }
  }
}

// ---------- fused input GEMM (128x256): blocks 0-255 q@WqT, 256-767 k@WkvT ----------
__global__ __launch_bounds__(512) void gemmIn_kernel(
    const f16* __restrict__ q16, const f16* __restrict__ WqT, f16* __restrict__ tmpq,
    const f16* __restrict__ k16, const f16* __restrict__ WkvT, f16* __restrict__ tmp2) {
  __shared__ __attribute__((aligned(16))) f16 sm[2 * (128 + 256) * 64];  // 96KB
  const int b = blockIdx.x;                       // 768
  const int swz = (b & 7) * 96 + (b >> 3);        // bijective XCD swizzle
  const f16 *A, *B;
  f16* C;
  int ldc, m0, n0;
  if (swz < 256) {                                // q: 64 m-tiles x 4 n-tiles
    const int bx = swz & 63, by = swz >> 6;
    A = q16; B = WqT; C = tmpq; ldc = 1024; m0 = bx * 128; n0 = by * 256;
  } else {                                        // kv: 64 m-tiles x 8 n-tiles
    const int idx = swz - 256;
    const int bx = idx & 63, by = idx >> 6;
    A = k16; B = WkvT; C = tmp2; ldc = 2048; m0 = bx * 128; n0 = by * 256;
  }
  f32x4 acc[4][4] = {};
  gemm_core2<128, 256>(A, B, 1024, 1024, 1024, m0, n0, sm, acc);
  epi_f16<128, 256>(acc, sm, C, ldc, m0, n0);
}

// ---------- s1 GEMM (256x256): e1 = exp(qn.kn^T/32), 8 col-tile partials ----------
__global__ __launch_bounds__(512) void gemmS1_kernel(
    const f16* __restrict__ qn, const f16* __restrict__ kn,
    f16* __restrict__ e1, float* __restrict__ PS) {
  __shared__ __attribute__((aligned(16))) f16 sm[2 * (256 + 256) * 64];  // 128KB
  __shared__ float psum[256];
  const int b = blockIdx.x;                       // 256
  const int swz = (b & 7) * 32 + (b >> 3);
  const int bz = swz >> 6;
  const int rem = swz & 63;
  const int bx = rem & 7, by = rem >> 3;          // 8 m x 8 n per batch
  const int m0 = bx * 256, n0 = by * 256;
  const f16* Ab = qn + (size_t)bz * 2048 * 1024;
  const f16* Bb = kn + (size_t)bz * 2048 * 2048;
  f16* Cp = e1 + (size_t)bz * 2048 * 2048;
  f32x4 acc[8][4] = {};
  gemm_core2<256, 256>(Ab, Bb, 1024, 2048, 1024, m0, n0, sm, acc);
  epi_exp<256, 256>(acc, sm, psum, Cp, 2048, m0, n0, 0.03125f,
                    PS + (size_t)by * (CB * CNQ) + bz * 2048 + m0);
}

// ---------- out GEMM (128x256): out = e2n @ vn ----------
__global__ __launch_bounds__(512) void gemmOut_kernel(
    const f16* __restrict__ e2, const f16* __restrict__ vnT, float* __restrict__ out) {
  __shared__ __attribute__((aligned(16))) f16 sm[2 * (128 + 256) * 64];  // 96KB
  const int b = blockIdx.x;                       // 256
  const int swz = (b & 7) * 32 + (b >> 3);
  const int bz = swz >> 6;
  const int rem = swz & 63;
  const int bx = rem & 15, by = rem >> 4;         // 16 m x 4 n per batch
  const int m0 = bx * 128, n0 = by * 256;
  const f16* Ab = e2 + (size_t)bz * 2048 * 2048;
  const f16* Bb = vnT + (size_t)bz * 1024 * 2048;
  float* Cp = out + (size_t)bz * 2048 * 1024;
  f32x4 acc[4][4] = {};
  gemm_core2<128, 256>(Ab, Bb, 2048, 2048, 2048, m0, n0, sm, acc);
  epi_f32<128, 256>(acc, sm, Cp, 1024, m0, n0);
}

// ---------- merged LayerNorm: z=0 q in place, z=1 k in place, z=2 v STATS only ----------
__global__ __launch_bounds__(256) void ln3_kernel(
    f16* __restrict__ tmpq, f16* __restrict__ tmp2, float* __restrict__ vstat,
    const float* __restrict__ bq, const float* __restrict__ gq, const float* __restrict__ beq,
    const float* __restrict__ bk, const float* __restrict__ gk, const float* __restrict__ bek,
    const float* __restrict__ bv) {
  __shared__ float rs_[4], rq_[4];
  const int z = blockIdx.y;
  f16* rp;
  const float *bias, *g, *beta;
  if (z == 0)      { rp = tmpq + (size_t)blockIdx.x * 1024;        bias = bq; g = gq; beta = beq; }
  else if (z == 1) { rp = tmp2 + (size_t)blockIdx.x * 2048;        bias = bk; g = gk; beta = bek; }
  else             { rp = tmp2 + (size_t)blockIdx.x * 2048 + 1024; bias = bv; g = nullptr; beta = nullptr; }
  const int t = threadIdx.x;
  f16x4 v = *reinterpret_cast<const f16x4*>(rp + t * 4);
  float y[4], s = 0.f, q = 0.f;
#pragma unroll
  for (int j = 0; j < 4; j++) {
    y[j] = (float)v[j] + bias[t * 4 + j];
    s += y[j]; q += y[j] * y[j];
  }
#pragma unroll
  for (int o = 32; o; o >>= 1) { s += __shfl_xor(s, o); q += __shfl_xor(q, o); }
  if ((t & 63) == 0) { rs_[t >> 6] = s; rq_[t >> 6] = q; }
  __syncthreads();
  s = rs_[0] + rs_[1] + rs_[2] + rs_[3];
  q = rq_[0] + rq_[1] + rq_[2] + rq_[3];
  const float mean = s * (1.0f / CD);
  const float rstd = rsqrtf(q * (1.0f / CD) - mean * mean + 1e-5f);
  if (z == 2) {                          // stats only; transpose applies LN
    if (t == 0) { vstat[blockIdx.x] = mean; vstat[CB * CNK + blockIdx.x] = rstd; }
    return;
  }
  f16x4 o;
#pragma unroll
  for (int j = 0; j < 4; j++) {
    int c = t * 4 + j;
    o[j] = (f16)((y[j] - mean) * rstd * g[c] + beta[c]);
  }
  *reinterpret_cast<f16x4*>(rp + t * 4) = o;
}

// ---------- transpose + apply v-LN: vnT[b][d][n] = LN(tmp2v[b][n][d]) ----------
__global__ __launch_bounds__(256) void transposeLN_kernel(
    const f16* __restrict__ tmp2, f16* __restrict__ vnT,
    const float* __restrict__ vstat, const float* __restrict__ bv,
    const float* __restrict__ gv, const float* __restrict__ bev) {
  __shared__ f16 t[64][65];
  __shared__ float ms[64], rs[64];
  int n0 = blockIdx.x * 64, d0 = blockIdx.y * 64;
  size_t ibase = (size_t)blockIdx.z * CNK * 2048;
  size_t obase = (size_t)blockIdx.z * CNK * CD;
  int tx = threadIdx.x & 63, ty = threadIdx.x >> 6;
  const int tokbase = blockIdx.z * CNK + n0;
  if (threadIdx.x < 64) {
    ms[threadIdx.x] = vstat[tokbase + threadIdx.x];
    rs[threadIdx.x] = vstat[CB * CNK + tokbase + threadIdx.x];
  }
#pragma unroll
  for (int i = 0; i < 16; i++)
    t[ty + 4 * i][tx] = tmp2[ibase + (size_t)(n0 + ty + 4 * i) * 2048 + 1024 + d0 + tx];
  __syncthreads();
#pragma unroll
  for (int i = 0; i < 16; i++) {
    const int dim = d0 + 4 * i + ty;
    const float yv = (float)t[tx][ty + 4 * i] + bv[dim];
    vnT[obase + (size_t)dim * CNK + n0 + tx] =
        (f16)((yv - ms[tx]) * rs[tx] * gv[dim] + bev[dim]);
  }
}

// ---------- x-GEMM: xw[z] = e1 @ pos (K half z); also writes att0 = e1*inv1 ----------
__global__ __launch_bounds__(256) void xgemm_kernel(
    const f16* __restrict__ e1, const f16* __restrict__ posTb,
    const float* __restrict__ PS, float* __restrict__ xw, float* __restrict__ att) {
  constexpr int BM = 64, BN = 64;
  __shared__ __attribute__((aligned(16))) f16 As[BM * 32];
  __shared__ __attribute__((aligned(16))) f16 Bs[BN * 32];
  __shared__ float invs[BM];
  const int tid = threadIdx.x;
  const int lane = tid & 63;
  const int wave = tid >> 6;
  const int wr = wave >> 1, wc = wave & 1;
  const int m0 = blockIdx.x * BM;
  const int kbase = blockIdx.z * 1024;
  const int srow = lane >> 2;
  const int scol = (lane & 3) * 8;
  const int lrow = lane & 15;
  const int kg = lane >> 4;

  if (tid < BM) {                 // inv1 from the 8 PS partials
    float s = 0.f;
#pragma unroll
    for (int j = 0; j < 8; j++) s += PS[j * (CB * CNQ) + m0 + tid];
    invs[tid] = 1.0f / s;
  }

  const int bb = m0 >> 11, nloc = m0 & (CNQ - 1);
  float* attb = att + ((size_t)(bb << 1) * CNQ + nloc) * CNK + kbase;
  const int arow = tid >> 2, acol = (tid & 3) * 8;

  f32x4 acc[2][2] = {};
  for (int k0 = 0; k0 < 1024; k0 += 32) {
    __syncthreads();
#pragma unroll
    for (int i = wave; i < 8; i += 4) {
      if (i < 4)
        async16(e1 + (size_t)(m0 + i * 16 + srow) * CNK + kbase + k0 + scol, &As[i * 512]);
      else
        async16(posTb + (size_t)((i - 4) * 16 + srow) * CNK + kbase + k0 + scol,
                &Bs[(i - 4) * 512]);
    }
    __syncthreads();
    f16x8 af[2], bfr[2];
#pragma unroll
    for (int m = 0; m < 2; m++)
      af[m] = *reinterpret_cast<const f16x8*>(&As[(wr * 32 + m * 16 + lrow) * 32 + kg * 8]);
#pragma unroll
    for (int n = 0; n < 2; n++)
      bfr[n] = *reinterpret_cast<const f16x8*>(&Bs[(wc * 32 + n * 16 + lrow) * 32 + kg * 8]);
#pragma unroll
    for (int m = 0; m < 2; m++)
#pragma unroll
      for (int n = 0; n < 2; n++)
        acc[m][n] = __builtin_amdgcn_mfma_f32_16x16x32_f16(af[m], bfr[n], acc[m][n], 0, 0, 0);
    {   // att0 write from staged e1 tile
      const float iv = invs[arow];
      f16x8 v = *reinterpret_cast<const f16x8*>(&As[arow * 32 + acol]);
      float4 w0 = {(float)v[0] * iv, (float)v[1] * iv, (float)v[2] * iv, (float)v[3] * iv};
      float4 w1 = {(float)v[4] * iv, (float)v[5] * iv, (float)v[6] * iv, (float)v[7] * iv};
      float* ap = attb + (size_t)arow * CNK + k0 + acol;
      reinterpret_cast<float4*>(ap)[0] = w0;
      reinterpret_cast<float4*>(ap)[1] = w1;
    }
  }
  float* Cp = xw + (size_t)blockIdx.z * (CB * CNQ) * CP;
  const int crow = m0 + wr * 32 + (lane >> 4) * 4;
  const int ccol = wc * 32 + (lane & 15);
#pragma unroll
  for (int m = 0; m < 2; m++)
#pragma unroll
    for (int n = 0; n < 2; n++)
#pragma unroll
      for (int r = 0; r < 4; r++)
        Cp[(size_t)(crow + m * 16 + r) * CP + ccol + n * 16] = acc[m][n][r];
}

// ---------- attn2 (8 waves, 4-way j-split): x'=(x*inv1)@Wp+bp;
//            e=exp(x'.pos^T/8); writes normalized att head-1 + e2 ----------
__global__ __launch_bounds__(512) void attn2_kernel(
    const float* __restrict__ xw, const float* __restrict__ Wp,
    const float* __restrict__ bp, const f16* __restrict__ posb,
    const float* __restrict__ PS, f16* __restrict__ e2,
    float* __restrict__ att) {
  // e2lds [32][2048] f16 (128KB) || xpb [32][64] f16 (4KB);
  // xs (8KB f32) + Wps (16KB f32) alias e2lds head (dead before e2lds use).
  __shared__ __attribute__((aligned(16))) f16 shm[32 * 2048 + 32 * 64];
  __shared__ float rsum4[4][32];
  __shared__ float invs[32];
  f16* e2lds = shm;
  f16* xpb = shm + 32 * 2048;
  float* xs = (float*)shm;              // [32][64]
  float* Wps = (float*)shm + 32 * 64;   // [64][64]
  const int tid = threadIdx.x, l = tid & 63, w = tid >> 6;   // w 0..7
  const int r0 = blockIdx.x * 32;
  if (tid < 32) {
    float s = 0.f;
#pragma unroll
    for (int j = 0; j < 8; j++) s += PS[j * (CB * CNQ) + r0 + tid];
    invs[tid] = 1.0f / s;
  }
  __syncthreads();
  if (w < 2) {
#pragma unroll
    for (int i = 0; i < 16; i++) {
      const int row = w * 16 + i;
      const size_t gi = (size_t)(r0 + row) * CP + l;
      xs[row * 64 + l] = (xw[gi] + xw[(size_t)(CB * CNQ) * CP + gi]) * invs[row];
    }
#pragma unroll
    for (int i = w; i < 64; i += 2) Wps[i * 64 + l] = Wp[i * 64 + l];
  }
  const float bpl = bp[l];
  __syncthreads();
  if (w < 2) {
#pragma unroll 2
    for (int i = 0; i < 16; i++) {
      float a = bpl;
#pragma unroll 8
      for (int p = 0; p < 64; p++) a = fmaf(xs[(w * 16 + i) * 64 + p], Wps[p * 64 + l], a);
      xpb[(w * 16 + i) * 64 + l] = (f16)a;
    }
  }
  __syncthreads();                       // xpb ready; xs/Wps dead -> e2lds free
  const int rb = (w & 1) * 16, jh = w >> 1;   // rb: row half, jh: j quarter
  const f16x8 af0 = *reinterpret_cast<const f16x8*>(&xpb[(rb + (l & 15)) * 64 + (l >> 4) * 8]);
  const f16x8 af1 = *reinterpret_cast<const f16x8*>(&xpb[(rb + (l & 15)) * 64 + 32 + (l >> 4) * 8]);
  float rs[4] = {0.f, 0.f, 0.f, 0.f};
  for (int jt = jh * 8; jt < jh * 8 + 8; jt++) {
#pragma unroll
    for (int q4 = 0; q4 < 4; q4++) {
      const int j = jt * 64 + q4 * 16 + (l & 15);
      const f16* pp = posb + (size_t)j * CP + (l >> 4) * 8;
      f16x8 b0 = *reinterpret_cast<const f16x8*>(pp);
      f16x8 b1 = *reinterpret_cast<const f16x8*>(pp + 32);
      f32x4 c = {};
      c = __builtin_amdgcn_mfma_f32_16x16x32_f16(af0, b0, c, 0, 0, 0);
      c = __builtin_amdgcn_mfma_f32_16x16x32_f16(af1, b1, c, 0, 0, 0);
#pragma unroll
      for (int r = 0; r < 4; r++) {
        float ev = __expf(c[r] * 0.125f);
        rs[r] += ev;
        e2lds[(rb + (l >> 4) * 4 + r) * 2048 + j] = (f16)ev;
      }
    }
  }
#pragma unroll
  for (int r = 0; r < 4; r++) {
#pragma unroll
    for (int o = 1; o < 16; o <<= 1) rs[r] += __shfl_xor(rs[r], o);
    if ((l & 15) == 0) rsum4[jh][rb + (l >> 4) * 4 + r] = rs[r];
  }
  __syncthreads();
  const int b = r0 >> 11, nloc = r0 & (CNQ - 1);
  float* attb = att + ((size_t)((b << 1) + 1) * CNQ + nloc) * CNK;
  f16* e2b = e2 + (size_t)r0 * CNK;
  // 512 threads: 4 rows per iteration, 128 threads per row
  for (int it = 0; it < 8; it++) {
    const int row = it * 4 + (tid >> 7);
    const int col = (tid & 127) * 16;
    const float iv = 1.0f / (rsum4[0][row] + rsum4[1][row] + rsum4[2][row] + rsum4[3][row]);
    const f16x8 a0 = *reinterpret_cast<const f16x8*>(&e2lds[row * 2048 + col]);
    const f16x8 a1 = *reinterpret_cast<const f16x8*>(&e2lds[row * 2048 + col + 8]);
    float4 w0 = {(float)a0[0] * iv, (float)a0[1] * iv, (float)a0[2] * iv, (float)a0[3] * iv};
    float4 w1 = {(float)a0[4] * iv, (float)a0[5] * iv, (float)a0[6] * iv, (float)a0[7] * iv};
    float4 w2 = {(float)a1[0] * iv, (float)a1[1] * iv, (float)a1[2] * iv, (float)a1[3] * iv};
    float4 w3 = {(float)a1[4] * iv, (float)a1[5] * iv, (float)a1[6] * iv, (float)a1[7] * iv};
    float* ap = attb + (size_t)row * CNK + col;
    reinterpret_cast<float4*>(ap)[0] = w0;
    reinterpret_cast<float4*>(ap)[1] = w1;
    reinterpret_cast<float4*>(ap)[2] = w2;
    reinterpret_cast<float4*>(ap)[3] = w3;
    f16x8 h0 = {(f16)w0.x, (f16)w0.y, (f16)w0.z, (f16)w0.w,
                (f16)w1.x, (f16)w1.y, (f16)w1.z, (f16)w1.w};
    f16x8 h1 = {(f16)w2.x, (f16)w2.y, (f16)w2.z, (f16)w2.w,
                (f16)w3.x, (f16)w3.y, (f16)w3.z, (f16)w3.w};
    f16* ep = e2b + (size_t)row * CNK + col;
    *reinterpret_cast<f16x8*>(ep)     = h0;
    *reinterpret_cast<f16x8*>(ep + 8) = h1;
  }
}

extern "C" void kernel_launch(void* const* d_in, const int* in_sizes, int n_in,
                              void* d_out, int out_size, void* d_ws, size_t ws_size,
                              hipStream_t stream) {
  (void)in_sizes; (void)n_in; (void)out_size; (void)ws_size;
  const float* q    = (const float*)d_in[0];
  const float* k    = (const float*)d_in[1];
  const float* Wq   = (const float*)d_in[2];
  const float* bq   = (const float*)d_in[3];
  const float* Wk   = (const float*)d_in[4];
  const float* bk   = (const float*)d_in[5];
  const float* Wv   = (const float*)d_in[6];
  const float* bv   = (const float*)d_in[7];
  const float* gq   = (const float*)d_in[8];
  const float* betaq= (const float*)d_in[9];
  const float* gk   = (const float*)d_in[10];
  const float* betak= (const float*)d_in[11];
  const float* gv   = (const float*)d_in[12];
  const float* betav= (const float*)d_in[13];
  const float* Wp   = (const float*)d_in[14];
  const float* bp   = (const float*)d_in[15];

  float* out = (float*)d_out;
  float* att = out + (size_t)CB * CNQ * CD;   // [B,2,NQ,NK]
  char* ws = (char*)d_ws;
  const size_t MB = 1ull << 20;

  f16* q16   = (f16*)(ws);                     // 0-16MB, dead after gemmIn
  f16* k16   = (f16*)(ws + 16 * MB);           // 16-32, dead after gemmIn
  f16* e1    = (f16*)(ws);                     // 0-32 (after q16/k16 die)
  f16* e2    = (f16*)(ws);                     // 0-32 (after e1 dies)
  f16* WqT   = (f16*)(ws + 32 * MB);           // 2MB
  f16* WkvT  = (f16*)(ws + 34 * MB);           // 4MB
  f16* posb  = (f16*)(ws + 38 * MB);           // 256KB
  f16* posTb = (f16*)(ws + 38 * MB + 256 * 1024);
  float* xw  = (float*)(ws + 38 * MB + 512 * 1024); // 4MB [2][8192][64]
  float* PS  = (float*)(ws + 42 * MB + 512 * 1024); // 256KB [8][8192]
  float* vstat = (float*)(ws + 42 * MB + 768 * 1024); // 64KB [2][8192]
  f16* tmpq  = (f16*)(ws + 43 * MB);           // 16MB (qn in place)
  f16* tmp2  = (f16*)(ws + 59 * MB);           // 32MB (kn in place | v raw)
  f16* vnT   = (f16*)(ws + 91 * MB);           // 16MB (ends 107MB)
  f16* qn = tmpq;
  f16* kn = tmp2;            // ld 2048, cols 0-1023

  prep_kernel<<<512 + 16384 + 768, 256, 0, stream>>>(
      q, k, Wq, Wk, Wv, q16, k16, WqT, WkvT, posb, posTb);

  gemmIn_kernel<<<768, 512, 0, stream>>>(q16, WqT, tmpq, k16, WkvT, tmp2);
  ln3_kernel<<<dim3(CB * CNQ, 3), 256, 0, stream>>>(
      tmpq, tmp2, vstat, bq, gq, betaq, bk, gk, betak, bv);
  transposeLN_kernel<<<dim3(CNK / 64, CD / 64, CB), 256, 0, stream>>>(
      tmp2, vnT, vstat, bv, gv, betav);

  gemmS1_kernel<<<256, 512, 0, stream>>>(qn, kn, e1, PS);

  xgemm_kernel<<<dim3(CB * CNQ / 64, 1, 2), 256, 0, stream>>>(e1, posTb, PS, xw, att);
  attn2_kernel<<<CB * CNQ / 32, 512, 0, stream>>>(xw, Wp, bp, posb, PS, e2, att);

  gemmOut_kernel<<<256, 512, 0, stream>>>(e2, vnT, out);
}